// Round 2
// baseline (5825.366 us; speedup 1.0000x reference)
//
#include <hip/hip_runtime.h>
#include <math.h>

#define B_   8
#define S_   1024
#define SR_  256
#define SN_  1024
#define D1_  768
#define D2_  512
#define D3_  768
#define MVH_ 256
#define H_   12
#define HD_  64
#define MLP_ 3072

// ---------------- LayerNorm (optionally dual output) ----------------
__global__ __launch_bounds__(256) void ln_dual(const float* __restrict__ x,
    const float* __restrict__ w1, const float* __restrict__ w2,
    float* __restrict__ o1, float* __restrict__ o2, int D) {
  int row = blockIdx.x;
  const float* xr = x + (size_t)row * D;
  int tid = threadIdx.x;
  float s = 0.f, ss = 0.f;
  for (int i = tid; i < D; i += 256) { float v = xr[i]; s += v; ss += v * v; }
  __shared__ float rs[256];
  __shared__ float rq[256];
  rs[tid] = s; rq[tid] = ss;
  __syncthreads();
  for (int off = 128; off > 0; off >>= 1) {
    if (tid < off) { rs[tid] += rs[tid + off]; rq[tid] += rq[tid + off]; }
    __syncthreads();
  }
  float mu  = rs[0] / (float)D;
  float var = rq[0] / (float)D - mu * mu;
  float inv = rsqrtf(var + 1e-6f);
  for (int i = tid; i < D; i += 256) {
    float v = (xr[i] - mu) * inv;
    o1[(size_t)row * D + i] = v * w1[i];
    if (o2) o2[(size_t)row * D + i] = v * w2[i];
  }
}

// ---------------- GEMM: C[M,N] = A[M,K] @ B[N,K]^T  (+ epilogue) ----------------
// EPI: 0 = none, 1 = += R, 2 = exact gelu
template <int EPI>
__global__ __launch_bounds__(256) void gemm_abT(const float* __restrict__ A,
    const float* __restrict__ Bm, const float* __restrict__ R,
    float* __restrict__ C, int M, int N, int K) {
  __shared__ float As[16][68];
  __shared__ float Bs[16][68];
  int tid = threadIdx.x;
  int tx = tid & 15, ty = tid >> 4;
  int m0 = blockIdx.y << 6, n0 = blockIdx.x << 6;
  int lrow = tid >> 2;
  int lk = (tid & 3) << 2;
  const float* Ap = A + (size_t)(m0 + lrow) * K + lk;
  const float* Bp = Bm + (size_t)(n0 + lrow) * K + lk;
  float acc[4][4] = {};
  for (int k0 = 0; k0 < K; k0 += 16) {
    float4 av = *(const float4*)(Ap + k0);
    float4 bv = *(const float4*)(Bp + k0);
    As[lk + 0][lrow] = av.x; As[lk + 1][lrow] = av.y;
    As[lk + 2][lrow] = av.z; As[lk + 3][lrow] = av.w;
    Bs[lk + 0][lrow] = bv.x; Bs[lk + 1][lrow] = bv.y;
    Bs[lk + 2][lrow] = bv.z; Bs[lk + 3][lrow] = bv.w;
    __syncthreads();
#pragma unroll
    for (int kk = 0; kk < 16; ++kk) {
      float a[4], b[4];
#pragma unroll
      for (int i = 0; i < 4; ++i) a[i] = As[kk][ty * 4 + i];
#pragma unroll
      for (int j = 0; j < 4; ++j) b[j] = Bs[kk][tx * 4 + j];
#pragma unroll
      for (int i = 0; i < 4; ++i)
#pragma unroll
        for (int j = 0; j < 4; ++j) acc[i][j] = fmaf(a[i], b[j], acc[i][j]);
    }
    __syncthreads();
  }
#pragma unroll
  for (int i = 0; i < 4; ++i)
#pragma unroll
    for (int j = 0; j < 4; ++j) {
      int r = m0 + ty * 4 + i, c = n0 + tx * 4 + j;
      float v = acc[i][j];
      if (EPI == 1) v += R[(size_t)r * N + c];
      if (EPI == 2) v = 0.5f * v * (1.0f + erff(v * 0.70710678118654752f));
      C[(size_t)r * N + c] = v;
    }
}

// ---------------- Batched GEMM: C_b[M,N] = W[M,K] @ X_b[K,N] ----------------
__global__ __launch_bounds__(256) void gemm_wx(const float* __restrict__ W,
    const float* __restrict__ X, float* __restrict__ C,
    int M, int N, int K, long strideX, long strideC) {
  int bb = blockIdx.z;
  const float* Xb = X + (size_t)bb * strideX;
  float* Cb = C + (size_t)bb * strideC;
  __shared__ float Ws[16][68];
  __shared__ float Xs[16][64];
  int tid = threadIdx.x;
  int tx = tid & 15, ty = tid >> 4;
  int m0 = blockIdx.y << 6, n0 = blockIdx.x << 6;
  int lrow = tid >> 2, lk = (tid & 3) << 2;
  int xrow = tid >> 4, xcol = (tid & 15) << 2;
  float acc[4][4] = {};
  for (int k0 = 0; k0 < K; k0 += 16) {
    float4 wv = *(const float4*)&W[(size_t)(m0 + lrow) * K + k0 + lk];
    float4 xv = *(const float4*)&Xb[(size_t)(k0 + xrow) * N + n0 + xcol];
    Ws[lk + 0][lrow] = wv.x; Ws[lk + 1][lrow] = wv.y;
    Ws[lk + 2][lrow] = wv.z; Ws[lk + 3][lrow] = wv.w;
    *(float4*)&Xs[xrow][xcol] = xv;
    __syncthreads();
#pragma unroll
    for (int kk = 0; kk < 16; ++kk) {
      float a[4], b[4];
#pragma unroll
      for (int i = 0; i < 4; ++i) a[i] = Ws[kk][ty * 4 + i];
#pragma unroll
      for (int j = 0; j < 4; ++j) b[j] = Xs[kk][tx * 4 + j];
#pragma unroll
      for (int i = 0; i < 4; ++i)
#pragma unroll
        for (int j = 0; j < 4; ++j) acc[i][j] = fmaf(a[i], b[j], acc[i][j]);
    }
    __syncthreads();
  }
#pragma unroll
  for (int i = 0; i < 4; ++i)
#pragma unroll
    for (int j = 0; j < 4; ++j) {
      int r = m0 + ty * 4 + i, c = n0 + tx * 4 + j;
      Cb[(size_t)r * N + c] = acc[i][j];
    }
}

// ---------------- reparameterization: z = mean + (e*eps + (1-e)*dirty)*exp(0.5*var) ----------------
__global__ __launch_bounds__(256) void z_combine(float* __restrict__ mean_io,
    const float* __restrict__ var, const float* __restrict__ eps,
    const float* __restrict__ dirty, const float* __restrict__ e2de_p,
    int total, int perBatch) {
  int i = blockIdx.x * 256 + threadIdx.x;
  if (i >= total) return;
  float e = e2de_p[0];
  float v = mean_io[i] +
            (e * eps[i] + (1.0f - e) * dirty[i % perBatch]) * expf(0.5f * var[i]);
  mean_io[i] = v;
}

// ---------------- head pack + RoPE: out[b,h,s,64] = concat(zf heads, rope(rf heads)) * scale ----------------
__global__ __launch_bounds__(256) void pack_qk(const float* __restrict__ zf,
    const float* __restrict__ rf, const float* __restrict__ freqs,
    float* __restrict__ out, float scale) {
  int i = blockIdx.x * 256 + threadIdx.x;  // i = ((b*H+h)*S + s)*64 + d
  int d = i & 63;
  int s = (i >> 6) & (S_ - 1);
  int bh = i >> 16;
  int b = bh / H_, h = bh % H_;
  float v;
  if (d < 32) {
    v = zf[((size_t)(b * S_ + s)) * (H_ * 32) + h * 32 + d];
  } else {
    int dr = d - 32;
    const float* xr = rf + ((size_t)(b * S_ + s)) * (H_ * 32) + h * 32;
    float f = freqs[s * 16 + (dr & 15)];
    float c = cosf(f), sn = sinf(f);
    if (dr < 16) v = xr[dr] * c - xr[dr + 16] * sn;
    else         v = xr[dr] * c + xr[dr - 16] * sn;
  }
  out[i] = v * scale;
}

__global__ __launch_bounds__(256) void pack_v(const float* __restrict__ vzf,
    float* __restrict__ out) {
  int i = blockIdx.x * 256 + threadIdx.x;  // i = ((b*H+h)*S + s)*64 + d
  int d = i & 63;
  int s = (i >> 6) & (S_ - 1);
  int bh = i >> 16;
  int b = bh / H_, h = bh % H_;
  out[i] = vzf[((size_t)(b * S_ + s)) * D3_ + h * 64 + d];
}

// ---------------- flash attention: 1 wave per (b,h,q-row), online softmax ----------------
__global__ __launch_bounds__(64) void flash_attn(const float* __restrict__ Q,
    const float* __restrict__ K, const float* __restrict__ V,
    float* __restrict__ O) {
  int gr = blockIdx.x;          // bh*S + s
  int srow = gr & (S_ - 1);
  int bh = gr >> 10;
  int b = bh / H_, h = bh % H_;
  const float* q = Q + (size_t)gr * HD_;
  const float* Kb = K + (size_t)bh * S_ * HD_;
  const float* Vb = V + (size_t)bh * S_ * HD_;
  int lane = threadIdx.x;
  __shared__ float qs[HD_];
  qs[lane] = q[lane];
  __syncthreads();
  float m = -1e30f, l = 0.f, acc = 0.f;
  for (int k0 = 0; k0 < S_; k0 += 64) {
    const float4* kr = (const float4*)(Kb + (size_t)(k0 + lane) * HD_);
    const float4* qf = (const float4*)qs;
    float s0 = 0.f, s1 = 0.f, s2 = 0.f, s3 = 0.f;
#pragma unroll
    for (int d4 = 0; d4 < 16; d4 += 4) {
      float4 kv0 = kr[d4 + 0], kv1 = kr[d4 + 1], kv2 = kr[d4 + 2], kv3 = kr[d4 + 3];
      float4 qv0 = qf[d4 + 0], qv1 = qf[d4 + 1], qv2 = qf[d4 + 2], qv3 = qf[d4 + 3];
      s0 += kv0.x * qv0.x + kv0.y * qv0.y + kv0.z * qv0.z + kv0.w * qv0.w;
      s1 += kv1.x * qv1.x + kv1.y * qv1.y + kv1.z * qv1.z + kv1.w * qv1.w;
      s2 += kv2.x * qv2.x + kv2.y * qv2.y + kv2.z * qv2.z + kv2.w * qv2.w;
      s3 += kv3.x * qv3.x + kv3.y * qv3.y + kv3.z * qv3.z + kv3.w * qv3.w;
    }
    float sc = (s0 + s1) + (s2 + s3);   // q was pre-scaled by 1/sqrt(HD)
    float cm = sc;
#pragma unroll
    for (int off = 32; off > 0; off >>= 1) cm = fmaxf(cm, __shfl_xor(cm, off));
    float mn = fmaxf(m, cm);
    float p = expf(sc - mn);
    float alpha = expf(m - mn);
    float psum = p;
#pragma unroll
    for (int off = 32; off > 0; off >>= 1) psum += __shfl_xor(psum, off);
    l = l * alpha + psum;
    acc *= alpha;
#pragma unroll 16
    for (int t = 0; t < 64; ++t) {
      acc = fmaf(__shfl(p, t), Vb[(size_t)(k0 + t) * HD_ + lane], acc);
    }
    m = mn;
  }
  O[((size_t)(b * S_ + srow)) * D3_ + h * HD_ + lane] = acc / l;
}

// ---------------- host ----------------
extern "C" void kernel_launch(void* const* d_in, const int* in_sizes, int n_in,
                              void* d_out, int out_size, void* d_ws, size_t ws_size,
                              hipStream_t stream) {
  const float* input_q = (const float*)d_in[0];
  const float* ln_q_w  = (const float*)d_in[1];
  const float* ln_kv_w = (const float*)d_in[2];
  const float* Wt_mq   = (const float*)d_in[3];
  const float* Wt_vq   = (const float*)d_in[4];
  const float* Wt_mkv  = (const float*)d_in[5];
  const float* Wt_vkv  = (const float*)d_in[6];
  const float* mq_w1   = (const float*)d_in[7];
  const float* mq_w2   = (const float*)d_in[8];
  const float* vq_w1   = (const float*)d_in[9];
  const float* vq_w2   = (const float*)d_in[10];
  const float* mkv_w1  = (const float*)d_in[11];
  const float* mkv_w2  = (const float*)d_in[12];
  const float* vkv_w1  = (const float*)d_in[13];
  const float* vkv_w2  = (const float*)d_in[14];
  const float* dirty_zq  = (const float*)d_in[15];
  const float* dirty_zkv = (const float*)d_in[16];
  const float* e2de      = (const float*)d_in[17];
  const float* Wt_qzu  = (const float*)d_in[18];
  const float* Wt_kzu  = (const float*)d_in[19];
  const float* Wt_vzu  = (const float*)d_in[20];
  const float* Wt_qr   = (const float*)d_in[21];
  const float* Wt_kr   = (const float*)d_in[22];
  const float* qz_up   = (const float*)d_in[23];
  const float* kz_up   = (const float*)d_in[24];
  const float* vz_up   = (const float*)d_in[25];
  const float* q_w     = (const float*)d_in[26];
  const float* k_w     = (const float*)d_in[27];
  const float* v_w     = (const float*)d_in[28];
  const float* qr_w    = (const float*)d_in[29];
  const float* kr_w    = (const float*)d_in[30];
  const float* rope_q_f = (const float*)d_in[31];
  const float* rope_k_f = (const float*)d_in[32];
  const float* out_w   = (const float*)d_in[33];
  const float* ln2_w   = (const float*)d_in[34];
  const float* mlp_w1  = (const float*)d_in[35];
  const float* mlp_w2  = (const float*)d_in[36];
  const float* eps_zq  = (const float*)d_in[37];
  const float* eps_zkv = (const float*)d_in[38];

  float* ws = (float*)d_ws;
  // arena layout (floats); later buffers overlay dead earlier regions
  float* xq   = ws + 0;         // [8,1024,768]
  float* xkv  = ws + 6291456;   // [8,1024,768]
  float* t1   = ws + 12582912;  // [8,256,768]
  float* t2   = ws + 14155776;  // [8,256,512]
  float* varb = ws + 15204352;  // [8,256,256]
  float* zq   = ws + 15728640;  // [8,256,256]
  float* zkv  = ws + 16252928;  // [8,256,256]
  float* up_t = ws + 16777216;  // [8,1024,256]
  float* mid  = ws + 18874368;  // [8,1024,512]
  float* qzf  = ws + 23068672;  // [8,1024,384]
  float* kzf  = ws + 26214400;  // [8,1024,384]
  float* qrf  = ws + 29360128;  // [8,1024,384]
  float* krf  = ws + 32505856;  // [8,1024,384]
  float* vzf  = ws + 35651584;  // [8,1024,768] -> high water 41943040 floats (168 MB)
  float* tkr  = ws + 0;         // [8,1024,768] overlays dead xq
  float* qp   = ws + 0;         // [8,12,1024,64] overlays xq (after tkr dead)
  float* kp   = ws + 6291456;   // overlays xkv
  float* vp   = ws + 12582912;  // overlays t1..up_t (dead)
  float* of   = ws + 18874368;  // o flat [8,1024,768] overlays mid+qzf head
  float* xb   = ws + 25165824;  // x overlays kzf/qrf (dead)
  float* yl   = ws + 31457280;  // LN2 out overlays krf/vzf (dead)
  float* hm   = ws + 0;         // [8192,3072] overlays q/k/v/of (dead)

  auto launch_abT = [&](int epi, const float* A, const float* Bm, const float* R,
                        float* C, int M, int N, int K) {
    dim3 g(N / 64, M / 64);
    if (epi == 0)      gemm_abT<0><<<g, 256, 0, stream>>>(A, Bm, R, C, M, N, K);
    else if (epi == 1) gemm_abT<1><<<g, 256, 0, stream>>>(A, Bm, R, C, M, N, K);
    else               gemm_abT<2><<<g, 256, 0, stream>>>(A, Bm, R, C, M, N, K);
  };
  auto launch_wx = [&](const float* W, const float* X, float* C, int M, int N, int K,
                       long sx, long sc) {
    dim3 g(N / 64, M / 64, B_);
    gemm_wx<<<g, 256, 0, stream>>>(W, X, C, M, N, K, sx, sc);
  };

  // 1) dual LN
  ln_dual<<<B_ * S_, 256, 0, stream>>>(input_q, ln_q_w, ln_kv_w, xq, xkv, D1_);

  // 2) VAE q: mean and var chains, then reparam
  launch_wx(Wt_mq, xq, t1, SR_, D1_, S_, (long)S_ * D1_, (long)SR_ * D1_);
  launch_abT(0, t1, mq_w1, nullptr, t2, B_ * SR_, D2_, D1_);
  launch_abT(0, t2, mq_w2, nullptr, zq, B_ * SR_, MVH_, D2_);
  launch_wx(Wt_vq, xq, t1, SR_, D1_, S_, (long)S_ * D1_, (long)SR_ * D1_);
  launch_abT(0, t1, vq_w1, nullptr, t2, B_ * SR_, D2_, D1_);
  launch_abT(0, t2, vq_w2, nullptr, varb, B_ * SR_, MVH_, D2_);
  z_combine<<<(B_ * SR_ * MVH_) / 256, 256, 0, stream>>>(zq, varb, eps_zq, dirty_zq,
                                                         e2de, B_ * SR_ * MVH_, SR_ * MVH_);
  // VAE kv
  launch_wx(Wt_mkv, xkv, t1, SR_, D1_, S_, (long)S_ * D1_, (long)SR_ * D1_);
  launch_abT(0, t1, mkv_w1, nullptr, t2, B_ * SR_, D2_, D1_);
  launch_abT(0, t2, mkv_w2, nullptr, zkv, B_ * SR_, MVH_, D2_);
  launch_wx(Wt_vkv, xkv, t1, SR_, D1_, S_, (long)S_ * D1_, (long)SR_ * D1_);
  launch_abT(0, t1, vkv_w1, nullptr, t2, B_ * SR_, D2_, D1_);
  launch_abT(0, t2, vkv_w2, nullptr, varb, B_ * SR_, MVH_, D2_);
  z_combine<<<(B_ * SR_ * MVH_) / 256, 256, 0, stream>>>(zkv, varb, eps_zkv, dirty_zkv,
                                                         e2de, B_ * SR_ * MVH_, SR_ * MVH_);

  // 3) upsample chains
  // qz
  launch_wx(Wt_qzu, zq, up_t, SN_, MVH_, SR_, (long)SR_ * MVH_, (long)SN_ * MVH_);
  launch_abT(0, up_t, qz_up, nullptr, mid, B_ * SN_, D2_, MVH_);
  launch_abT(0, mid, q_w, nullptr, qzf, B_ * SN_, H_ * 32, D2_);
  // kz
  launch_wx(Wt_kzu, zkv, up_t, SN_, MVH_, SR_, (long)SR_ * MVH_, (long)SN_ * MVH_);
  launch_abT(0, up_t, kz_up, nullptr, mid, B_ * SN_, D2_, MVH_);
  launch_abT(0, mid, k_w, nullptr, kzf, B_ * SN_, H_ * 32, D2_);
  // vz
  launch_wx(Wt_vzu, zkv, up_t, SN_, MVH_, SR_, (long)SR_ * MVH_, (long)SN_ * MVH_);
  launch_abT(0, up_t, vz_up, nullptr, mid, B_ * SN_, D2_, MVH_);
  launch_abT(0, mid, v_w, nullptr, vzf, B_ * SN_, D3_, D2_);
  // qr
  launch_wx(Wt_qr, zq, up_t, SN_, MVH_, SR_, (long)SR_ * MVH_, (long)SN_ * MVH_);
  launch_abT(0, up_t, qr_w, nullptr, qrf, B_ * SN_, H_ * 32, MVH_);
  // kr (from raw input_q)
  launch_wx(Wt_kr, input_q, tkr, SN_, D1_, S_, (long)S_ * D1_, (long)SN_ * D1_);
  launch_abT(0, tkr, kr_w, nullptr, krf, B_ * SN_, H_ * 32, D1_);

  // 4) pack heads (+RoPE; q pre-scaled by 1/sqrt(64))
  int tot = B_ * H_ * S_ * HD_;
  pack_qk<<<tot / 256, 256, 0, stream>>>(qzf, qrf, rope_q_f, qp, 0.125f);
  pack_qk<<<tot / 256, 256, 0, stream>>>(kzf, krf, rope_k_f, kp, 1.0f);
  pack_v<<<tot / 256, 256, 0, stream>>>(vzf, vp);

  // 5) attention
  flash_attn<<<B_ * H_ * S_, 64, 0, stream>>>(qp, kp, vp, of);

  // 6) epilogue: out-proj + residual, LN2, MLP
  launch_abT(1, of, out_w, input_q, xb, B_ * SN_, D3_, D3_);
  ln_dual<<<B_ * SN_, 256, 0, stream>>>(xb, ln2_w, nullptr, yl, nullptr, D3_);
  launch_abT(2, yl, mlp_w1, nullptr, hm, B_ * SN_, MLP_, D3_);
  launch_abT(1, hm, mlp_w2, xb, (float*)d_out, B_ * SN_, D3_, MLP_);
}

// Round 3
// 3089.048 us; speedup vs baseline: 1.8858x; 1.8858x over previous
//
#include <hip/hip_runtime.h>
#include <math.h>

#define B_   8
#define S_   1024
#define SR_  256
#define SN_  1024
#define D1_  768
#define D2_  512
#define D3_  768
#define MVH_ 256
#define H_   12
#define HD_  64
#define MLP_ 3072

// ---------------- LayerNorm (optionally dual output) ----------------
__global__ __launch_bounds__(256) void ln_dual(const float* __restrict__ x,
    const float* __restrict__ w1, const float* __restrict__ w2,
    float* __restrict__ o1, float* __restrict__ o2, int D) {
  int row = blockIdx.x;
  const float* xr = x + (size_t)row * D;
  int tid = threadIdx.x;
  float s = 0.f, ss = 0.f;
  for (int i = tid; i < D; i += 256) { float v = xr[i]; s += v; ss += v * v; }
  __shared__ float rs[256];
  __shared__ float rq[256];
  rs[tid] = s; rq[tid] = ss;
  __syncthreads();
  for (int off = 128; off > 0; off >>= 1) {
    if (tid < off) { rs[tid] += rs[tid + off]; rq[tid] += rq[tid + off]; }
    __syncthreads();
  }
  float mu  = rs[0] / (float)D;
  float var = rq[0] / (float)D - mu * mu;
  float inv = rsqrtf(var + 1e-6f);
  for (int i = tid; i < D; i += 256) {
    float v = (xr[i] - mu) * inv;
    o1[(size_t)row * D + i] = v * w1[i];
    if (o2) o2[(size_t)row * D + i] = v * w2[i];
  }
}

// ---------------- GEMM: C[M,N] = A[M,K] @ B[N,K]^T  (+ epilogue) ----------------
// EPI: 0 = none, 1 = += R, 2 = exact gelu
template <int EPI>
__global__ __launch_bounds__(256) void gemm_abT(const float* __restrict__ A,
    const float* __restrict__ Bm, const float* __restrict__ R,
    float* __restrict__ C, int M, int N, int K) {
  __shared__ float As[16][68];
  __shared__ float Bs[16][68];
  int tid = threadIdx.x;
  int tx = tid & 15, ty = tid >> 4;
  int m0 = blockIdx.y << 6, n0 = blockIdx.x << 6;
  int lrow = tid >> 2;
  int lk = (tid & 3) << 2;
  const float* Ap = A + (size_t)(m0 + lrow) * K + lk;
  const float* Bp = Bm + (size_t)(n0 + lrow) * K + lk;
  float acc[4][4] = {};
  for (int k0 = 0; k0 < K; k0 += 16) {
    float4 av = *(const float4*)(Ap + k0);
    float4 bv = *(const float4*)(Bp + k0);
    As[lk + 0][lrow] = av.x; As[lk + 1][lrow] = av.y;
    As[lk + 2][lrow] = av.z; As[lk + 3][lrow] = av.w;
    Bs[lk + 0][lrow] = bv.x; Bs[lk + 1][lrow] = bv.y;
    Bs[lk + 2][lrow] = bv.z; Bs[lk + 3][lrow] = bv.w;
    __syncthreads();
#pragma unroll
    for (int kk = 0; kk < 16; ++kk) {
      float a[4], b[4];
#pragma unroll
      for (int i = 0; i < 4; ++i) a[i] = As[kk][ty * 4 + i];
#pragma unroll
      for (int j = 0; j < 4; ++j) b[j] = Bs[kk][tx * 4 + j];
#pragma unroll
      for (int i = 0; i < 4; ++i)
#pragma unroll
        for (int j = 0; j < 4; ++j) acc[i][j] = fmaf(a[i], b[j], acc[i][j]);
    }
    __syncthreads();
  }
#pragma unroll
  for (int i = 0; i < 4; ++i)
#pragma unroll
    for (int j = 0; j < 4; ++j) {
      int r = m0 + ty * 4 + i, c = n0 + tx * 4 + j;
      float v = acc[i][j];
      if (EPI == 1) v += R[(size_t)r * N + c];
      if (EPI == 2) v = 0.5f * v * (1.0f + erff(v * 0.70710678118654752f));
      C[(size_t)r * N + c] = v;
    }
}

// ---------------- Batched GEMM: C_b[M,N] = W[M,K] @ X_b[K,N] ----------------
__global__ __launch_bounds__(256) void gemm_wx(const float* __restrict__ W,
    const float* __restrict__ X, float* __restrict__ C,
    int M, int N, int K, long strideX, long strideC) {
  int bb = blockIdx.z;
  const float* Xb = X + (size_t)bb * strideX;
  float* Cb = C + (size_t)bb * strideC;
  __shared__ float Ws[16][68];
  __shared__ float Xs[16][64];
  int tid = threadIdx.x;
  int tx = tid & 15, ty = tid >> 4;
  int m0 = blockIdx.y << 6, n0 = blockIdx.x << 6;
  int lrow = tid >> 2, lk = (tid & 3) << 2;
  int xrow = tid >> 4, xcol = (tid & 15) << 2;
  float acc[4][4] = {};
  for (int k0 = 0; k0 < K; k0 += 16) {
    float4 wv = *(const float4*)&W[(size_t)(m0 + lrow) * K + k0 + lk];
    float4 xv = *(const float4*)&Xb[(size_t)(k0 + xrow) * N + n0 + xcol];
    Ws[lk + 0][lrow] = wv.x; Ws[lk + 1][lrow] = wv.y;
    Ws[lk + 2][lrow] = wv.z; Ws[lk + 3][lrow] = wv.w;
    *(float4*)&Xs[xrow][xcol] = xv;
    __syncthreads();
#pragma unroll
    for (int kk = 0; kk < 16; ++kk) {
      float a[4], b[4];
#pragma unroll
      for (int i = 0; i < 4; ++i) a[i] = Ws[kk][ty * 4 + i];
#pragma unroll
      for (int j = 0; j < 4; ++j) b[j] = Xs[kk][tx * 4 + j];
#pragma unroll
      for (int i = 0; i < 4; ++i)
#pragma unroll
        for (int j = 0; j < 4; ++j) acc[i][j] = fmaf(a[i], b[j], acc[i][j]);
    }
    __syncthreads();
  }
#pragma unroll
  for (int i = 0; i < 4; ++i)
#pragma unroll
    for (int j = 0; j < 4; ++j) {
      int r = m0 + ty * 4 + i, c = n0 + tx * 4 + j;
      Cb[(size_t)r * N + c] = acc[i][j];
    }
}

// ---------------- reparameterization ----------------
__global__ __launch_bounds__(256) void z_combine(float* __restrict__ mean_io,
    const float* __restrict__ var, const float* __restrict__ eps,
    const float* __restrict__ dirty, const float* __restrict__ e2de_p,
    int total, int perBatch) {
  int i = blockIdx.x * 256 + threadIdx.x;
  if (i >= total) return;
  float e = e2de_p[0];
  float v = mean_io[i] +
            (e * eps[i] + (1.0f - e) * dirty[i % perBatch]) * expf(0.5f * var[i]);
  mean_io[i] = v;
}

// ---------------- head pack + RoPE ----------------
__global__ __launch_bounds__(256) void pack_qk(const float* __restrict__ zf,
    const float* __restrict__ rf, const float* __restrict__ freqs,
    float* __restrict__ out, float scale) {
  int i = blockIdx.x * 256 + threadIdx.x;  // i = ((b*H+h)*S + s)*64 + d
  int d = i & 63;
  int s = (i >> 6) & (S_ - 1);
  int bh = i >> 16;
  int b = bh / H_, h = bh % H_;
  float v;
  if (d < 32) {
    v = zf[((size_t)(b * S_ + s)) * (H_ * 32) + h * 32 + d];
  } else {
    int dr = d - 32;
    const float* xr = rf + ((size_t)(b * S_ + s)) * (H_ * 32) + h * 32;
    float f = freqs[s * 16 + (dr & 15)];
    float c = cosf(f), sn = sinf(f);
    if (dr < 16) v = xr[dr] * c - xr[dr + 16] * sn;
    else         v = xr[dr] * c + xr[dr - 16] * sn;
  }
  out[i] = v * scale;
}

__global__ __launch_bounds__(256) void pack_v(const float* __restrict__ vzf,
    float* __restrict__ out) {
  int i = blockIdx.x * 256 + threadIdx.x;  // i = ((b*H+h)*S + s)*64 + d
  int d = i & 63;
  int s = (i >> 6) & (S_ - 1);
  int bh = i >> 16;
  int b = bh / H_, h = bh % H_;
  out[i] = vzf[((size_t)(b * S_ + s)) * D3_ + h * 64 + d];
}

// ---------------- tiled flash attention ----------------
// grid: (S/64, B*H), block 256. Each block: 64 q-rows x full head.
// Thread (ty,tx) owns a 4x4 S/P microtile and a 4(row)x4(dcol) O microtile.
__global__ __launch_bounds__(256) void attn_tile(const float* __restrict__ Q,
    const float* __restrict__ K, const float* __restrict__ V,
    float* __restrict__ O) {
  __shared__ float Qt[64][64];  // Qt[d][r]  (Q transposed)
  __shared__ float Kt[64][64];  // Kt[d][c]  (K transposed)
  __shared__ float Vs[64][64];  // Vs[c][d]  (natural)
  __shared__ float Ps[64][64];  // Ps[c][r]  (P transposed)
  int tid = threadIdx.x;
  int tx = tid & 15, ty = tid >> 4;
  int bh = blockIdx.y;
  int q0 = blockIdx.x << 6;
  const float* Qb = Q + (size_t)bh * S_ * HD_;
  const float* Kb = K + (size_t)bh * S_ * HD_;
  const float* Vb = V + (size_t)bh * S_ * HD_;
  {
    int r = tid >> 4;
    int d0 = (tid & 15) << 2;
#pragma unroll
    for (int p = 0; p < 4; ++p) {
      int row = p * 16 + r;
      float4 v = *(const float4*)&Qb[(size_t)(q0 + row) * HD_ + d0];
      Qt[d0 + 0][row] = v.x; Qt[d0 + 1][row] = v.y;
      Qt[d0 + 2][row] = v.z; Qt[d0 + 3][row] = v.w;
    }
  }
  float m[4], l[4], o[4][4];
#pragma unroll
  for (int i = 0; i < 4; ++i) {
    m[i] = -1e30f; l[i] = 0.f;
#pragma unroll
    for (int j = 0; j < 4; ++j) o[i][j] = 0.f;
  }
  for (int k0 = 0; k0 < S_; k0 += 64) {
    __syncthreads();   // previous PV done before overwriting K/V tiles
    {
      int r = tid >> 4;
      int d0 = (tid & 15) << 2;
#pragma unroll
      for (int p = 0; p < 4; ++p) {
        int row = p * 16 + r;
        float4 kv = *(const float4*)&Kb[(size_t)(k0 + row) * HD_ + d0];
        Kt[d0 + 0][row] = kv.x; Kt[d0 + 1][row] = kv.y;
        Kt[d0 + 2][row] = kv.z; Kt[d0 + 3][row] = kv.w;
        *(float4*)&Vs[row][d0] = *(const float4*)&Vb[(size_t)(k0 + row) * HD_ + d0];
      }
    }
    __syncthreads();
    // S = Qtile @ Ktile^T  (q pre-scaled by 1/8)
    float s[4][4] = {};
#pragma unroll
    for (int d = 0; d < 64; ++d) {
      float a[4], bv[4];
#pragma unroll
      for (int i = 0; i < 4; ++i) a[i] = Qt[d][ty * 4 + i];
#pragma unroll
      for (int j = 0; j < 4; ++j) bv[j] = Kt[d][tx * 4 + j];
#pragma unroll
      for (int i = 0; i < 4; ++i)
#pragma unroll
        for (int j = 0; j < 4; ++j) s[i][j] = fmaf(a[i], bv[j], s[i][j]);
    }
    // online softmax; row group = 16 consecutive lanes (same ty)
#pragma unroll
    for (int i = 0; i < 4; ++i) {
      float cm = fmaxf(fmaxf(s[i][0], s[i][1]), fmaxf(s[i][2], s[i][3]));
      cm = fmaxf(cm, __shfl_xor(cm, 1));
      cm = fmaxf(cm, __shfl_xor(cm, 2));
      cm = fmaxf(cm, __shfl_xor(cm, 4));
      cm = fmaxf(cm, __shfl_xor(cm, 8));
      float mn = fmaxf(m[i], cm);
      float al = __expf(m[i] - mn);
      float ps = 0.f;
#pragma unroll
      for (int j = 0; j < 4; ++j) { s[i][j] = __expf(s[i][j] - mn); ps += s[i][j]; }
      ps += __shfl_xor(ps, 1);
      ps += __shfl_xor(ps, 2);
      ps += __shfl_xor(ps, 4);
      ps += __shfl_xor(ps, 8);
      l[i] = l[i] * al + ps;
      m[i] = mn;
#pragma unroll
      for (int j = 0; j < 4; ++j) o[i][j] *= al;
    }
    // store P transposed for PV pass
#pragma unroll
    for (int i = 0; i < 4; ++i)
#pragma unroll
      for (int j = 0; j < 4; ++j)
        Ps[tx * 4 + j][ty * 4 + i] = s[i][j];
    __syncthreads();
    // O += P @ Vtile
#pragma unroll
    for (int c = 0; c < 64; ++c) {
      float a[4], bv[4];
#pragma unroll
      for (int i = 0; i < 4; ++i) a[i] = Ps[c][ty * 4 + i];
#pragma unroll
      for (int j = 0; j < 4; ++j) bv[j] = Vs[c][tx * 4 + j];
#pragma unroll
      for (int i = 0; i < 4; ++i)
#pragma unroll
        for (int j = 0; j < 4; ++j) o[i][j] = fmaf(a[i], bv[j], o[i][j]);
    }
  }
  int b = bh / H_, h = bh % H_;
#pragma unroll
  for (int i = 0; i < 4; ++i) {
    float inv = 1.f / l[i];
    int row = q0 + ty * 4 + i;
#pragma unroll
    for (int j = 0; j < 4; ++j)
      O[((size_t)(b * S_ + row)) * D3_ + h * HD_ + tx * 4 + j] = o[i][j] * inv;
  }
}

// ---------------- host ----------------
extern "C" void kernel_launch(void* const* d_in, const int* in_sizes, int n_in,
                              void* d_out, int out_size, void* d_ws, size_t ws_size,
                              hipStream_t stream) {
  const float* input_q = (const float*)d_in[0];
  const float* ln_q_w  = (const float*)d_in[1];
  const float* ln_kv_w = (const float*)d_in[2];
  const float* Wt_mq   = (const float*)d_in[3];
  const float* Wt_vq   = (const float*)d_in[4];
  const float* Wt_mkv  = (const float*)d_in[5];
  const float* Wt_vkv  = (const float*)d_in[6];
  const float* mq_w1   = (const float*)d_in[7];
  const float* mq_w2   = (const float*)d_in[8];
  const float* vq_w1   = (const float*)d_in[9];
  const float* vq_w2   = (const float*)d_in[10];
  const float* mkv_w1  = (const float*)d_in[11];
  const float* mkv_w2  = (const float*)d_in[12];
  const float* vkv_w1  = (const float*)d_in[13];
  const float* vkv_w2  = (const float*)d_in[14];
  const float* dirty_zq  = (const float*)d_in[15];
  const float* dirty_zkv = (const float*)d_in[16];
  const float* e2de      = (const float*)d_in[17];
  const float* Wt_qzu  = (const float*)d_in[18];
  const float* Wt_kzu  = (const float*)d_in[19];
  const float* Wt_vzu  = (const float*)d_in[20];
  const float* Wt_qr   = (const float*)d_in[21];
  const float* Wt_kr   = (const float*)d_in[22];
  const float* qz_up   = (const float*)d_in[23];
  const float* kz_up   = (const float*)d_in[24];
  const float* vz_up   = (const float*)d_in[25];
  const float* q_w     = (const float*)d_in[26];
  const float* k_w     = (const float*)d_in[27];
  const float* v_w     = (const float*)d_in[28];
  const float* qr_w    = (const float*)d_in[29];
  const float* kr_w    = (const float*)d_in[30];
  const float* rope_q_f = (const float*)d_in[31];
  const float* rope_k_f = (const float*)d_in[32];
  const float* out_w   = (const float*)d_in[33];
  const float* ln2_w   = (const float*)d_in[34];
  const float* mlp_w1  = (const float*)d_in[35];
  const float* mlp_w2  = (const float*)d_in[36];
  const float* eps_zq  = (const float*)d_in[37];
  const float* eps_zkv = (const float*)d_in[38];

  float* ws = (float*)d_ws;
  float* xq   = ws + 0;         // [8,1024,768]
  float* xkv  = ws + 6291456;   // [8,1024,768]
  float* t1   = ws + 12582912;  // [8,256,768]
  float* t2   = ws + 14155776;  // [8,256,512]
  float* varb = ws + 15204352;  // [8,256,256]
  float* zq   = ws + 15728640;  // [8,256,256]
  float* zkv  = ws + 16252928;  // [8,256,256]
  float* up_t = ws + 16777216;  // [8,1024,256]
  float* mid  = ws + 18874368;  // [8,1024,512]
  float* qzf  = ws + 23068672;  // [8,1024,384]
  float* kzf  = ws + 26214400;  // [8,1024,384]
  float* qrf  = ws + 29360128;  // [8,1024,384]
  float* krf  = ws + 32505856;  // [8,1024,384]
  float* vzf  = ws + 35651584;  // [8,1024,768]
  float* tkr  = ws + 0;         // overlays dead xq
  float* qp   = ws + 0;         // overlays xq
  float* kp   = ws + 6291456;   // overlays xkv
  float* vp   = ws + 12582912;  // overlays t1..up_t
  float* of   = ws + 18874368;  // overlays mid+qzf head
  float* xb   = ws + 25165824;  // overlays kzf/qrf
  float* yl   = ws + 31457280;  // overlays krf/vzf
  float* hm   = ws + 0;         // overlays q/k/v (dead)

  auto launch_abT = [&](int epi, const float* A, const float* Bm, const float* R,
                        float* C, int M, int N, int K) {
    dim3 g(N / 64, M / 64);
    if (epi == 0)      gemm_abT<0><<<g, 256, 0, stream>>>(A, Bm, R, C, M, N, K);
    else if (epi == 1) gemm_abT<1><<<g, 256, 0, stream>>>(A, Bm, R, C, M, N, K);
    else               gemm_abT<2><<<g, 256, 0, stream>>>(A, Bm, R, C, M, N, K);
  };
  auto launch_wx = [&](const float* W, const float* X, float* C, int M, int N, int K,
                       long sx, long sc) {
    dim3 g(N / 64, M / 64, B_);
    gemm_wx<<<g, 256, 0, stream>>>(W, X, C, M, N, K, sx, sc);
  };

  // 1) dual LN
  ln_dual<<<B_ * S_, 256, 0, stream>>>(input_q, ln_q_w, ln_kv_w, xq, xkv, D1_);

  // 2) VAE chains + reparam
  launch_wx(Wt_mq, xq, t1, SR_, D1_, S_, (long)S_ * D1_, (long)SR_ * D1_);
  launch_abT(0, t1, mq_w1, nullptr, t2, B_ * SR_, D2_, D1_);
  launch_abT(0, t2, mq_w2, nullptr, zq, B_ * SR_, MVH_, D2_);
  launch_wx(Wt_vq, xq, t1, SR_, D1_, S_, (long)S_ * D1_, (long)SR_ * D1_);
  launch_abT(0, t1, vq_w1, nullptr, t2, B_ * SR_, D2_, D1_);
  launch_abT(0, t2, vq_w2, nullptr, varb, B_ * SR_, MVH_, D2_);
  z_combine<<<(B_ * SR_ * MVH_) / 256, 256, 0, stream>>>(zq, varb, eps_zq, dirty_zq,
                                                         e2de, B_ * SR_ * MVH_, SR_ * MVH_);
  launch_wx(Wt_mkv, xkv, t1, SR_, D1_, S_, (long)S_ * D1_, (long)SR_ * D1_);
  launch_abT(0, t1, mkv_w1, nullptr, t2, B_ * SR_, D2_, D1_);
  launch_abT(0, t2, mkv_w2, nullptr, zkv, B_ * SR_, MVH_, D2_);
  launch_wx(Wt_vkv, xkv, t1, SR_, D1_, S_, (long)S_ * D1_, (long)SR_ * D1_);
  launch_abT(0, t1, vkv_w1, nullptr, t2, B_ * SR_, D2_, D1_);
  launch_abT(0, t2, vkv_w2, nullptr, varb, B_ * SR_, MVH_, D2_);
  z_combine<<<(B_ * SR_ * MVH_) / 256, 256, 0, stream>>>(zkv, varb, eps_zkv, dirty_zkv,
                                                         e2de, B_ * SR_ * MVH_, SR_ * MVH_);

  // 3) upsample chains
  launch_wx(Wt_qzu, zq, up_t, SN_, MVH_, SR_, (long)SR_ * MVH_, (long)SN_ * MVH_);
  launch_abT(0, up_t, qz_up, nullptr, mid, B_ * SN_, D2_, MVH_);
  launch_abT(0, mid, q_w, nullptr, qzf, B_ * SN_, H_ * 32, D2_);
  launch_wx(Wt_kzu, zkv, up_t, SN_, MVH_, SR_, (long)SR_ * MVH_, (long)SN_ * MVH_);
  launch_abT(0, up_t, kz_up, nullptr, mid, B_ * SN_, D2_, MVH_);
  launch_abT(0, mid, k_w, nullptr, kzf, B_ * SN_, H_ * 32, D2_);
  launch_wx(Wt_vzu, zkv, up_t, SN_, MVH_, SR_, (long)SR_ * MVH_, (long)SN_ * MVH_);
  launch_abT(0, up_t, vz_up, nullptr, mid, B_ * SN_, D2_, MVH_);
  launch_abT(0, mid, v_w, nullptr, vzf, B_ * SN_, D3_, D2_);
  launch_wx(Wt_qr, zq, up_t, SN_, MVH_, SR_, (long)SR_ * MVH_, (long)SN_ * MVH_);
  launch_abT(0, up_t, qr_w, nullptr, qrf, B_ * SN_, H_ * 32, MVH_);
  launch_wx(Wt_kr, input_q, tkr, SN_, D1_, S_, (long)S_ * D1_, (long)SN_ * D1_);
  launch_abT(0, tkr, kr_w, nullptr, krf, B_ * SN_, H_ * 32, D1_);

  // 4) pack heads (+RoPE; q pre-scaled by 1/sqrt(64))
  int tot = B_ * H_ * S_ * HD_;
  pack_qk<<<tot / 256, 256, 0, stream>>>(qzf, qrf, rope_q_f, qp, 0.125f);
  pack_qk<<<tot / 256, 256, 0, stream>>>(kzf, krf, rope_k_f, kp, 1.0f);
  pack_v<<<tot / 256, 256, 0, stream>>>(vzf, vp);

  // 5) attention (tiled flash)
  {
    dim3 g(S_ / 64, B_ * H_);
    attn_tile<<<g, 256, 0, stream>>>(qp, kp, vp, of);
  }

  // 6) epilogue
  launch_abT(1, of, out_w, input_q, xb, B_ * SN_, D3_, D3_);
  ln_dual<<<B_ * SN_, 256, 0, stream>>>(xb, ln2_w, nullptr, yl, nullptr, D3_);
  launch_abT(2, yl, mlp_w1, nullptr, hm, B_ * SN_, MLP_, D3_);
  launch_abT(1, hm, mlp_w2, xb, (float*)d_out, B_ * SN_, D3_, MLP_);
}

// Round 5
// 2004.714 us; speedup vs baseline: 2.9058x; 1.5409x over previous
//
#include <hip/hip_runtime.h>
#include <math.h>

#define B_   8
#define S_   1024
#define SR_  256
#define SN_  1024
#define D1_  768
#define D2_  512
#define D3_  768
#define MVH_ 256
#define H_   12
#define HD_  64
#define MLP_ 3072

typedef __attribute__((ext_vector_type(8))) short bf16x8;
typedef __attribute__((ext_vector_type(4))) float f32x4;

__device__ inline ushort f2bf(float f) {
  uint u = __float_as_uint(f);
  uint r = (u + 0x7fffu + ((u >> 16) & 1u)) >> 16;
  return (ushort)r;
}

// ---------------- LayerNorm (optionally dual output) ----------------
__global__ __launch_bounds__(256) void ln_dual(const float* __restrict__ x,
    const float* __restrict__ w1, const float* __restrict__ w2,
    float* __restrict__ o1, float* __restrict__ o2, int D) {
  int row = blockIdx.x;
  const float* xr = x + (size_t)row * D;
  int tid = threadIdx.x;
  float s = 0.f, ss = 0.f;
  for (int i = tid; i < D; i += 256) { float v = xr[i]; s += v; ss += v * v; }
  __shared__ float rs[256];
  __shared__ float rq[256];
  rs[tid] = s; rq[tid] = ss;
  __syncthreads();
  for (int off = 128; off > 0; off >>= 1) {
    if (tid < off) { rs[tid] += rs[tid + off]; rq[tid] += rq[tid + off]; }
    __syncthreads();
  }
  float mu  = rs[0] / (float)D;
  float var = rq[0] / (float)D - mu * mu;
  float inv = rsqrtf(var + 1e-6f);
  for (int i = tid; i < D; i += 256) {
    float v = (xr[i] - mu) * inv;
    o1[(size_t)row * D + i] = v * w1[i];
    if (o2) o2[(size_t)row * D + i] = v * w2[i];
  }
}

// ---------------- fp32 GEMM: C[M,N] = A[M,K] @ B[N,K]^T ----------------
template <int EPI>   // 0 none
__global__ __launch_bounds__(256) void gemm_abT(const float* __restrict__ A,
    const float* __restrict__ Bm, const float* __restrict__ R,
    float* __restrict__ C, int M, int N, int K) {
  __shared__ float As[16][68];
  __shared__ float Bs[16][68];
  int tid = threadIdx.x;
  int tx = tid & 15, ty = tid >> 4;
  int m0 = blockIdx.y << 6, n0 = blockIdx.x << 6;
  int lrow = tid >> 2;
  int lk = (tid & 3) << 2;
  const float* Ap = A + (size_t)(m0 + lrow) * K + lk;
  const float* Bp = Bm + (size_t)(n0 + lrow) * K + lk;
  float acc[4][4] = {};
  for (int k0 = 0; k0 < K; k0 += 16) {
    float4 av = *(const float4*)(Ap + k0);
    float4 bv = *(const float4*)(Bp + k0);
    As[lk + 0][lrow] = av.x; As[lk + 1][lrow] = av.y;
    As[lk + 2][lrow] = av.z; As[lk + 3][lrow] = av.w;
    Bs[lk + 0][lrow] = bv.x; Bs[lk + 1][lrow] = bv.y;
    Bs[lk + 2][lrow] = bv.z; Bs[lk + 3][lrow] = bv.w;
    __syncthreads();
#pragma unroll
    for (int kk = 0; kk < 16; ++kk) {
      float a[4], b[4];
#pragma unroll
      for (int i = 0; i < 4; ++i) a[i] = As[kk][ty * 4 + i];
#pragma unroll
      for (int j = 0; j < 4; ++j) b[j] = Bs[kk][tx * 4 + j];
#pragma unroll
      for (int i = 0; i < 4; ++i)
#pragma unroll
        for (int j = 0; j < 4; ++j) acc[i][j] = fmaf(a[i], b[j], acc[i][j]);
    }
    __syncthreads();
  }
#pragma unroll
  for (int i = 0; i < 4; ++i)
#pragma unroll
    for (int j = 0; j < 4; ++j) {
      int r = m0 + ty * 4 + i, c = n0 + tx * 4 + j;
      C[(size_t)r * N + c] = acc[i][j];
    }
}

// ---------------- Batched fp32 GEMM: C_b[M,N] = W[M,K] @ X_b[K,N] ----------------
__global__ __launch_bounds__(256) void gemm_wx(const float* __restrict__ W,
    const float* __restrict__ X, float* __restrict__ C,
    int M, int N, int K, long strideX, long strideC) {
  int bb = blockIdx.z;
  const float* Xb = X + (size_t)bb * strideX;
  float* Cb = C + (size_t)bb * strideC;
  __shared__ float Ws[16][68];
  __shared__ float Xs[16][64];
  int tid = threadIdx.x;
  int tx = tid & 15, ty = tid >> 4;
  int m0 = blockIdx.y << 6, n0 = blockIdx.x << 6;
  int lrow = tid >> 2, lk = (tid & 3) << 2;
  int xrow = tid >> 4, xcol = (tid & 15) << 2;
  float acc[4][4] = {};
  for (int k0 = 0; k0 < K; k0 += 16) {
    float4 wv = *(const float4*)&W[(size_t)(m0 + lrow) * K + k0 + lk];
    float4 xv = *(const float4*)&Xb[(size_t)(k0 + xrow) * N + n0 + xcol];
    Ws[lk + 0][lrow] = wv.x; Ws[lk + 1][lrow] = wv.y;
    Ws[lk + 2][lrow] = wv.z; Ws[lk + 3][lrow] = wv.w;
    *(float4*)&Xs[xrow][xcol] = xv;
    __syncthreads();
#pragma unroll
    for (int kk = 0; kk < 16; ++kk) {
      float a[4], b[4];
#pragma unroll
      for (int i = 0; i < 4; ++i) a[i] = Ws[kk][ty * 4 + i];
#pragma unroll
      for (int j = 0; j < 4; ++j) b[j] = Xs[kk][tx * 4 + j];
#pragma unroll
      for (int i = 0; i < 4; ++i)
#pragma unroll
        for (int j = 0; j < 4; ++j) acc[i][j] = fmaf(a[i], b[j], acc[i][j]);
    }
    __syncthreads();
  }
#pragma unroll
  for (int i = 0; i < 4; ++i)
#pragma unroll
    for (int j = 0; j < 4; ++j) {
      int r = m0 + ty * 4 + i, c = n0 + tx * 4 + j;
      Cb[(size_t)r * N + c] = acc[i][j];
    }
}

// ---------------- bf16 MFMA GEMM: C[M,N] = A[M,K]@B[N,K]^T (A,B bf16; fp32 acc) ----
// EPI: 1 = +R (fp32 out), 2 = gelu (bf16 out)
template <int EPI>
__global__ __launch_bounds__(256) void gemm_bf16(const ushort* __restrict__ A,
    const ushort* __restrict__ Bm, const float* __restrict__ R,
    void* __restrict__ Cout, int M, int N, int K) {
  __shared__ ushort As[128 * 32];
  __shared__ ushort Bs[128 * 32];
  int tid = threadIdx.x;
  int lane = tid & 63, wid = tid >> 6;
  int m0 = blockIdx.y << 7, n0 = blockIdx.x << 7;
  int wm = (wid >> 1) << 6, wn = (wid & 1) << 6;
  f32x4 acc[4][4];
#pragma unroll
  for (int i = 0; i < 4; ++i)
#pragma unroll
    for (int j = 0; j < 4; ++j) acc[i][j] = (f32x4){0.f, 0.f, 0.f, 0.f};
  // staging: thread stages 2x16B of A and B
  int r0 = tid >> 2, kof = (tid & 3) << 3;
  for (int k0 = 0; k0 < K; k0 += 32) {
    __syncthreads();
    uint4 a0 = *(const uint4*)&A[(size_t)(m0 + r0) * K + k0 + kof];
    uint4 a1 = *(const uint4*)&A[(size_t)(m0 + 64 + r0) * K + k0 + kof];
    uint4 b0 = *(const uint4*)&Bm[(size_t)(n0 + r0) * K + k0 + kof];
    uint4 b1 = *(const uint4*)&Bm[(size_t)(n0 + 64 + r0) * K + k0 + kof];
    *(uint4*)&As[r0 * 32 + kof] = a0;
    *(uint4*)&As[(64 + r0) * 32 + kof] = a1;
    *(uint4*)&Bs[r0 * 32 + kof] = b0;
    *(uint4*)&Bs[(64 + r0) * 32 + kof] = b1;
    __syncthreads();
    bf16x8 af[4], bf[4];
#pragma unroll
    for (int m = 0; m < 4; ++m)
      af[m] = *(bf16x8*)&As[(wm + m * 16 + (lane & 15)) * 32 + ((lane >> 4) << 3)];
#pragma unroll
    for (int n = 0; n < 4; ++n)
      bf[n] = *(bf16x8*)&Bs[(wn + n * 16 + (lane & 15)) * 32 + ((lane >> 4) << 3)];
#pragma unroll
    for (int m = 0; m < 4; ++m)
#pragma unroll
      for (int n = 0; n < 4; ++n)
        acc[m][n] = __builtin_amdgcn_mfma_f32_16x16x32_bf16(af[m], bf[n], acc[m][n], 0, 0, 0);
  }
  int cr = (lane >> 4) << 2, cc = lane & 15;
#pragma unroll
  for (int m = 0; m < 4; ++m)
#pragma unroll
    for (int n = 0; n < 4; ++n) {
#pragma unroll
      for (int r = 0; r < 4; ++r) {
        int row = m0 + wm + m * 16 + cr + r;
        int col = n0 + wn + n * 16 + cc;
        float v = acc[m][n][r];
        if (EPI == 1) {
          ((float*)Cout)[(size_t)row * N + col] = v + R[(size_t)row * N + col];
        } else {
          v = 0.5f * v * (1.0f + erff(v * 0.70710678118654752f));
          ((ushort*)Cout)[(size_t)row * N + col] = f2bf(v);
        }
      }
    }
}

// ---------------- fp32 -> bf16 conversion (4 elems/thread) ----------------
__global__ __launch_bounds__(256) void f2b_kern(const float* __restrict__ x,
    ushort* __restrict__ y, int n4) {
  int i = blockIdx.x * 256 + threadIdx.x;
  if (i >= n4) return;
  float4 v = ((const float4*)x)[i];
  ushort4 o;
  o.x = f2bf(v.x); o.y = f2bf(v.y); o.z = f2bf(v.z); o.w = f2bf(v.w);
  ((ushort4*)y)[i] = o;
}

// ---------------- reparameterization ----------------
__global__ __launch_bounds__(256) void z_combine(float* __restrict__ mean_io,
    const float* __restrict__ var, const float* __restrict__ eps,
    const float* __restrict__ dirty, const float* __restrict__ e2de_p,
    int total, int perBatch) {
  int i = blockIdx.x * 256 + threadIdx.x;
  if (i >= total) return;
  float e = e2de_p[0];
  float v = mean_io[i] +
            (e * eps[i] + (1.0f - e) * dirty[i % perBatch]) * expf(0.5f * var[i]);
  mean_io[i] = v;
}

// ---------------- head pack + RoPE ----------------
__global__ __launch_bounds__(256) void pack_qk(const float* __restrict__ zf,
    const float* __restrict__ rf, const float* __restrict__ freqs,
    float* __restrict__ out, float scale) {
  int i = blockIdx.x * 256 + threadIdx.x;  // i = ((b*H+h)*S + s)*64 + d
  int d = i & 63;
  int s = (i >> 6) & (S_ - 1);
  int bh = i >> 16;
  int b = bh / H_, h = bh % H_;
  float v;
  if (d < 32) {
    v = zf[((size_t)(b * S_ + s)) * (H_ * 32) + h * 32 + d];
  } else {
    int dr = d - 32;
    const float* xr = rf + ((size_t)(b * S_ + s)) * (H_ * 32) + h * 32;
    float f = freqs[s * 16 + (dr & 15)];
    float c = cosf(f), sn = sinf(f);
    if (dr < 16) v = xr[dr] * c - xr[dr + 16] * sn;
    else         v = xr[dr] * c + xr[dr - 16] * sn;
  }
  out[i] = v * scale;
}

__global__ __launch_bounds__(256) void pack_v(const float* __restrict__ vzf,
    float* __restrict__ out) {
  int i = blockIdx.x * 256 + threadIdx.x;
  int d = i & 63;
  int s = (i >> 6) & (S_ - 1);
  int bh = i >> 16;
  int b = bh / H_, h = bh % H_;
  out[i] = vzf[((size_t)(b * S_ + s)) * D3_ + h * 64 + d];
}

// ---------------- tiled flash attention (bank-conflict-reduced LDS) ----------------
__global__ __launch_bounds__(256) void attn_tile(const float* __restrict__ Q,
    const float* __restrict__ K, const float* __restrict__ V,
    float* __restrict__ O) {
  __shared__ float Qt[64][65];  // Qt[d][r]; stride 65: staging writes & reads <=2-way
  __shared__ float Kt[64][65];  // Kt[d][c]
  __shared__ float Vs[64][68];  // Vs[c][d]; float4-aligned
  __shared__ float Ps[64][68];  // Ps[q-row][key], natural; float4 writes 4-way, reads broadcast
  int tid = threadIdx.x;
  int tx = tid & 15, ty = tid >> 4;
  int bh = blockIdx.y;
  int q0 = blockIdx.x << 6;
  const float* Qb = Q + (size_t)bh * S_ * HD_;
  const float* Kb = K + (size_t)bh * S_ * HD_;
  const float* Vb = V + (size_t)bh * S_ * HD_;
  {
    int r = tid >> 4;
    int d0 = (tid & 15) << 2;
#pragma unroll
    for (int p = 0; p < 4; ++p) {
      int row = p * 16 + r;
      float4 v = *(const float4*)&Qb[(size_t)(q0 + row) * HD_ + d0];
      Qt[d0 + 0][row] = v.x; Qt[d0 + 1][row] = v.y;
      Qt[d0 + 2][row] = v.z; Qt[d0 + 3][row] = v.w;
    }
  }
  float m[4], l[4], o[4][4];
#pragma unroll
  for (int i = 0; i < 4; ++i) {
    m[i] = -1e30f; l[i] = 0.f;
#pragma unroll
    for (int j = 0; j < 4; ++j) o[i][j] = 0.f;
  }
  for (int k0 = 0; k0 < S_; k0 += 64) {
    __syncthreads();
    {
      int r = tid >> 4;
      int d0 = (tid & 15) << 2;
#pragma unroll
      for (int p = 0; p < 4; ++p) {
        int row = p * 16 + r;
        float4 kv = *(const float4*)&Kb[(size_t)(k0 + row) * HD_ + d0];
        Kt[d0 + 0][row] = kv.x; Kt[d0 + 1][row] = kv.y;
        Kt[d0 + 2][row] = kv.z; Kt[d0 + 3][row] = kv.w;
        *(float4*)&Vs[row][d0] = *(const float4*)&Vb[(size_t)(k0 + row) * HD_ + d0];
      }
    }
    __syncthreads();
    float s[4][4] = {};
#pragma unroll
    for (int d = 0; d < 64; ++d) {
      float a[4], bv[4];
#pragma unroll
      for (int i = 0; i < 4; ++i) a[i] = Qt[d][ty * 4 + i];
#pragma unroll
      for (int j = 0; j < 4; ++j) bv[j] = Kt[d][tx * 4 + j];
#pragma unroll
      for (int i = 0; i < 4; ++i)
#pragma unroll
        for (int j = 0; j < 4; ++j) s[i][j] = fmaf(a[i], bv[j], s[i][j]);
    }
#pragma unroll
    for (int i = 0; i < 4; ++i) {
      float cm = fmaxf(fmaxf(s[i][0], s[i][1]), fmaxf(s[i][2], s[i][3]));
      cm = fmaxf(cm, __shfl_xor(cm, 1));
      cm = fmaxf(cm, __shfl_xor(cm, 2));
      cm = fmaxf(cm, __shfl_xor(cm, 4));
      cm = fmaxf(cm, __shfl_xor(cm, 8));
      float mn = fmaxf(m[i], cm);
      float al = __expf(m[i] - mn);
      float ps = 0.f;
#pragma unroll
      for (int j = 0; j < 4; ++j) { s[i][j] = __expf(s[i][j] - mn); ps += s[i][j]; }
      ps += __shfl_xor(ps, 1);
      ps += __shfl_xor(ps, 2);
      ps += __shfl_xor(ps, 4);
      ps += __shfl_xor(ps, 8);
      l[i] = l[i] * al + ps;
      m[i] = mn;
#pragma unroll
      for (int j = 0; j < 4; ++j) o[i][j] *= al;
    }
#pragma unroll
    for (int i = 0; i < 4; ++i) {
      float4 pv = make_float4(s[i][0], s[i][1], s[i][2], s[i][3]);
      *(float4*)&Ps[ty * 4 + i][tx * 4] = pv;
    }
    __syncthreads();
#pragma unroll
    for (int c = 0; c < 64; ++c) {
      float a[4], bv[4];
#pragma unroll
      for (int i = 0; i < 4; ++i) a[i] = Ps[ty * 4 + i][c];
#pragma unroll
      for (int j = 0; j < 4; ++j) bv[j] = Vs[c][tx * 4 + j];
#pragma unroll
      for (int i = 0; i < 4; ++i)
#pragma unroll
        for (int j = 0; j < 4; ++j) o[i][j] = fmaf(a[i], bv[j], o[i][j]);
    }
  }
  int b = bh / H_, h = bh % H_;
#pragma unroll
  for (int i = 0; i < 4; ++i) {
    float inv = 1.f / l[i];
    int row = q0 + ty * 4 + i;
#pragma unroll
    for (int j = 0; j < 4; ++j)
      O[((size_t)(b * S_ + row)) * D3_ + h * HD_ + tx * 4 + j] = o[i][j] * inv;
  }
}

// ---------------- host ----------------
extern "C" void kernel_launch(void* const* d_in, const int* in_sizes, int n_in,
                              void* d_out, int out_size, void* d_ws, size_t ws_size,
                              hipStream_t stream) {
  const float* input_q = (const float*)d_in[0];
  const float* ln_q_w  = (const float*)d_in[1];
  const float* ln_kv_w = (const float*)d_in[2];
  const float* Wt_mq   = (const float*)d_in[3];
  const float* Wt_vq   = (const float*)d_in[4];
  const float* Wt_mkv  = (const float*)d_in[5];
  const float* Wt_vkv  = (const float*)d_in[6];
  const float* mq_w1   = (const float*)d_in[7];
  const float* mq_w2   = (const float*)d_in[8];
  const float* vq_w1   = (const float*)d_in[9];
  const float* vq_w2   = (const float*)d_in[10];
  const float* mkv_w1  = (const float*)d_in[11];
  const float* mkv_w2  = (const float*)d_in[12];
  const float* vkv_w1  = (const float*)d_in[13];
  const float* vkv_w2  = (const float*)d_in[14];
  const float* dirty_zq  = (const float*)d_in[15];
  const float* dirty_zkv = (const float*)d_in[16];
  const float* e2de      = (const float*)d_in[17];
  const float* Wt_qzu  = (const float*)d_in[18];
  const float* Wt_kzu  = (const float*)d_in[19];
  const float* Wt_vzu  = (const float*)d_in[20];
  const float* Wt_qr   = (const float*)d_in[21];
  const float* Wt_kr   = (const float*)d_in[22];
  const float* qz_up   = (const float*)d_in[23];
  const float* kz_up   = (const float*)d_in[24];
  const float* vz_up   = (const float*)d_in[25];
  const float* q_w     = (const float*)d_in[26];
  const float* k_w     = (const float*)d_in[27];
  const float* v_w     = (const float*)d_in[28];
  const float* qr_w    = (const float*)d_in[29];
  const float* kr_w    = (const float*)d_in[30];
  const float* rope_q_f = (const float*)d_in[31];
  const float* rope_k_f = (const float*)d_in[32];
  const float* out_w   = (const float*)d_in[33];
  const float* ln2_w   = (const float*)d_in[34];
  const float* mlp_w1  = (const float*)d_in[35];
  const float* mlp_w2  = (const float*)d_in[36];
  const float* eps_zq  = (const float*)d_in[37];
  const float* eps_zkv = (const float*)d_in[38];

  float* ws = (float*)d_ws;
  float* xq   = ws + 0;         // [8,1024,768]
  float* xkv  = ws + 6291456;
  float* t1   = ws + 12582912;
  float* t2   = ws + 14155776;
  float* varb = ws + 15204352;
  float* zq   = ws + 15728640;
  float* zkv  = ws + 16252928;
  float* up_t = ws + 16777216;
  float* mid  = ws + 18874368;
  float* qzf  = ws + 23068672;
  float* kzf  = ws + 26214400;
  float* qrf  = ws + 29360128;
  float* krf  = ws + 32505856;
  float* vzf  = ws + 35651584;  // high water 41943040 floats
  float* tkr  = ws + 0;
  float* qp   = ws + 0;
  float* kp   = ws + 6291456;
  float* vp   = ws + 12582912;
  float* of   = ws + 18874368;  // fp32 attn out, dead after out_w GEMM
  float* xb   = ws + 25165824;
  float* yl   = ws + 31457280;
  // bf16 regions (ushort), overlaying dead fp32 (offsets in float slots):
  ushort* outw_b = (ushort*)(ws + 0);         // 768*768
  ushort* of_b   = (ushort*)(ws + 524288);    // 8192*768
  ushort* w1_b   = (ushort*)(ws + 4194304);   // 3072*768
  ushort* w2_b   = (ushort*)(ws + 5505024);   // 768*3072
  ushort* yl_b   = (ushort*)(ws + 6815744);   // 8192*768
  ushort* hm_b   = (ushort*)(ws + 10485760);  // 8192*3072 (ends 16777216; 'of' dead then)

  auto launch_abT = [&](const float* A, const float* Bm, float* C, int M, int N, int K) {
    dim3 g(N / 64, M / 64);
    gemm_abT<0><<<g, 256, 0, stream>>>(A, Bm, nullptr, C, M, N, K);
  };
  auto launch_wx = [&](const float* W, const float* X, float* C, int M, int N, int K,
                       long sx, long sc) {
    dim3 g(N / 64, M / 64, B_);
    gemm_wx<<<g, 256, 0, stream>>>(W, X, C, M, N, K, sx, sc);
  };
  auto conv = [&](const float* x, ushort* y, long n) {
    int n4 = (int)(n / 4);
    f2b_kern<<<(n4 + 255) / 256, 256, 0, stream>>>(x, y, n4);
  };

  // 1) dual LN
  ln_dual<<<B_ * S_, 256, 0, stream>>>(input_q, ln_q_w, ln_kv_w, xq, xkv, D1_);

  // 2) VAE chains + reparam
  launch_wx(Wt_mq, xq, t1, SR_, D1_, S_, (long)S_ * D1_, (long)SR_ * D1_);
  launch_abT(t1, mq_w1, t2, B_ * SR_, D2_, D1_);
  launch_abT(t2, mq_w2, zq, B_ * SR_, MVH_, D2_);
  launch_wx(Wt_vq, xq, t1, SR_, D1_, S_, (long)S_ * D1_, (long)SR_ * D1_);
  launch_abT(t1, vq_w1, t2, B_ * SR_, D2_, D1_);
  launch_abT(t2, vq_w2, varb, B_ * SR_, MVH_, D2_);
  z_combine<<<(B_ * SR_ * MVH_) / 256, 256, 0, stream>>>(zq, varb, eps_zq, dirty_zq,
                                                         e2de, B_ * SR_ * MVH_, SR_ * MVH_);
  launch_wx(Wt_mkv, xkv, t1, SR_, D1_, S_, (long)S_ * D1_, (long)SR_ * D1_);
  launch_abT(t1, mkv_w1, t2, B_ * SR_, D2_, D1_);
  launch_abT(t2, mkv_w2, zkv, B_ * SR_, MVH_, D2_);
  launch_wx(Wt_vkv, xkv, t1, SR_, D1_, S_, (long)S_ * D1_, (long)SR_ * D1_);
  launch_abT(t1, vkv_w1, t2, B_ * SR_, D2_, D1_);
  launch_abT(t2, vkv_w2, varb, B_ * SR_, MVH_, D2_);
  z_combine<<<(B_ * SR_ * MVH_) / 256, 256, 0, stream>>>(zkv, varb, eps_zkv, dirty_zkv,
                                                         e2de, B_ * SR_ * MVH_, SR_ * MVH_);

  // 3) upsample chains
  launch_wx(Wt_qzu, zq, up_t, SN_, MVH_, SR_, (long)SR_ * MVH_, (long)SN_ * MVH_);
  launch_abT(up_t, qz_up, mid, B_ * SN_, D2_, MVH_);
  launch_abT(mid, q_w, qzf, B_ * SN_, H_ * 32, D2_);
  launch_wx(Wt_kzu, zkv, up_t, SN_, MVH_, SR_, (long)SR_ * MVH_, (long)SN_ * MVH_);
  launch_abT(up_t, kz_up, mid, B_ * SN_, D2_, MVH_);
  launch_abT(mid, k_w, kzf, B_ * SN_, H_ * 32, D2_);
  launch_wx(Wt_vzu, zkv, up_t, SN_, MVH_, SR_, (long)SR_ * MVH_, (long)SN_ * MVH_);
  launch_abT(up_t, vz_up, mid, B_ * SN_, D2_, MVH_);
  launch_abT(mid, v_w, vzf, B_ * SN_, D3_, D2_);
  launch_wx(Wt_qr, zq, up_t, SN_, MVH_, SR_, (long)SR_ * MVH_, (long)SN_ * MVH_);
  launch_abT(up_t, qr_w, qrf, B_ * SN_, H_ * 32, MVH_);
  launch_wx(Wt_kr, input_q, tkr, SN_, D1_, S_, (long)S_ * D1_, (long)SN_ * D1_);
  launch_abT(tkr, kr_w, krf, B_ * SN_, H_ * 32, D1_);

  // 4) pack heads (+RoPE)
  int tot = B_ * H_ * S_ * HD_;
  pack_qk<<<tot / 256, 256, 0, stream>>>(qzf, qrf, rope_q_f, qp, 0.125f);
  pack_qk<<<tot / 256, 256, 0, stream>>>(kzf, krf, rope_k_f, kp, 1.0f);
  pack_v<<<tot / 256, 256, 0, stream>>>(vzf, vp);

  // 5) attention
  {
    dim3 g(S_ / 64, B_ * H_);
    attn_tile<<<g, 256, 0, stream>>>(qp, kp, vp, of);
  }

  // 6) epilogue: bf16 MFMA path
  conv(of, of_b, (long)B_ * SN_ * D3_);
  conv(out_w, outw_b, (long)D3_ * D3_);
  {
    dim3 g(D3_ / 128, (B_ * SN_) / 128);
    gemm_bf16<1><<<g, 256, 0, stream>>>(of_b, outw_b, input_q, xb, B_ * SN_, D3_, D3_);
  }
  ln_dual<<<B_ * SN_, 256, 0, stream>>>(xb, ln2_w, nullptr, yl, nullptr, D3_);
  conv(yl, yl_b, (long)B_ * SN_ * D3_);
  conv(mlp_w1, w1_b, (long)MLP_ * D3_);
  {
    dim3 g(MLP_ / 128, (B_ * SN_) / 128);
    gemm_bf16<2><<<g, 256, 0, stream>>>(yl_b, w1_b, nullptr, hm_b, B_ * SN_, MLP_, D3_);
  }
  conv(mlp_w2, w2_b, (long)D3_ * MLP_);
  {
    dim3 g(D3_ / 128, (B_ * SN_) / 128);
    gemm_bf16<1><<<g, 256, 0, stream>>>(hm_b, w2_b, xb, (float*)d_out, B_ * SN_, D3_, MLP_);
  }
}

// Round 6
// 1370.277 us; speedup vs baseline: 4.2512x; 1.4630x over previous
//
#include <hip/hip_runtime.h>
#include <math.h>

#define B_   8
#define S_   1024
#define SR_  256
#define SN_  1024
#define D1_  768
#define D2_  512
#define D3_  768
#define MVH_ 256
#define H_   12
#define HD_  64
#define MLP_ 3072

typedef __attribute__((ext_vector_type(8))) short bf16x8;
typedef __attribute__((ext_vector_type(4))) float f32x4;

__device__ inline ushort f2bf(float f) {
  uint u = __float_as_uint(f);
  uint r = (u + 0x7fffu + ((u >> 16) & 1u)) >> 16;
  return (ushort)r;
}
__device__ inline float b2f(ushort u) { return __uint_as_float(((uint)u) << 16); }

// ---------------- LayerNorm (optionally dual output) ----------------
__global__ __launch_bounds__(256) void ln_dual(const float* __restrict__ x,
    const float* __restrict__ w1, const float* __restrict__ w2,
    float* __restrict__ o1, float* __restrict__ o2, int D) {
  int row = blockIdx.x;
  const float* xr = x + (size_t)row * D;
  int tid = threadIdx.x;
  float s = 0.f, ss = 0.f;
  for (int i = tid; i < D; i += 256) { float v = xr[i]; s += v; ss += v * v; }
  __shared__ float rs[256];
  __shared__ float rq[256];
  rs[tid] = s; rq[tid] = ss;
  __syncthreads();
  for (int off = 128; off > 0; off >>= 1) {
    if (tid < off) { rs[tid] += rs[tid + off]; rq[tid] += rq[tid + off]; }
    __syncthreads();
  }
  float mu  = rs[0] / (float)D;
  float var = rq[0] / (float)D - mu * mu;
  float inv = rsqrtf(var + 1e-6f);
  for (int i = tid; i < D; i += 256) {
    float v = (xr[i] - mu) * inv;
    o1[(size_t)row * D + i] = v * w1[i];
    if (o2) o2[(size_t)row * D + i] = v * w2[i];
  }
}

// ---------------- transpose fp32 -> bf16: out[b][C][R] = in[b][R][C] ----------------
__global__ __launch_bounds__(256) void trans_f2b(const float* __restrict__ in,
    ushort* __restrict__ out, int R, int C, long strideEl) {
  __shared__ float tile[32][33];
  int bb = blockIdx.z;
  const float* ib = in + (size_t)bb * strideEl;
  ushort* ob = out + (size_t)bb * strideEl;
  int c0 = blockIdx.x << 5, r0 = blockIdx.y << 5;
  int tx = threadIdx.x & 31, ty = threadIdx.x >> 5;  // ty 0..7
#pragma unroll
  for (int i = 0; i < 4; ++i)
    tile[ty + 8 * i][tx] = ib[(size_t)(r0 + ty + 8 * i) * C + c0 + tx];
  __syncthreads();
#pragma unroll
  for (int i = 0; i < 4; ++i)
    ob[(size_t)(c0 + ty + 8 * i) * R + r0 + tx] = f2bf(tile[tx][ty + 8 * i]);
}

// ---------------- transpose bf16 -> bf16 ----------------
__global__ __launch_bounds__(256) void trans_b2b(const ushort* __restrict__ in,
    ushort* __restrict__ out, int R, int C, long strideEl) {
  __shared__ ushort tile[32][33];
  int bb = blockIdx.z;
  const ushort* ib = in + (size_t)bb * strideEl;
  ushort* ob = out + (size_t)bb * strideEl;
  int c0 = blockIdx.x << 5, r0 = blockIdx.y << 5;
  int tx = threadIdx.x & 31, ty = threadIdx.x >> 5;
#pragma unroll
  for (int i = 0; i < 4; ++i)
    tile[ty + 8 * i][tx] = ib[(size_t)(r0 + ty + 8 * i) * C + c0 + tx];
  __syncthreads();
#pragma unroll
  for (int i = 0; i < 4; ++i)
    ob[(size_t)(c0 + ty + 8 * i) * R + r0 + tx] = tile[tx][ty + 8 * i];
}

// ---------------- multi-tensor fp32 -> bf16 weight conversion ----------------
struct ConvTab {
  const float* src[28];
  int off[28];   // element offset in wb
  int cum[29];   // cumulative float4 counts
};
__global__ __launch_bounds__(256) void multi_f2b(ConvTab t, ushort* __restrict__ wb,
                                                 int total4) {
  int i = blockIdx.x * 256 + threadIdx.x;
  if (i >= total4) return;
  int ti = 0;
  while (t.cum[ti + 1] <= i) ++ti;
  int j = i - t.cum[ti];
  float4 v = ((const float4*)t.src[ti])[j];
  ushort4 o;
  o.x = f2bf(v.x); o.y = f2bf(v.y); o.z = f2bf(v.z); o.w = f2bf(v.w);
  ((ushort4*)(wb + t.off[ti]))[j] = o;
}

// ---------------- fp32 -> bf16 (flat) ----------------
__global__ __launch_bounds__(256) void f2b_kern(const float* __restrict__ x,
    ushort* __restrict__ y, int n4) {
  int i = blockIdx.x * 256 + threadIdx.x;
  if (i >= n4) return;
  float4 v = ((const float4*)x)[i];
  ushort4 o;
  o.x = f2bf(v.x); o.y = f2bf(v.y); o.z = f2bf(v.z); o.w = f2bf(v.w);
  ((ushort4*)y)[i] = o;
}

// ---------------- bf16 MFMA GEMM (batched, strided): C_b = A_b @ B_b^T ----------------
// EPI: 0 = bf16 out, 1 = fp32 out + R, 2 = gelu bf16 out
template <int EPI>
__global__ __launch_bounds__(256) void gemm_bf16(const ushort* __restrict__ A, long sA,
    const ushort* __restrict__ Bm, long sB, const float* __restrict__ R,
    void* __restrict__ Cout, long sC, int M, int N, int K) {
  int bb = blockIdx.z;
  const ushort* Ab = A + (size_t)bb * sA;
  const ushort* Bb = Bm + (size_t)bb * sB;
  __shared__ ushort As[128 * 32];
  __shared__ ushort Bs[128 * 32];
  int tid = threadIdx.x;
  int lane = tid & 63, wid = tid >> 6;
  int m0 = blockIdx.y << 7, n0 = blockIdx.x << 7;
  int wm = (wid >> 1) << 6, wn = (wid & 1) << 6;
  f32x4 acc[4][4];
#pragma unroll
  for (int i = 0; i < 4; ++i)
#pragma unroll
    for (int j = 0; j < 4; ++j) acc[i][j] = (f32x4){0.f, 0.f, 0.f, 0.f};
  int r0 = tid >> 2, kof = (tid & 3) << 3;
  for (int k0 = 0; k0 < K; k0 += 32) {
    __syncthreads();
    uint4 a0 = *(const uint4*)&Ab[(size_t)(m0 + r0) * K + k0 + kof];
    uint4 a1 = *(const uint4*)&Ab[(size_t)(m0 + 64 + r0) * K + k0 + kof];
    uint4 b0 = *(const uint4*)&Bb[(size_t)(n0 + r0) * K + k0 + kof];
    uint4 b1 = *(const uint4*)&Bb[(size_t)(n0 + 64 + r0) * K + k0 + kof];
    *(uint4*)&As[r0 * 32 + kof] = a0;
    *(uint4*)&As[(64 + r0) * 32 + kof] = a1;
    *(uint4*)&Bs[r0 * 32 + kof] = b0;
    *(uint4*)&Bs[(64 + r0) * 32 + kof] = b1;
    __syncthreads();
    bf16x8 af[4], bf[4];
#pragma unroll
    for (int m = 0; m < 4; ++m)
      af[m] = *(bf16x8*)&As[(wm + m * 16 + (lane & 15)) * 32 + ((lane >> 4) << 3)];
#pragma unroll
    for (int n = 0; n < 4; ++n)
      bf[n] = *(bf16x8*)&Bs[(wn + n * 16 + (lane & 15)) * 32 + ((lane >> 4) << 3)];
#pragma unroll
    for (int m = 0; m < 4; ++m)
#pragma unroll
      for (int n = 0; n < 4; ++n)
        acc[m][n] = __builtin_amdgcn_mfma_f32_16x16x32_bf16(af[m], bf[n], acc[m][n], 0, 0, 0);
  }
  int cr = (lane >> 4) << 2, cc = lane & 15;
#pragma unroll
  for (int m = 0; m < 4; ++m)
#pragma unroll
    for (int n = 0; n < 4; ++n) {
#pragma unroll
      for (int r = 0; r < 4; ++r) {
        int row = m0 + wm + m * 16 + cr + r;
        int col = n0 + wn + n * 16 + cc;
        float v = acc[m][n][r];
        if (EPI == 0) {
          ((ushort*)Cout)[(size_t)bb * sC + (size_t)row * N + col] = f2bf(v);
        } else if (EPI == 1) {
          ((float*)Cout)[(size_t)row * N + col] = v + R[(size_t)row * N + col];
        } else {
          v = 0.5f * v * (1.0f + erff(v * 0.70710678118654752f));
          ((ushort*)Cout)[(size_t)row * N + col] = f2bf(v);
        }
      }
    }
}

// ---------------- reparameterization (bf16 in/out) ----------------
__global__ __launch_bounds__(256) void z_combine_b(const ushort* __restrict__ mean,
    const ushort* __restrict__ var, const float* __restrict__ eps,
    const float* __restrict__ dirty, const float* __restrict__ e2de_p,
    ushort* __restrict__ zout, int total, int perBatch) {
  int i = blockIdx.x * 256 + threadIdx.x;
  if (i >= total) return;
  float e = e2de_p[0];
  float v = b2f(mean[i]) +
            (e * eps[i] + (1.0f - e) * dirty[i % perBatch]) * expf(0.5f * b2f(var[i]));
  zout[i] = f2bf(v);
}

// ---------------- head pack + RoPE (bf16 in, fp32 out) ----------------
__global__ __launch_bounds__(256) void pack_qk(const ushort* __restrict__ zf,
    const ushort* __restrict__ rf, const float* __restrict__ freqs,
    float* __restrict__ out, float scale) {
  int i = blockIdx.x * 256 + threadIdx.x;  // i = ((b*H+h)*S + s)*64 + d
  int d = i & 63;
  int s = (i >> 6) & (S_ - 1);
  int bh = i >> 16;
  int b = bh / H_, h = bh % H_;
  float v;
  if (d < 32) {
    v = b2f(zf[((size_t)(b * S_ + s)) * (H_ * 32) + h * 32 + d]);
  } else {
    int dr = d - 32;
    const ushort* xr = rf + ((size_t)(b * S_ + s)) * (H_ * 32) + h * 32;
    float f = freqs[s * 16 + (dr & 15)];
    float c = cosf(f), sn = sinf(f);
    if (dr < 16) v = b2f(xr[dr]) * c - b2f(xr[dr + 16]) * sn;
    else         v = b2f(xr[dr]) * c + b2f(xr[dr - 16]) * sn;
  }
  out[i] = v * scale;
}

__global__ __launch_bounds__(256) void pack_v(const ushort* __restrict__ vzf,
    float* __restrict__ out) {
  int i = blockIdx.x * 256 + threadIdx.x;
  int d = i & 63;
  int s = (i >> 6) & (S_ - 1);
  int bh = i >> 16;
  int b = bh / H_, h = bh % H_;
  out[i] = b2f(vzf[((size_t)(b * S_ + s)) * D3_ + h * 64 + d]);
}

// ---------------- tiled flash attention ----------------
__global__ __launch_bounds__(256) void attn_tile(const float* __restrict__ Q,
    const float* __restrict__ K, const float* __restrict__ V,
    float* __restrict__ O) {
  __shared__ float Qt[64][65];  // Qt[d][r]
  __shared__ float Kt[64][65];  // Kt[d][c]
  __shared__ float Vt[64][65];  // Vt[d][c]  (transposed: scalar writes, 2-way free)
  __shared__ float Ps[64][68];  // Ps[q-row][key]
  int tid = threadIdx.x;
  int tx = tid & 15, ty = tid >> 4;
  int bh = blockIdx.y;
  int q0 = blockIdx.x << 6;
  const float* Qb = Q + (size_t)bh * S_ * HD_;
  const float* Kb = K + (size_t)bh * S_ * HD_;
  const float* Vb = V + (size_t)bh * S_ * HD_;
  {
    int r = tid >> 4;
    int d0 = (tid & 15) << 2;
#pragma unroll
    for (int p = 0; p < 4; ++p) {
      int row = p * 16 + r;
      float4 v = *(const float4*)&Qb[(size_t)(q0 + row) * HD_ + d0];
      Qt[d0 + 0][row] = v.x; Qt[d0 + 1][row] = v.y;
      Qt[d0 + 2][row] = v.z; Qt[d0 + 3][row] = v.w;
    }
  }
  float m[4], l[4], o[4][4];
#pragma unroll
  for (int i = 0; i < 4; ++i) {
    m[i] = -1e30f; l[i] = 0.f;
#pragma unroll
    for (int j = 0; j < 4; ++j) o[i][j] = 0.f;
  }
  for (int k0 = 0; k0 < S_; k0 += 64) {
    __syncthreads();
    {
      int r = tid >> 4;
      int d0 = (tid & 15) << 2;
#pragma unroll
      for (int p = 0; p < 4; ++p) {
        int row = p * 16 + r;
        float4 kv = *(const float4*)&Kb[(size_t)(k0 + row) * HD_ + d0];
        float4 vv = *(const float4*)&Vb[(size_t)(k0 + row) * HD_ + d0];
        Kt[d0 + 0][row] = kv.x; Kt[d0 + 1][row] = kv.y;
        Kt[d0 + 2][row] = kv.z; Kt[d0 + 3][row] = kv.w;
        Vt[d0 + 0][row] = vv.x; Vt[d0 + 1][row] = vv.y;
        Vt[d0 + 2][row] = vv.z; Vt[d0 + 3][row] = vv.w;
      }
    }
    __syncthreads();
    float s[4][4] = {};
#pragma unroll
    for (int d = 0; d < 64; ++d) {
      float a[4], bv[4];
#pragma unroll
      for (int i = 0; i < 4; ++i) a[i] = Qt[d][ty * 4 + i];
#pragma unroll
      for (int j = 0; j < 4; ++j) bv[j] = Kt[d][tx * 4 + j];
#pragma unroll
      for (int i = 0; i < 4; ++i)
#pragma unroll
        for (int j = 0; j < 4; ++j) s[i][j] = fmaf(a[i], bv[j], s[i][j]);
    }
#pragma unroll
    for (int i = 0; i < 4; ++i) {
      float cm = fmaxf(fmaxf(s[i][0], s[i][1]), fmaxf(s[i][2], s[i][3]));
      cm = fmaxf(cm, __shfl_xor(cm, 1));
      cm = fmaxf(cm, __shfl_xor(cm, 2));
      cm = fmaxf(cm, __shfl_xor(cm, 4));
      cm = fmaxf(cm, __shfl_xor(cm, 8));
      float mn = fmaxf(m[i], cm);
      float al = __expf(m[i] - mn);
      float ps = 0.f;
#pragma unroll
      for (int j = 0; j < 4; ++j) { s[i][j] = __expf(s[i][j] - mn); ps += s[i][j]; }
      ps += __shfl_xor(ps, 1);
      ps += __shfl_xor(ps, 2);
      ps += __shfl_xor(ps, 4);
      ps += __shfl_xor(ps, 8);
      l[i] = l[i] * al + ps;
      m[i] = mn;
#pragma unroll
      for (int j = 0; j < 4; ++j) o[i][j] *= al;
    }
#pragma unroll
    for (int i = 0; i < 4; ++i) {
      float4 pv = make_float4(s[i][0], s[i][1], s[i][2], s[i][3]);
      *(float4*)&Ps[ty * 4 + i][tx * 4] = pv;
    }
    __syncthreads();
#pragma unroll
    for (int c = 0; c < 64; ++c) {
      float a[4], bv[4];
#pragma unroll
      for (int i = 0; i < 4; ++i) a[i] = Ps[ty * 4 + i][c];
#pragma unroll
      for (int j = 0; j < 4; ++j) bv[j] = Vt[tx * 4 + j][c];
#pragma unroll
      for (int i = 0; i < 4; ++i)
#pragma unroll
        for (int j = 0; j < 4; ++j) o[i][j] = fmaf(a[i], bv[j], o[i][j]);
    }
  }
  int b = bh / H_, h = bh % H_;
#pragma unroll
  for (int i = 0; i < 4; ++i) {
    float inv = 1.f / l[i];
    int row = q0 + ty * 4 + i;
#pragma unroll
    for (int j = 0; j < 4; ++j)
      O[((size_t)(b * S_ + row)) * D3_ + h * HD_ + tx * 4 + j] = o[i][j] * inv;
  }
}

// ---------------- host ----------------
extern "C" void kernel_launch(void* const* d_in, const int* in_sizes, int n_in,
                              void* d_out, int out_size, void* d_ws, size_t ws_size,
                              hipStream_t stream) {
  const float* input_q = (const float*)d_in[0];
  const float* ln_q_w  = (const float*)d_in[1];
  const float* ln_kv_w = (const float*)d_in[2];
  const float* e2de    = (const float*)d_in[17];
  const float* rope_q_f = (const float*)d_in[31];
  const float* rope_k_f = (const float*)d_in[32];
  const float* ln2_w   = (const float*)d_in[34];
  const float* eps_zq  = (const float*)d_in[37];
  const float* eps_zkv = (const float*)d_in[38];
  const float* dirty_zq  = (const float*)d_in[15];
  const float* dirty_zkv = (const float*)d_in[16];

  float* ws = (float*)d_ws;
  // ---- arena (float-slot offsets) ----
  ushort* wb    = (ushort*)(ws + 0);          // 12124160 el -> 6062080 slots
  float*  xq    = ws + 6062080;               // [8,1024,768]
  float*  xkv   = ws + 12353536;
  ushort* xqT   = (ushort*)(ws + 18644992);   // [8,768,1024]
  ushort* xkvT  = (ushort*)(ws + 21790720);
  ushort* inT   = (ushort*)(ws + 24936448);
  ushort* t1_b  = (ushort*)(ws + 28082176);   // [8,256,768]
  ushort* t2_b  = (ushort*)(ws + 28868608);   // [2048,512]
  ushort* mean_b= (ushort*)(ws + 29392896);   // [2048,256]
  ushort* var_b = (ushort*)(ws + 29655040);
  ushort* zq_b  = (ushort*)(ws + 29917184);
  ushort* zkv_b = (ushort*)(ws + 30179328);
  ushort* zqT   = (ushort*)(ws + 30441472);
  ushort* zkvT  = (ushort*)(ws + 30703616);
  ushort* up_b  = (ushort*)(ws + 6062080);    // [8,1024,256] overlays dead xq
  ushort* mid_b = (ushort*)(ws + 7110656);    // [8192,512]
  ushort* tkr_b = (ushort*)(ws + 9207808);    // [8,1024,768]
  ushort* qzf_b = (ushort*)(ws + 12353536);   // [8192,384] overlays dead xkv
  ushort* kzf_b = (ushort*)(ws + 13926400);
  ushort* qrf_b = (ushort*)(ws + 15499264);
  ushort* krf_b = (ushort*)(ws + 17072128);
  ushort* vzf_b = (ushort*)(ws + 31227904);   // [8192,768]
  float*  qp    = ws + 18644992;              // overlays xqT/xkvT (dead)
  float*  kp    = ws + 24936448;              // overlays inT/t1..zkvT (dead)
  float*  vp    = ws + 12353536;              // overlays qzf..krf (dead after packs)
  float*  of    = ws + 6062080;               // overlays up/mid/tkr (dead)
  float*  xb    = ws + 18644992;              // overlays qp (dead after attn)
  ushort* of_b  = (ushort*)(ws + 24936448);   // overlays kp (dead after attn)
  float*  yl    = ws + 12353536;              // overlays vp (dead after attn)
  ushort* yl_b  = (ushort*)(ws + 28082176);   // overlays t1..zq (dead)
  ushort* hm_b  = (ushort*)(ws + 6062080);    // [8192,3072] overlays of/yl (dead)

  // weight offsets within wb (elements)
  const int W_mq = 0,       W_vq = 262144,  W_mkv = 524288, W_vkv = 786432;
  const int Wq1 = 1048576,  Wv1 = 1441792,  Wk1 = 1835008,  Wkv1 = 2228224;
  const int Wq2 = 2621440,  Wv2 = 2752512,  Wk2 = 2883584,  Wkv2 = 3014656;
  const int W_qzu = 3145728, W_kzu = 3407872, W_vzu = 3670016, W_qr = 3932160;
  const int W_kr = 4194304, W_qzup = 5242880, W_kzup = 5373952, W_vzup = 5505024;
  const int W_qw = 5636096, W_kw = 5832704,  W_vw = 6029312,  W_qrw = 6422528;
  const int W_krw = 6520832, W_ow = 6815744, W_m1 = 7405568,  W_m2 = 9764864;

  auto G0 = [&](const ushort* A, long sA, const ushort* Bm, long sB, ushort* C, long sC,
                int M, int N, int K, int nb) {
    dim3 g(N / 128, M / 128, nb);
    gemm_bf16<0><<<g, 256, 0, stream>>>(A, sA, Bm, sB, nullptr, C, sC, M, N, K);
  };

  // 1) dual LN (fp32 out)
  ln_dual<<<B_ * S_, 256, 0, stream>>>(input_q, ln_q_w, ln_kv_w, xq, xkv, D1_);

  // 2) transposes to bf16 [b, D, S]
  {
    dim3 g(D1_ / 32, S_ / 32, B_);
    trans_f2b<<<g, 256, 0, stream>>>(xq, xqT, S_, D1_, (long)S_ * D1_);
    trans_f2b<<<g, 256, 0, stream>>>(xkv, xkvT, S_, D1_, (long)S_ * D1_);
    trans_f2b<<<g, 256, 0, stream>>>(input_q, inT, S_, D1_, (long)S_ * D1_);
  }

  // 3) weights -> bf16 (single kernel)
  {
    ConvTab t;
    const int srcIdx[28] = {3,4,5,6, 7,9,11,13, 8,10,12,14, 18,19,20,21, 22,
                            23,24,25, 26,27, 28, 29, 30, 33, 35, 36};
    const int sz[28] = {262144,262144,262144,262144, 393216,393216,393216,393216,
                        131072,131072,131072,131072, 262144,262144,262144,262144,
                        1048576, 131072,131072,131072, 196608,196608, 393216,
                        98304, 294912, 589824, 2359296, 2359296};
    int off = 0, c4 = 0;
    for (int i = 0; i < 28; ++i) {
      t.src[i] = (const float*)d_in[srcIdx[i]];
      t.off[i] = off;
      t.cum[i] = c4;
      off += sz[i];
      c4 += sz[i] / 4;
    }
    t.cum[28] = c4;
    multi_f2b<<<(c4 + 255) / 256, 256, 0, stream>>>(t, wb, c4);
  }

  long sXT = (long)S_ * D1_;     // 786432
  long sT1 = (long)SR_ * D1_;    // 196608
  long sZT = (long)SR_ * MVH_;   // 65536
  long sUP = (long)SN_ * MVH_;   // 262144
  long sTK = (long)SN_ * D1_;    // 786432

  // 4) VAE q
  G0(wb + W_mq, 0, xqT, sXT, t1_b, sT1, SR_, D1_, S_, B_);
  G0(t1_b, 0, wb + Wq1, 0, t2_b, 0, B_ * SR_, D2_, D1_, 1);
  G0(t2_b, 0, wb + Wq2, 0, mean_b, 0, B_ * SR_, MVH_, D2_, 1);
  G0(wb + W_vq, 0, xqT, sXT, t1_b, sT1, SR_, D1_, S_, B_);
  G0(t1_b, 0, wb + Wv1, 0, t2_b, 0, B_ * SR_, D2_, D1_, 1);
  G0(t2_b, 0, wb + Wv2, 0, var_b, 0, B_ * SR_, MVH_, D2_, 1);
  z_combine_b<<<(B_ * SR_ * MVH_) / 256, 256, 0, stream>>>(mean_b, var_b, eps_zq,
      dirty_zq, e2de, zq_b, B_ * SR_ * MVH_, SR_ * MVH_);
  // VAE kv
  G0(wb + W_mkv, 0, xkvT, sXT, t1_b, sT1, SR_, D1_, S_, B_);
  G0(t1_b, 0, wb + Wk1, 0, t2_b, 0, B_ * SR_, D2_, D1_, 1);
  G0(t2_b, 0, wb + Wk2, 0, mean_b, 0, B_ * SR_, MVH_, D2_, 1);
  G0(wb + W_vkv, 0, xkvT, sXT, t1_b, sT1, SR_, D1_, S_, B_);
  G0(t1_b, 0, wb + Wkv1, 0, t2_b, 0, B_ * SR_, D2_, D1_, 1);
  G0(t2_b, 0, wb + Wkv2, 0, var_b, 0, B_ * SR_, MVH_, D2_, 1);
  z_combine_b<<<(B_ * SR_ * MVH_) / 256, 256, 0, stream>>>(mean_b, var_b, eps_zkv,
      dirty_zkv, e2de, zkv_b, B_ * SR_ * MVH_, SR_ * MVH_);

  // 5) z transposes [b,256,256]
  {
    dim3 g(MVH_ / 32, SR_ / 32, B_);
    trans_b2b<<<g, 256, 0, stream>>>(zq_b, zqT, SR_, MVH_, sZT);
    trans_b2b<<<g, 256, 0, stream>>>(zkv_b, zkvT, SR_, MVH_, sZT);
  }

  // 6) upsample chains
  G0(wb + W_qzu, 0, zqT, sZT, up_b, sUP, SN_, MVH_, SR_, B_);
  G0(up_b, 0, wb + W_qzup, 0, mid_b, 0, B_ * SN_, D2_, MVH_, 1);
  G0(mid_b, 0, wb + W_qw, 0, qzf_b, 0, B_ * SN_, H_ * 32, D2_, 1);
  G0(wb + W_kzu, 0, zkvT, sZT, up_b, sUP, SN_, MVH_, SR_, B_);
  G0(up_b, 0, wb + W_kzup, 0, mid_b, 0, B_ * SN_, D2_, MVH_, 1);
  G0(mid_b, 0, wb + W_kw, 0, kzf_b, 0, B_ * SN_, H_ * 32, D2_, 1);
  G0(wb + W_vzu, 0, zkvT, sZT, up_b, sUP, SN_, MVH_, SR_, B_);
  G0(up_b, 0, wb + W_vzup, 0, mid_b, 0, B_ * SN_, D2_, MVH_, 1);
  G0(mid_b, 0, wb + W_vw, 0, vzf_b, 0, B_ * SN_, D3_, D2_, 1);
  G0(wb + W_qr, 0, zqT, sZT, up_b, sUP, SN_, MVH_, SR_, B_);
  G0(up_b, 0, wb + W_qrw, 0, qrf_b, 0, B_ * SN_, H_ * 32, MVH_, 1);
  G0(wb + W_kr, 0, inT, sXT, tkr_b, sTK, SN_, D1_, S_, B_);
  G0(tkr_b, 0, wb + W_krw, 0, krf_b, 0, B_ * SN_, H_ * 32, D1_, 1);

  // 7) pack heads (+RoPE; q pre-scaled)
  int tot = B_ * H_ * S_ * HD_;
  pack_qk<<<tot / 256, 256, 0, stream>>>(qzf_b, qrf_b, rope_q_f, qp, 0.125f);
  pack_qk<<<tot / 256, 256, 0, stream>>>(kzf_b, krf_b, rope_k_f, kp, 1.0f);
  pack_v<<<tot / 256, 256, 0, stream>>>(vzf_b, vp);

  // 8) attention
  {
    dim3 g(S_ / 64, B_ * H_);
    attn_tile<<<g, 256, 0, stream>>>(qp, kp, vp, of);
  }

  // 9) epilogue
  f2b_kern<<<(B_ * SN_ * D3_ / 4 + 255) / 256, 256, 0, stream>>>(of, of_b,
                                                                 B_ * SN_ * D3_ / 4);
  {
    dim3 g(D3_ / 128, (B_ * SN_) / 128);
    gemm_bf16<1><<<g, 256, 0, stream>>>(of_b, 0, wb + W_ow, 0, input_q, xb, 0,
                                        B_ * SN_, D3_, D3_);
  }
  ln_dual<<<B_ * SN_, 256, 0, stream>>>(xb, ln2_w, nullptr, yl, nullptr, D3_);
  f2b_kern<<<(B_ * SN_ * D3_ / 4 + 255) / 256, 256, 0, stream>>>(yl, yl_b,
                                                                 B_ * SN_ * D3_ / 4);
  {
    dim3 g(MLP_ / 128, (B_ * SN_) / 128);
    gemm_bf16<2><<<g, 256, 0, stream>>>(yl_b, 0, wb + W_m1, 0, nullptr, hm_b, 0,
                                        B_ * SN_, MLP_, D3_);
  }
  {
    dim3 g(D3_ / 128, (B_ * SN_) / 128);
    gemm_bf16<1><<<g, 256, 0, stream>>>(hm_b, 0, wb + W_m2, 0, xb, (float*)d_out, 0,
                                        B_ * SN_, D3_, MLP_);
  }
}

// Round 7
// 828.155 us; speedup vs baseline: 7.0342x; 1.6546x over previous
//
#include <hip/hip_runtime.h>
#include <math.h>

#define B_   8
#define S_   1024
#define SR_  256
#define SN_  1024
#define D1_  768
#define D2_  512
#define D3_  768
#define MVH_ 256
#define H_   12
#define HD_  64
#define MLP_ 3072

typedef __attribute__((ext_vector_type(8))) short bf16x8;
typedef __attribute__((ext_vector_type(4))) float f32x4;

__device__ inline ushort f2bf(float f) {
  uint u = __float_as_uint(f);
  uint r = (u + 0x7fffu + ((u >> 16) & 1u)) >> 16;
  return (ushort)r;
}
__device__ inline float b2f(ushort u) { return __uint_as_float(((uint)u) << 16); }

// ---------------- LayerNorm (optionally dual output) ----------------
__global__ __launch_bounds__(256) void ln_dual(const float* __restrict__ x,
    const float* __restrict__ w1, const float* __restrict__ w2,
    float* __restrict__ o1, float* __restrict__ o2, int D) {
  int row = blockIdx.x;
  const float* xr = x + (size_t)row * D;
  int tid = threadIdx.x;
  float s = 0.f, ss = 0.f;
  for (int i = tid; i < D; i += 256) { float v = xr[i]; s += v; ss += v * v; }
  __shared__ float rs[256];
  __shared__ float rq[256];
  rs[tid] = s; rq[tid] = ss;
  __syncthreads();
  for (int off = 128; off > 0; off >>= 1) {
    if (tid < off) { rs[tid] += rs[tid + off]; rq[tid] += rq[tid + off]; }
    __syncthreads();
  }
  float mu  = rs[0] / (float)D;
  float var = rq[0] / (float)D - mu * mu;
  float inv = rsqrtf(var + 1e-6f);
  for (int i = tid; i < D; i += 256) {
    float v = (xr[i] - mu) * inv;
    o1[(size_t)row * D + i] = v * w1[i];
    if (o2) o2[(size_t)row * D + i] = v * w2[i];
  }
}

// ---------------- transpose fp32 -> bf16: out[b][C][R] = in[b][R][C] ----------------
__global__ __launch_bounds__(256) void trans_f2b(const float* __restrict__ in,
    ushort* __restrict__ out, int R, int C, long strideEl) {
  __shared__ float tile[32][33];
  int bb = blockIdx.z;
  const float* ib = in + (size_t)bb * strideEl;
  ushort* ob = out + (size_t)bb * strideEl;
  int c0 = blockIdx.x << 5, r0 = blockIdx.y << 5;
  int tx = threadIdx.x & 31, ty = threadIdx.x >> 5;  // ty 0..7
#pragma unroll
  for (int i = 0; i < 4; ++i)
    tile[ty + 8 * i][tx] = ib[(size_t)(r0 + ty + 8 * i) * C + c0 + tx];
  __syncthreads();
#pragma unroll
  for (int i = 0; i < 4; ++i)
    ob[(size_t)(c0 + ty + 8 * i) * R + r0 + tx] = f2bf(tile[tx][ty + 8 * i]);
}

// ---------------- transpose bf16 -> bf16 ----------------
__global__ __launch_bounds__(256) void trans_b2b(const ushort* __restrict__ in,
    ushort* __restrict__ out, int R, int C, long strideEl) {
  __shared__ ushort tile[32][33];
  int bb = blockIdx.z;
  const ushort* ib = in + (size_t)bb * strideEl;
  ushort* ob = out + (size_t)bb * strideEl;
  int c0 = blockIdx.x << 5, r0 = blockIdx.y << 5;
  int tx = threadIdx.x & 31, ty = threadIdx.x >> 5;
#pragma unroll
  for (int i = 0; i < 4; ++i)
    tile[ty + 8 * i][tx] = ib[(size_t)(r0 + ty + 8 * i) * C + c0 + tx];
  __syncthreads();
#pragma unroll
  for (int i = 0; i < 4; ++i)
    ob[(size_t)(c0 + ty + 8 * i) * R + r0 + tx] = tile[tx][ty + 8 * i];
}

// ---------------- multi-tensor fp32 -> bf16 weight conversion ----------------
struct ConvTab {
  const float* src[28];
  int off[28];
  int cum[29];
};
__global__ __launch_bounds__(256) void multi_f2b(ConvTab t, ushort* __restrict__ wb,
                                                 int total4) {
  int i = blockIdx.x * 256 + threadIdx.x;
  if (i >= total4) return;
  int ti = 0;
  while (t.cum[ti + 1] <= i) ++ti;
  int j = i - t.cum[ti];
  float4 v = ((const float4*)t.src[ti])[j];
  ushort4 o;
  o.x = f2bf(v.x); o.y = f2bf(v.y); o.z = f2bf(v.z); o.w = f2bf(v.w);
  ((ushort4*)(wb + t.off[ti]))[j] = o;
}

// ---------------- fp32 -> bf16 (flat) ----------------
__global__ __launch_bounds__(256) void f2b_kern(const float* __restrict__ x,
    ushort* __restrict__ y, int n4) {
  int i = blockIdx.x * 256 + threadIdx.x;
  if (i >= n4) return;
  float4 v = ((const float4*)x)[i];
  ushort4 o;
  o.x = f2bf(v.x); o.y = f2bf(v.y); o.z = f2bf(v.z); o.w = f2bf(v.w);
  ((ushort4*)y)[i] = o;
}

// ---------------- bf16 MFMA GEMM (batched, strided): C_b = A_b @ B_b^T ----------------
// EPI: 0 = bf16 out, 1 = fp32 out + R, 2 = gelu bf16 out
template <int EPI>
__global__ __launch_bounds__(256) void gemm_bf16(const ushort* __restrict__ A, long sA,
    const ushort* __restrict__ Bm, long sB, const float* __restrict__ R,
    void* __restrict__ Cout, long sC, int M, int N, int K) {
  int bb = blockIdx.z;
  const ushort* Ab = A + (size_t)bb * sA;
  const ushort* Bb = Bm + (size_t)bb * sB;
  __shared__ ushort As[128 * 32];
  __shared__ ushort Bs[128 * 32];
  int tid = threadIdx.x;
  int lane = tid & 63, wid = tid >> 6;
  int m0 = blockIdx.y << 7, n0 = blockIdx.x << 7;
  int wm = (wid >> 1) << 6, wn = (wid & 1) << 6;
  f32x4 acc[4][4];
#pragma unroll
  for (int i = 0; i < 4; ++i)
#pragma unroll
    for (int j = 0; j < 4; ++j) acc[i][j] = (f32x4){0.f, 0.f, 0.f, 0.f};
  int r0 = tid >> 2, kof = (tid & 3) << 3;
  for (int k0 = 0; k0 < K; k0 += 32) {
    __syncthreads();
    uint4 a0 = *(const uint4*)&Ab[(size_t)(m0 + r0) * K + k0 + kof];
    uint4 a1 = *(const uint4*)&Ab[(size_t)(m0 + 64 + r0) * K + k0 + kof];
    uint4 b0 = *(const uint4*)&Bb[(size_t)(n0 + r0) * K + k0 + kof];
    uint4 b1 = *(const uint4*)&Bb[(size_t)(n0 + 64 + r0) * K + k0 + kof];
    *(uint4*)&As[r0 * 32 + kof] = a0;
    *(uint4*)&As[(64 + r0) * 32 + kof] = a1;
    *(uint4*)&Bs[r0 * 32 + kof] = b0;
    *(uint4*)&Bs[(64 + r0) * 32 + kof] = b1;
    __syncthreads();
    bf16x8 af[4], bf[4];
#pragma unroll
    for (int m = 0; m < 4; ++m)
      af[m] = *(bf16x8*)&As[(wm + m * 16 + (lane & 15)) * 32 + ((lane >> 4) << 3)];
#pragma unroll
    for (int n = 0; n < 4; ++n)
      bf[n] = *(bf16x8*)&Bs[(wn + n * 16 + (lane & 15)) * 32 + ((lane >> 4) << 3)];
#pragma unroll
    for (int m = 0; m < 4; ++m)
#pragma unroll
      for (int n = 0; n < 4; ++n)
        acc[m][n] = __builtin_amdgcn_mfma_f32_16x16x32_bf16(af[m], bf[n], acc[m][n], 0, 0, 0);
  }
  int cr = (lane >> 4) << 2, cc = lane & 15;
#pragma unroll
  for (int m = 0; m < 4; ++m)
#pragma unroll
    for (int n = 0; n < 4; ++n) {
#pragma unroll
      for (int r = 0; r < 4; ++r) {
        int row = m0 + wm + m * 16 + cr + r;
        int col = n0 + wn + n * 16 + cc;
        float v = acc[m][n][r];
        if (EPI == 0) {
          ((ushort*)Cout)[(size_t)bb * sC + (size_t)row * N + col] = f2bf(v);
        } else if (EPI == 1) {
          ((float*)Cout)[(size_t)row * N + col] = v + R[(size_t)row * N + col];
        } else {
          v = 0.5f * v * (1.0f + erff(v * 0.70710678118654752f));
          ((ushort*)Cout)[(size_t)row * N + col] = f2bf(v);
        }
      }
    }
}

// ---------------- reparameterization (bf16 in/out) ----------------
__global__ __launch_bounds__(256) void z_combine_b(const ushort* __restrict__ mean,
    const ushort* __restrict__ var, const float* __restrict__ eps,
    const float* __restrict__ dirty, const float* __restrict__ e2de_p,
    ushort* __restrict__ zout, int total, int perBatch) {
  int i = blockIdx.x * 256 + threadIdx.x;
  if (i >= total) return;
  float e = e2de_p[0];
  float v = b2f(mean[i]) +
            (e * eps[i] + (1.0f - e) * dirty[i % perBatch]) * expf(0.5f * b2f(var[i]));
  zout[i] = f2bf(v);
}

// ---------------- head pack + RoPE (bf16 in, bf16 out) ----------------
__global__ __launch_bounds__(256) void pack_qk_b(const ushort* __restrict__ zf,
    const ushort* __restrict__ rf, const float* __restrict__ freqs,
    ushort* __restrict__ out, float scale) {
  int i = blockIdx.x * 256 + threadIdx.x;  // i = ((b*H+h)*S + s)*64 + d
  int d = i & 63;
  int s = (i >> 6) & (S_ - 1);
  int bh = i >> 16;
  int b = bh / H_, h = bh % H_;
  float v;
  if (d < 32) {
    v = b2f(zf[((size_t)(b * S_ + s)) * (H_ * 32) + h * 32 + d]);
  } else {
    int dr = d - 32;
    const ushort* xr = rf + ((size_t)(b * S_ + s)) * (H_ * 32) + h * 32;
    float f = freqs[s * 16 + (dr & 15)];
    float c = cosf(f), sn = sinf(f);
    if (dr < 16) v = b2f(xr[dr]) * c - b2f(xr[dr + 16]) * sn;
    else         v = b2f(xr[dr]) * c + b2f(xr[dr - 16]) * sn;
  }
  out[i] = f2bf(v * scale);
}

__global__ __launch_bounds__(256) void pack_v_b(const ushort* __restrict__ vzf,
    ushort* __restrict__ out) {
  int i = blockIdx.x * 256 + threadIdx.x;
  int d = i & 63;
  int s = (i >> 6) & (S_ - 1);
  int bh = i >> 16;
  int b = bh / H_, h = bh % H_;
  out[i] = vzf[((size_t)(b * S_ + s)) * D3_ + h * 64 + d];
}

// ---------------- MFMA flash attention ----------------
// grid (S/64, B*H), 256 threads = 4 waves; wave w owns q-rows [w*16, w*16+16).
// LDS rows are 128 B, XOR-swizzled: byte_in_row ^= (row&7)<<4.
__global__ __launch_bounds__(256) void attn_mfma(const ushort* __restrict__ Q,
    const ushort* __restrict__ K, const ushort* __restrict__ V,
    ushort* __restrict__ O) {
  __shared__ ushort lds[16384];                 // 32 KB
  char* qc = (char*)lds;                        // Qs [64 q][64 d]
  char* kc = (char*)lds + 8192;                 // Ks [64 key][64 d]
  char* vc = (char*)lds + 16384;                // Vt [64 d][64 key]
  char* pc = (char*)lds + 24576;                // Ps [64 q][64 key]
  int tid = threadIdx.x, lane = tid & 63, wid = tid >> 6;
  int bh = blockIdx.y, q0 = blockIdx.x << 6;
  int b = bh / H_, h = bh % H_;
  const ushort* Qb = Q + ((size_t)bh * S_ + q0) * HD_;
  const ushort* Kb = K + (size_t)bh * S_ * HD_;
  const ushort* Vb = V + (size_t)bh * S_ * HD_;
  // stage Q
  {
    int r = tid >> 2, c0 = (tid & 3) * 32;
    const char* src = (const char*)Qb + r * 128;
    uint4 v0 = *(const uint4*)(src + c0);
    uint4 v1 = *(const uint4*)(src + c0 + 16);
    int sw = (r & 7) << 4;
    *(uint4*)(qc + r * 128 + (c0 ^ sw)) = v0;
    *(uint4*)(qc + r * 128 + ((c0 + 16) ^ sw)) = v1;
  }
  __syncthreads();
  // Q A-frags: row = wave q-row (lane&15), k = (lane>>4)*8 within 32-K chunk
  bf16x8 aq[2];
  {
    int r = wid * 16 + (lane & 15);
    int sw = (r & 7) << 4;
#pragma unroll
    for (int kk = 0; kk < 2; ++kk) {
      int c2 = kk * 64 + ((lane >> 4) << 4);
      aq[kk] = *(bf16x8*)(qc + r * 128 + (c2 ^ sw));
    }
  }
  f32x4 o_[4];
  float m_[4], l_[4];
#pragma unroll
  for (int i = 0; i < 4; ++i) { o_[i] = (f32x4){0.f,0.f,0.f,0.f}; m_[i] = -1e30f; l_[i] = 0.f; }

  for (int kt = 0; kt < S_ / 64; ++kt) {
    __syncthreads();   // prev PV done before restaging
    {  // stage K tile
      int r = tid >> 2, c0 = (tid & 3) * 32;
      const char* src = (const char*)(Kb + (size_t)(kt * 64 + r) * HD_);
      uint4 v0 = *(const uint4*)(src + c0);
      uint4 v1 = *(const uint4*)(src + c0 + 16);
      int sw = (r & 7) << 4;
      *(uint4*)(kc + r * 128 + (c0 ^ sw)) = v0;
      *(uint4*)(kc + r * 128 + ((c0 + 16) ^ sw)) = v1;
    }
    {  // stage V tile transposed: Vt[d][key], paired-key b32 writes
      int kp = tid & 31, g = tid >> 5, d0 = g * 8;
      const ushort* s0 = Vb + (size_t)(kt * 64 + 2 * kp) * HD_ + d0;
      bf16x8 va = *(const bf16x8*)s0;
      bf16x8 vb2 = *(const bf16x8*)(s0 + HD_);
#pragma unroll
      for (int j = 0; j < 8; ++j) {
        int d = d0 + j;
        uint val = (uint)(ushort)va[j] | ((uint)(ushort)vb2[j] << 16);
        *(uint*)(vc + d * 128 + ((kp * 4) ^ ((d & 7) << 4))) = val;
      }
    }
    __syncthreads();
    // QK^T: S[16q][64k] per wave
    f32x4 sacc[4];
#pragma unroll
    for (int ksub = 0; ksub < 4; ++ksub) {
      sacc[ksub] = (f32x4){0.f,0.f,0.f,0.f};
#pragma unroll
      for (int kk = 0; kk < 2; ++kk) {
        int r = ksub * 16 + (lane & 15);
        int c2 = kk * 64 + ((lane >> 4) << 4);
        bf16x8 bk = *(bf16x8*)(kc + r * 128 + (c2 ^ ((r & 7) << 4)));
        sacc[ksub] = __builtin_amdgcn_mfma_f32_16x16x32_bf16(aq[kk], bk, sacc[ksub], 0, 0, 0);
      }
    }
    // online softmax; C-layout row = (lane>>4)*4 + rr
    float p[4][4];
#pragma unroll
    for (int rr = 0; rr < 4; ++rr) {
      float cm = fmaxf(fmaxf(sacc[0][rr], sacc[1][rr]), fmaxf(sacc[2][rr], sacc[3][rr]));
      cm = fmaxf(cm, __shfl_xor(cm, 1));
      cm = fmaxf(cm, __shfl_xor(cm, 2));
      cm = fmaxf(cm, __shfl_xor(cm, 4));
      cm = fmaxf(cm, __shfl_xor(cm, 8));
      float mn = fmaxf(m_[rr], cm);
      float al = __expf(m_[rr] - mn);
      float ps = 0.f;
#pragma unroll
      for (int ksub = 0; ksub < 4; ++ksub) {
        float pv = __expf(sacc[ksub][rr] - mn);
        p[ksub][rr] = pv;
        ps += pv;
      }
      ps += __shfl_xor(ps, 1);
      ps += __shfl_xor(ps, 2);
      ps += __shfl_xor(ps, 4);
      ps += __shfl_xor(ps, 8);
      l_[rr] = l_[rr] * al + ps;
      m_[rr] = mn;
#pragma unroll
      for (int ds = 0; ds < 4; ++ds) o_[ds][rr] *= al;
    }
    // write P (bf16) to wave-private LDS rows
#pragma unroll
    for (int ksub = 0; ksub < 4; ++ksub)
#pragma unroll
      for (int rr = 0; rr < 4; ++rr) {
        int r = wid * 16 + ((lane >> 4) << 2) + rr;
        int cb = (ksub * 16 + (lane & 15)) * 2;
        *(ushort*)(pc + r * 128 + (cb ^ ((r & 7) << 4))) = f2bf(p[ksub][rr]);
      }
    // PV: O[16q][64d] += P @ V
#pragma unroll
    for (int kk2 = 0; kk2 < 2; ++kk2) {
      int rA = wid * 16 + (lane & 15);
      int c2 = kk2 * 64 + ((lane >> 4) << 4);
      bf16x8 ap = *(bf16x8*)(pc + rA * 128 + (c2 ^ ((rA & 7) << 4)));
#pragma unroll
      for (int ds = 0; ds < 4; ++ds) {
        int rB = ds * 16 + (lane & 15);
        bf16x8 bv = *(bf16x8*)(vc + rB * 128 + (c2 ^ ((rB & 7) << 4)));
        o_[ds] = __builtin_amdgcn_mfma_f32_16x16x32_bf16(ap, bv, o_[ds], 0, 0, 0);
      }
    }
  }
  // epilogue: O already per-row; divide by l, write bf16
#pragma unroll
  for (int rr = 0; rr < 4; ++rr) {
    float inv = 1.f / l_[rr];
    int q = q0 + wid * 16 + ((lane >> 4) << 2) + rr;
#pragma unroll
    for (int ds = 0; ds < 4; ++ds) {
      int d = ds * 16 + (lane & 15);
      O[((size_t)(b * S_ + q)) * D3_ + h * HD_ + d] = f2bf(o_[ds][rr] * inv);
    }
  }
}

// ---------------- host ----------------
extern "C" void kernel_launch(void* const* d_in, const int* in_sizes, int n_in,
                              void* d_out, int out_size, void* d_ws, size_t ws_size,
                              hipStream_t stream) {
  const float* input_q = (const float*)d_in[0];
  const float* ln_q_w  = (const float*)d_in[1];
  const float* ln_kv_w = (const float*)d_in[2];
  const float* e2de    = (const float*)d_in[17];
  const float* rope_q_f = (const float*)d_in[31];
  const float* rope_k_f = (const float*)d_in[32];
  const float* ln2_w   = (const float*)d_in[34];
  const float* eps_zq  = (const float*)d_in[37];
  const float* eps_zkv = (const float*)d_in[38];
  const float* dirty_zq  = (const float*)d_in[15];
  const float* dirty_zkv = (const float*)d_in[16];

  float* ws = (float*)d_ws;
  // ---- arena (float-slot offsets) ----
  ushort* wb    = (ushort*)(ws + 0);
  float*  xq    = ws + 6062080;               // [8,1024,768]
  float*  xkv   = ws + 12353536;
  ushort* xqT   = (ushort*)(ws + 18644992);   // [8,768,1024]
  ushort* xkvT  = (ushort*)(ws + 21790720);
  ushort* inT   = (ushort*)(ws + 24936448);
  ushort* t1_b  = (ushort*)(ws + 28082176);   // [8,256,768]
  ushort* t2_b  = (ushort*)(ws + 28868608);   // [2048,512]
  ushort* mean_b= (ushort*)(ws + 29392896);   // [2048,256]
  ushort* var_b = (ushort*)(ws + 29655040);
  ushort* zq_b  = (ushort*)(ws + 29917184);
  ushort* zkv_b = (ushort*)(ws + 30179328);
  ushort* zqT   = (ushort*)(ws + 30441472);
  ushort* zkvT  = (ushort*)(ws + 30703616);
  ushort* up_b  = (ushort*)(ws + 6062080);    // overlays dead xq
  ushort* mid_b = (ushort*)(ws + 7110656);
  ushort* tkr_b = (ushort*)(ws + 9207808);
  ushort* qzf_b = (ushort*)(ws + 12353536);   // overlays dead xkv
  ushort* kzf_b = (ushort*)(ws + 13926400);
  ushort* qrf_b = (ushort*)(ws + 15499264);
  ushort* krf_b = (ushort*)(ws + 17072128);
  ushort* vzf_b = (ushort*)(ws + 31227904);   // [8192,768]
  ushort* qp_b  = (ushort*)(ws + 18644992);   // [96,1024,64] overlays xqT (dead)
  ushort* kp_b  = (ushort*)(ws + 21790720);   // overlays xkvT (dead)
  ushort* vp_b  = (ushort*)(ws + 24936448);   // overlays inT (dead after step 6)
  ushort* of_b  = (ushort*)(ws + 6062080);    // [8192,768] overlays up/mid/tkr (dead)
  float*  xb    = ws + 18644992;              // overlays qp_b (dead after attn)
  float*  yl    = ws + 12353536;              // overlays qzf..krf (dead after packs)
  ushort* yl_b  = (ushort*)(ws + 28082176);   // overlays t1_b (dead)
  ushort* hm_b  = (ushort*)(ws + 6062080);    // [8192,3072] overlays of_b (dead after out_w)

  // weight offsets within wb (elements)
  const int W_mq = 0,       W_vq = 262144,  W_mkv = 524288, W_vkv = 786432;
  const int Wq1 = 1048576,  Wv1 = 1441792,  Wk1 = 1835008,  Wkv1 = 2228224;
  const int Wq2 = 2621440,  Wv2 = 2752512,  Wk2 = 2883584,  Wkv2 = 3014656;
  const int W_qzu = 3145728, W_kzu = 3407872, W_vzu = 3670016, W_qr = 3932160;
  const int W_kr = 4194304, W_qzup = 5242880, W_kzup = 5373952, W_vzup = 5505024;
  const int W_qw = 5636096, W_kw = 5832704,  W_vw = 6029312,  W_qrw = 6422528;
  const int W_krw = 6520832, W_ow = 6815744, W_m1 = 7405568,  W_m2 = 9764864;

  auto G0 = [&](const ushort* A, long sA, const ushort* Bm, long sB, ushort* C, long sC,
                int M, int N, int K, int nb) {
    dim3 g(N / 128, M / 128, nb);
    gemm_bf16<0><<<g, 256, 0, stream>>>(A, sA, Bm, sB, nullptr, C, sC, M, N, K);
  };

  // 1) dual LN (fp32 out)
  ln_dual<<<B_ * S_, 256, 0, stream>>>(input_q, ln_q_w, ln_kv_w, xq, xkv, D1_);

  // 2) transposes to bf16 [b, D, S]
  {
    dim3 g(D1_ / 32, S_ / 32, B_);
    trans_f2b<<<g, 256, 0, stream>>>(xq, xqT, S_, D1_, (long)S_ * D1_);
    trans_f2b<<<g, 256, 0, stream>>>(xkv, xkvT, S_, D1_, (long)S_ * D1_);
    trans_f2b<<<g, 256, 0, stream>>>(input_q, inT, S_, D1_, (long)S_ * D1_);
  }

  // 3) weights -> bf16 (single kernel)
  {
    ConvTab t;
    const int srcIdx[28] = {3,4,5,6, 7,9,11,13, 8,10,12,14, 18,19,20,21, 22,
                            23,24,25, 26,27, 28, 29, 30, 33, 35, 36};
    const int sz[28] = {262144,262144,262144,262144, 393216,393216,393216,393216,
                        131072,131072,131072,131072, 262144,262144,262144,262144,
                        1048576, 131072,131072,131072, 196608,196608, 393216,
                        98304, 294912, 589824, 2359296, 2359296};
    int off = 0, c4 = 0;
    for (int i = 0; i < 28; ++i) {
      t.src[i] = (const float*)d_in[srcIdx[i]];
      t.off[i] = off;
      t.cum[i] = c4;
      off += sz[i];
      c4 += sz[i] / 4;
    }
    t.cum[28] = c4;
    multi_f2b<<<(c4 + 255) / 256, 256, 0, stream>>>(t, wb, c4);
  }

  long sXT = (long)S_ * D1_;
  long sT1 = (long)SR_ * D1_;
  long sZT = (long)SR_ * MVH_;
  long sUP = (long)SN_ * MVH_;
  long sTK = (long)SN_ * D1_;

  // 4) VAE q
  G0(wb + W_mq, 0, xqT, sXT, t1_b, sT1, SR_, D1_, S_, B_);
  G0(t1_b, 0, wb + Wq1, 0, t2_b, 0, B_ * SR_, D2_, D1_, 1);
  G0(t2_b, 0, wb + Wq2, 0, mean_b, 0, B_ * SR_, MVH_, D2_, 1);
  G0(wb + W_vq, 0, xqT, sXT, t1_b, sT1, SR_, D1_, S_, B_);
  G0(t1_b, 0, wb + Wv1, 0, t2_b, 0, B_ * SR_, D2_, D1_, 1);
  G0(t2_b, 0, wb + Wv2, 0, var_b, 0, B_ * SR_, MVH_, D2_, 1);
  z_combine_b<<<(B_ * SR_ * MVH_) / 256, 256, 0, stream>>>(mean_b, var_b, eps_zq,
      dirty_zq, e2de, zq_b, B_ * SR_ * MVH_, SR_ * MVH_);
  // VAE kv
  G0(wb + W_mkv, 0, xkvT, sXT, t1_b, sT1, SR_, D1_, S_, B_);
  G0(t1_b, 0, wb + Wk1, 0, t2_b, 0, B_ * SR_, D2_, D1_, 1);
  G0(t2_b, 0, wb + Wk2, 0, mean_b, 0, B_ * SR_, MVH_, D2_, 1);
  G0(wb + W_vkv, 0, xkvT, sXT, t1_b, sT1, SR_, D1_, S_, B_);
  G0(t1_b, 0, wb + Wkv1, 0, t2_b, 0, B_ * SR_, D2_, D1_, 1);
  G0(t2_b, 0, wb + Wkv2, 0, var_b, 0, B_ * SR_, MVH_, D2_, 1);
  z_combine_b<<<(B_ * SR_ * MVH_) / 256, 256, 0, stream>>>(mean_b, var_b, eps_zkv,
      dirty_zkv, e2de, zkv_b, B_ * SR_ * MVH_, SR_ * MVH_);

  // 5) z transposes
  {
    dim3 g(MVH_ / 32, SR_ / 32, B_);
    trans_b2b<<<g, 256, 0, stream>>>(zq_b, zqT, SR_, MVH_, sZT);
    trans_b2b<<<g, 256, 0, stream>>>(zkv_b, zkvT, SR_, MVH_, sZT);
  }

  // 6) upsample chains
  G0(wb + W_qzu, 0, zqT, sZT, up_b, sUP, SN_, MVH_, SR_, B_);
  G0(up_b, 0, wb + W_qzup, 0, mid_b, 0, B_ * SN_, D2_, MVH_, 1);
  G0(mid_b, 0, wb + W_qw, 0, qzf_b, 0, B_ * SN_, H_ * 32, D2_, 1);
  G0(wb + W_kzu, 0, zkvT, sZT, up_b, sUP, SN_, MVH_, SR_, B_);
  G0(up_b, 0, wb + W_kzup, 0, mid_b, 0, B_ * SN_, D2_, MVH_, 1);
  G0(mid_b, 0, wb + W_kw, 0, kzf_b, 0, B_ * SN_, H_ * 32, D2_, 1);
  G0(wb + W_vzu, 0, zkvT, sZT, up_b, sUP, SN_, MVH_, SR_, B_);
  G0(up_b, 0, wb + W_vzup, 0, mid_b, 0, B_ * SN_, D2_, MVH_, 1);
  G0(mid_b, 0, wb + W_vw, 0, vzf_b, 0, B_ * SN_, D3_, D2_, 1);
  G0(wb + W_qr, 0, zqT, sZT, up_b, sUP, SN_, MVH_, SR_, B_);
  G0(up_b, 0, wb + W_qrw, 0, qrf_b, 0, B_ * SN_, H_ * 32, MVH_, 1);
  G0(wb + W_kr, 0, inT, sXT, tkr_b, sTK, SN_, D1_, S_, B_);
  G0(tkr_b, 0, wb + W_krw, 0, krf_b, 0, B_ * SN_, H_ * 32, D1_, 1);

  // 7) pack heads (+RoPE; q pre-scaled), bf16 out
  int tot = B_ * H_ * S_ * HD_;
  pack_qk_b<<<tot / 256, 256, 0, stream>>>(qzf_b, qrf_b, rope_q_f, qp_b, 0.125f);
  pack_qk_b<<<tot / 256, 256, 0, stream>>>(kzf_b, krf_b, rope_k_f, kp_b, 1.0f);
  pack_v_b<<<tot / 256, 256, 0, stream>>>(vzf_b, vp_b);

  // 8) attention (bf16 MFMA)
  {
    dim3 g(S_ / 64, B_ * H_);
    attn_mfma<<<g, 256, 0, stream>>>(qp_b, kp_b, vp_b, of_b);
  }

  // 9) epilogue
  {
    dim3 g(D3_ / 128, (B_ * SN_) / 128);
    gemm_bf16<1><<<g, 256, 0, stream>>>(of_b, 0, wb + W_ow, 0, input_q, xb, 0,
                                        B_ * SN_, D3_, D3_);
  }
  ln_dual<<<B_ * SN_, 256, 0, stream>>>(xb, ln2_w, nullptr, yl, nullptr, D3_);
  f2b_kern<<<(B_ * SN_ * D3_ / 4 + 255) / 256, 256, 0, stream>>>(yl, yl_b,
                                                                 B_ * SN_ * D3_ / 4);
  {
    dim3 g(MLP_ / 128, (B_ * SN_) / 128);
    gemm_bf16<2><<<g, 256, 0, stream>>>(yl_b, 0, wb + W_m1, 0, nullptr, hm_b, 0,
                                        B_ * SN_, MLP_, D3_);
  }
  {
    dim3 g(D3_ / 128, (B_ * SN_) / 128);
    gemm_bf16<1><<<g, 256, 0, stream>>>(hm_b, 0, wb + W_m2, 0, xb, (float*)d_out, 0,
                                        B_ * SN_, D3_, MLP_);
  }
}

// Round 8
// 819.911 us; speedup vs baseline: 7.1049x; 1.0101x over previous
//
#include <hip/hip_runtime.h>
#include <math.h>

#define B_   8
#define S_   1024
#define SR_  256
#define SN_  1024
#define D1_  768
#define D2_  512
#define D3_  768
#define MVH_ 256
#define H_   12
#define HD_  64
#define MLP_ 3072

typedef __attribute__((ext_vector_type(8))) short bf16x8;
typedef __attribute__((ext_vector_type(4))) float f32x4;

__device__ inline ushort f2bf(float f) {
  uint u = __float_as_uint(f);
  uint r = (u + 0x7fffu + ((u >> 16) & 1u)) >> 16;
  return (ushort)r;
}
__device__ inline float b2f(ushort u) { return __uint_as_float(((uint)u) << 16); }

__device__ inline void gload16(const void* g, void* l) {
  __builtin_amdgcn_global_load_lds(
      (const __attribute__((address_space(1))) void*)g,
      (__attribute__((address_space(3))) void*)l, 16, 0, 0);
}

// ---------------- LayerNorm (optionally dual output) ----------------
__global__ __launch_bounds__(256) void ln_dual(const float* __restrict__ x,
    const float* __restrict__ w1, const float* __restrict__ w2,
    float* __restrict__ o1, float* __restrict__ o2, int D) {
  int row = blockIdx.x;
  const float* xr = x + (size_t)row * D;
  int tid = threadIdx.x;
  float s = 0.f, ss = 0.f;
  for (int i = tid; i < D; i += 256) { float v = xr[i]; s += v; ss += v * v; }
  __shared__ float rs[256];
  __shared__ float rq[256];
  rs[tid] = s; rq[tid] = ss;
  __syncthreads();
  for (int off = 128; off > 0; off >>= 1) {
    if (tid < off) { rs[tid] += rs[tid + off]; rq[tid] += rq[tid + off]; }
    __syncthreads();
  }
  float mu  = rs[0] / (float)D;
  float var = rq[0] / (float)D - mu * mu;
  float inv = rsqrtf(var + 1e-6f);
  for (int i = tid; i < D; i += 256) {
    float v = (xr[i] - mu) * inv;
    o1[(size_t)row * D + i] = v * w1[i];
    if (o2) o2[(size_t)row * D + i] = v * w2[i];
  }
}

// ---------------- transpose fp32 -> bf16: out[b][C][R] = in[b][R][C] ----------------
__global__ __launch_bounds__(256) void trans_f2b(const float* __restrict__ in,
    ushort* __restrict__ out, int R, int C, long strideEl) {
  __shared__ float tile[32][33];
  int bb = blockIdx.z;
  const float* ib = in + (size_t)bb * strideEl;
  ushort* ob = out + (size_t)bb * strideEl;
  int c0 = blockIdx.x << 5, r0 = blockIdx.y << 5;
  int tx = threadIdx.x & 31, ty = threadIdx.x >> 5;  // ty 0..7
#pragma unroll
  for (int i = 0; i < 4; ++i)
    tile[ty + 8 * i][tx] = ib[(size_t)(r0 + ty + 8 * i) * C + c0 + tx];
  __syncthreads();
#pragma unroll
  for (int i = 0; i < 4; ++i)
    ob[(size_t)(c0 + ty + 8 * i) * R + r0 + tx] = f2bf(tile[tx][ty + 8 * i]);
}

// ---------------- transpose bf16 -> bf16 ----------------
__global__ __launch_bounds__(256) void trans_b2b(const ushort* __restrict__ in,
    ushort* __restrict__ out, int R, int C, long strideEl) {
  __shared__ ushort tile[32][33];
  int bb = blockIdx.z;
  const ushort* ib = in + (size_t)bb * strideEl;
  ushort* ob = out + (size_t)bb * strideEl;
  int c0 = blockIdx.x << 5, r0 = blockIdx.y << 5;
  int tx = threadIdx.x & 31, ty = threadIdx.x >> 5;
#pragma unroll
  for (int i = 0; i < 4; ++i)
    tile[ty + 8 * i][tx] = ib[(size_t)(r0 + ty + 8 * i) * C + c0 + tx];
  __syncthreads();
#pragma unroll
  for (int i = 0; i < 4; ++i)
    ob[(size_t)(c0 + ty + 8 * i) * R + r0 + tx] = tile[tx][ty + 8 * i];
}

// ---------------- multi-tensor fp32 -> bf16 weight conversion ----------------
struct ConvTab {
  const float* src[28];
  int off[28];
  int cum[29];
};
__global__ __launch_bounds__(256) void multi_f2b(ConvTab t, ushort* __restrict__ wb,
                                                 int total4) {
  int i = blockIdx.x * 256 + threadIdx.x;
  if (i >= total4) return;
  int ti = 0;
  while (t.cum[ti + 1] <= i) ++ti;
  int j = i - t.cum[ti];
  float4 v = ((const float4*)t.src[ti])[j];
  ushort4 o;
  o.x = f2bf(v.x); o.y = f2bf(v.y); o.z = f2bf(v.z); o.w = f2bf(v.w);
  ((ushort4*)(wb + t.off[ti]))[j] = o;
}

// ---------------- fp32 -> bf16 (flat) ----------------
__global__ __launch_bounds__(256) void f2b_kern(const float* __restrict__ x,
    ushort* __restrict__ y, int n4) {
  int i = blockIdx.x * 256 + threadIdx.x;
  if (i >= n4) return;
  float4 v = ((const float4*)x)[i];
  ushort4 o;
  o.x = f2bf(v.x); o.y = f2bf(v.y); o.z = f2bf(v.z); o.w = f2bf(v.w);
  ((ushort4*)y)[i] = o;
}

// ---------------- bf16 MFMA GEMM (batched, strided): C_b = A_b @ B_b^T ----------------
// Staging via global_load_lds width=16 (wave-uniform LDS base + lane*16).
// EPI: 0 = bf16 out, 1 = fp32 out + R, 2 = gelu bf16 out
template <int EPI>
__global__ __launch_bounds__(256) void gemm_bf16(const ushort* __restrict__ A, long sA,
    const ushort* __restrict__ Bm, long sB, const float* __restrict__ R,
    void* __restrict__ Cout, long sC, int M, int N, int K) {
  int bb = blockIdx.z;
  const ushort* Ab = A + (size_t)bb * sA;
  const ushort* Bb = Bm + (size_t)bb * sB;
  __shared__ ushort As[128 * 32];
  __shared__ ushort Bs[128 * 32];
  int tid = threadIdx.x;
  int lane = tid & 63, wid = tid >> 6;
  int m0 = blockIdx.y << 7, n0 = blockIdx.x << 7;
  int wm = (wid >> 1) << 6, wn = (wid & 1) << 6;
  f32x4 acc[4][4];
#pragma unroll
  for (int i = 0; i < 4; ++i)
#pragma unroll
    for (int j = 0; j < 4; ++j) acc[i][j] = (f32x4){0.f, 0.f, 0.f, 0.f};
  char* asb = (char*)As;
  char* bsb = (char*)Bs;
  int srow = lane >> 2;            // 0..15
  int skb  = (lane & 3) << 4;      // byte offset within 64B row
  for (int k0 = 0; k0 < K; k0 += 32) {
    __syncthreads();
#pragma unroll
    for (int i = 0; i < 2; ++i) {
      int rr = wid * 32 + i * 16;
      gload16((const char*)Ab + ((size_t)(m0 + rr + srow) * K + k0) * 2 + skb,
              asb + rr * 64);
      gload16((const char*)Bb + ((size_t)(n0 + rr + srow) * K + k0) * 2 + skb,
              bsb + rr * 64);
    }
    __syncthreads();
    bf16x8 af[4], bf[4];
#pragma unroll
    for (int m = 0; m < 4; ++m)
      af[m] = *(bf16x8*)&As[(wm + m * 16 + (lane & 15)) * 32 + ((lane >> 4) << 3)];
#pragma unroll
    for (int n = 0; n < 4; ++n)
      bf[n] = *(bf16x8*)&Bs[(wn + n * 16 + (lane & 15)) * 32 + ((lane >> 4) << 3)];
#pragma unroll
    for (int m = 0; m < 4; ++m)
#pragma unroll
      for (int n = 0; n < 4; ++n)
        acc[m][n] = __builtin_amdgcn_mfma_f32_16x16x32_bf16(af[m], bf[n], acc[m][n], 0, 0, 0);
  }
  int cr = (lane >> 4) << 2, cc = lane & 15;
#pragma unroll
  for (int m = 0; m < 4; ++m)
#pragma unroll
    for (int n = 0; n < 4; ++n) {
#pragma unroll
      for (int r = 0; r < 4; ++r) {
        int row = m0 + wm + m * 16 + cr + r;
        int col = n0 + wn + n * 16 + cc;
        float v = acc[m][n][r];
        if (EPI == 0) {
          ((ushort*)Cout)[(size_t)bb * sC + (size_t)row * N + col] = f2bf(v);
        } else if (EPI == 1) {
          ((float*)Cout)[(size_t)row * N + col] = v + R[(size_t)row * N + col];
        } else {
          v = 0.5f * v * (1.0f + erff(v * 0.70710678118654752f));
          ((ushort*)Cout)[(size_t)row * N + col] = f2bf(v);
        }
      }
    }
}

// ---------------- reparameterization (bf16 in/out) ----------------
__global__ __launch_bounds__(256) void z_combine_b(const ushort* __restrict__ mean,
    const ushort* __restrict__ var, const float* __restrict__ eps,
    const float* __restrict__ dirty, const float* __restrict__ e2de_p,
    ushort* __restrict__ zout, int total, int perBatch) {
  int i = blockIdx.x * 256 + threadIdx.x;
  if (i >= total) return;
  float e = e2de_p[0];
  float v = b2f(mean[i]) +
            (e * eps[i] + (1.0f - e) * dirty[i % perBatch]) * expf(0.5f * b2f(var[i]));
  zout[i] = f2bf(v);
}

// ---------------- head pack + RoPE (bf16 in, bf16 out) ----------------
__global__ __launch_bounds__(256) void pack_qk_b(const ushort* __restrict__ zf,
    const ushort* __restrict__ rf, const float* __restrict__ freqs,
    ushort* __restrict__ out, float scale) {
  int i = blockIdx.x * 256 + threadIdx.x;  // i = ((b*H+h)*S + s)*64 + d
  int d = i & 63;
  int s = (i >> 6) & (S_ - 1);
  int bh = i >> 16;
  int b = bh / H_, h = bh % H_;
  float v;
  if (d < 32) {
    v = b2f(zf[((size_t)(b * S_ + s)) * (H_ * 32) + h * 32 + d]);
  } else {
    int dr = d - 32;
    const ushort* xr = rf + ((size_t)(b * S_ + s)) * (H_ * 32) + h * 32;
    float f = freqs[s * 16 + (dr & 15)];
    float c = cosf(f), sn = sinf(f);
    if (dr < 16) v = b2f(xr[dr]) * c - b2f(xr[dr + 16]) * sn;
    else         v = b2f(xr[dr]) * c + b2f(xr[dr - 16]) * sn;
  }
  out[i] = f2bf(v * scale);
}

__global__ __launch_bounds__(256) void pack_v_b(const ushort* __restrict__ vzf,
    ushort* __restrict__ out) {
  int i = blockIdx.x * 256 + threadIdx.x;
  int d = i & 63;
  int s = (i >> 6) & (S_ - 1);
  int bh = i >> 16;
  int b = bh / H_, h = bh % H_;
  out[i] = vzf[((size_t)(b * S_ + s)) * D3_ + h * 64 + d];
}

// ---------------- MFMA flash attention ----------------
__global__ __launch_bounds__(256) void attn_mfma(const ushort* __restrict__ Q,
    const ushort* __restrict__ K, const ushort* __restrict__ V,
    ushort* __restrict__ O) {
  __shared__ ushort lds[16384];                 // 32 KB
  char* qc = (char*)lds;                        // Qs [64 q][64 d]
  char* kc = (char*)lds + 8192;                 // Ks [64 key][64 d]
  char* vc = (char*)lds + 16384;                // Vt [64 d][64 key]
  char* pc = (char*)lds + 24576;                // Ps [64 q][64 key]
  int tid = threadIdx.x, lane = tid & 63, wid = tid >> 6;
  int bh = blockIdx.y, q0 = blockIdx.x << 6;
  int b = bh / H_, h = bh % H_;
  const ushort* Qb = Q + ((size_t)bh * S_ + q0) * HD_;
  const ushort* Kb = K + (size_t)bh * S_ * HD_;
  const ushort* Vb = V + (size_t)bh * S_ * HD_;
  {
    int r = tid >> 2, c0 = (tid & 3) * 32;
    const char* src = (const char*)Qb + r * 128;
    uint4 v0 = *(const uint4*)(src + c0);
    uint4 v1 = *(const uint4*)(src + c0 + 16);
    int sw = (r & 7) << 4;
    *(uint4*)(qc + r * 128 + (c0 ^ sw)) = v0;
    *(uint4*)(qc + r * 128 + ((c0 + 16) ^ sw)) = v1;
  }
  __syncthreads();
  bf16x8 aq[2];
  {
    int r = wid * 16 + (lane & 15);
    int sw = (r & 7) << 4;
#pragma unroll
    for (int kk = 0; kk < 2; ++kk) {
      int c2 = kk * 64 + ((lane >> 4) << 4);
      aq[kk] = *(bf16x8*)(qc + r * 128 + (c2 ^ sw));
    }
  }
  f32x4 o_[4];
  float m_[4], l_[4];
#pragma unroll
  for (int i = 0; i < 4; ++i) { o_[i] = (f32x4){0.f,0.f,0.f,0.f}; m_[i] = -1e30f; l_[i] = 0.f; }

  for (int kt = 0; kt < S_ / 64; ++kt) {
    __syncthreads();
    {
      int r = tid >> 2, c0 = (tid & 3) * 32;
      const char* src = (const char*)(Kb + (size_t)(kt * 64 + r) * HD_);
      uint4 v0 = *(const uint4*)(src + c0);
      uint4 v1 = *(const uint4*)(src + c0 + 16);
      int sw = (r & 7) << 4;
      *(uint4*)(kc + r * 128 + (c0 ^ sw)) = v0;
      *(uint4*)(kc + r * 128 + ((c0 + 16) ^ sw)) = v1;
    }
    {
      int kp = tid & 31, g = tid >> 5, d0 = g * 8;
      const ushort* s0 = Vb + (size_t)(kt * 64 + 2 * kp) * HD_ + d0;
      bf16x8 va = *(const bf16x8*)s0;
      bf16x8 vb2 = *(const bf16x8*)(s0 + HD_);
#pragma unroll
      for (int j = 0; j < 8; ++j) {
        int d = d0 + j;
        uint val = (uint)(ushort)va[j] | ((uint)(ushort)vb2[j] << 16);
        *(uint*)(vc + d * 128 + ((kp * 4) ^ ((d & 7) << 4))) = val;
      }
    }
    __syncthreads();
    f32x4 sacc[4];
#pragma unroll
    for (int ksub = 0; ksub < 4; ++ksub) {
      sacc[ksub] = (f32x4){0.f,0.f,0.f,0.f};
#pragma unroll
      for (int kk = 0; kk < 2; ++kk) {
        int r = ksub * 16 + (lane & 15);
        int c2 = kk * 64 + ((lane >> 4) << 4);
        bf16x8 bk = *(bf16x8*)(kc + r * 128 + (c2 ^ ((r & 7) << 4)));
        sacc[ksub] = __builtin_amdgcn_mfma_f32_16x16x32_bf16(aq[kk], bk, sacc[ksub], 0, 0, 0);
      }
    }
    float p[4][4];
#pragma unroll
    for (int rr = 0; rr < 4; ++rr) {
      float cm = fmaxf(fmaxf(sacc[0][rr], sacc[1][rr]), fmaxf(sacc[2][rr], sacc[3][rr]));
      cm = fmaxf(cm, __shfl_xor(cm, 1));
      cm = fmaxf(cm, __shfl_xor(cm, 2));
      cm = fmaxf(cm, __shfl_xor(cm, 4));
      cm = fmaxf(cm, __shfl_xor(cm, 8));
      float mn = fmaxf(m_[rr], cm);
      float al = __expf(m_[rr] - mn);
      float ps = 0.f;
#pragma unroll
      for (int ksub = 0; ksub < 4; ++ksub) {
        float pv = __expf(sacc[ksub][rr] - mn);
        p[ksub][rr] = pv;
        ps += pv;
      }
      ps += __shfl_xor(ps, 1);
      ps += __shfl_xor(ps, 2);
      ps += __shfl_xor(ps, 4);
      ps += __shfl_xor(ps, 8);
      l_[rr] = l_[rr] * al + ps;
      m_[rr] = mn;
#pragma unroll
      for (int ds = 0; ds < 4; ++ds) o_[ds][rr] *= al;
    }
#pragma unroll
    for (int ksub = 0; ksub < 4; ++ksub)
#pragma unroll
      for (int rr = 0; rr < 4; ++rr) {
        int r = wid * 16 + ((lane >> 4) << 2) + rr;
        int cb = (ksub * 16 + (lane & 15)) * 2;
        *(ushort*)(pc + r * 128 + (cb ^ ((r & 7) << 4))) = f2bf(p[ksub][rr]);
      }
#pragma unroll
    for (int kk2 = 0; kk2 < 2; ++kk2) {
      int rA = wid * 16 + (lane & 15);
      int c2 = kk2 * 64 + ((lane >> 4) << 4);
      bf16x8 ap = *(bf16x8*)(pc + rA * 128 + (c2 ^ ((rA & 7) << 4)));
#pragma unroll
      for (int ds = 0; ds < 4; ++ds) {
        int rB = ds * 16 + (lane & 15);
        bf16x8 bv = *(bf16x8*)(vc + rB * 128 + (c2 ^ ((rB & 7) << 4)));
        o_[ds] = __builtin_amdgcn_mfma_f32_16x16x32_bf16(ap, bv, o_[ds], 0, 0, 0);
      }
    }
  }
#pragma unroll
  for (int rr = 0; rr < 4; ++rr) {
    float inv = 1.f / l_[rr];
    int q = q0 + wid * 16 + ((lane >> 4) << 2) + rr;
#pragma unroll
    for (int ds = 0; ds < 4; ++ds) {
      int d = ds * 16 + (lane & 15);
      O[((size_t)(b * S_ + q)) * D3_ + h * HD_ + d] = f2bf(o_[ds][rr] * inv);
    }
  }
}

// ---------------- host ----------------
extern "C" void kernel_launch(void* const* d_in, const int* in_sizes, int n_in,
                              void* d_out, int out_size, void* d_ws, size_t ws_size,
                              hipStream_t stream) {
  const float* input_q = (const float*)d_in[0];
  const float* ln_q_w  = (const float*)d_in[1];
  const float* ln_kv_w = (const float*)d_in[2];
  const float* e2de    = (const float*)d_in[17];
  const float* rope_q_f = (const float*)d_in[31];
  const float* rope_k_f = (const float*)d_in[32];
  const float* ln2_w   = (const float*)d_in[34];
  const float* eps_zq  = (const float*)d_in[37];
  const float* eps_zkv = (const float*)d_in[38];
  const float* dirty_zq  = (const float*)d_in[15];
  const float* dirty_zkv = (const float*)d_in[16];

  float* ws = (float*)d_ws;
  // ---- arena (float-slot offsets) ----
  ushort* wb    = (ushort*)(ws + 0);
  float*  xq    = ws + 6062080;               // [8,1024,768]
  float*  xkv   = ws + 12353536;
  ushort* xqT   = (ushort*)(ws + 18644992);   // [8,768,1024]
  ushort* xkvT  = (ushort*)(ws + 21790720);
  ushort* inT   = (ushort*)(ws + 24936448);
  ushort* t1_b  = (ushort*)(ws + 28082176);   // [8,256,768]
  ushort* t2_b  = (ushort*)(ws + 28868608);   // [2048,512]
  ushort* mean_b= (ushort*)(ws + 29392896);   // [2048,256]
  ushort* var_b = (ushort*)(ws + 29655040);
  ushort* zq_b  = (ushort*)(ws + 29917184);
  ushort* zkv_b = (ushort*)(ws + 30179328);
  ushort* zqT   = (ushort*)(ws + 30441472);
  ushort* zkvT  = (ushort*)(ws + 30703616);
  ushort* up_b  = (ushort*)(ws + 6062080);    // overlays dead xq
  ushort* mid_b = (ushort*)(ws + 7110656);
  ushort* tkr_b = (ushort*)(ws + 9207808);
  ushort* qzf_b = (ushort*)(ws + 12353536);   // overlays dead xkv
  ushort* kzf_b = (ushort*)(ws + 13926400);
  ushort* qrf_b = (ushort*)(ws + 15499264);
  ushort* krf_b = (ushort*)(ws + 17072128);
  ushort* vzf_b = (ushort*)(ws + 31227904);   // [8192,768]
  ushort* qp_b  = (ushort*)(ws + 18644992);   // [96,1024,64] overlays xqT (dead)
  ushort* kp_b  = (ushort*)(ws + 21790720);   // overlays xkvT (dead)
  ushort* vp_b  = (ushort*)(ws + 24936448);   // overlays inT (dead after step 6)
  ushort* of_b  = (ushort*)(ws + 6062080);    // [8192,768] overlays up/mid/tkr (dead)
  float*  xb    = ws + 18644992;              // overlays qp_b (dead after attn)
  float*  yl    = ws + 12353536;              // overlays qzf..krf (dead after packs)
  ushort* yl_b  = (ushort*)(ws + 28082176);   // overlays t1_b (dead)
  ushort* hm_b  = (ushort*)(ws + 6062080);    // [8192,3072] overlays of_b (dead after out_w)

  // weight offsets within wb (elements)
  const int W_mq = 0,       W_vq = 262144,  W_mkv = 524288, W_vkv = 786432;
  const int Wq1 = 1048576,  Wv1 = 1441792,  Wk1 = 1835008,  Wkv1 = 2228224;
  const int Wq2 = 2621440,  Wv2 = 2752512,  Wk2 = 2883584,  Wkv2 = 3014656;
  const int W_qzu = 3145728, W_kzu = 3407872, W_vzu = 3670016, W_qr = 3932160;
  const int W_kr = 4194304, W_qzup = 5242880, W_kzup = 5373952, W_vzup = 5505024;
  const int W_qw = 5636096, W_kw = 5832704,  W_vw = 6029312,  W_qrw = 6422528;
  const int W_krw = 6520832, W_ow = 6815744, W_m1 = 7405568,  W_m2 = 9764864;

  auto G0 = [&](const ushort* A, long sA, const ushort* Bm, long sB, ushort* C, long sC,
                int M, int N, int K, int nb) {
    dim3 g(N / 128, M / 128, nb);
    gemm_bf16<0><<<g, 256, 0, stream>>>(A, sA, Bm, sB, nullptr, C, sC, M, N, K);
  };

  // 1) dual LN (fp32 out)
  ln_dual<<<B_ * S_, 256, 0, stream>>>(input_q, ln_q_w, ln_kv_w, xq, xkv, D1_);

  // 2) transposes to bf16 [b, D, S]
  {
    dim3 g(D1_ / 32, S_ / 32, B_);
    trans_f2b<<<g, 256, 0, stream>>>(xq, xqT, S_, D1_, (long)S_ * D1_);
    trans_f2b<<<g, 256, 0, stream>>>(xkv, xkvT, S_, D1_, (long)S_ * D1_);
    trans_f2b<<<g, 256, 0, stream>>>(input_q, inT, S_, D1_, (long)S_ * D1_);
  }

  // 3) weights -> bf16 (single kernel)
  {
    ConvTab t;
    const int srcIdx[28] = {3,4,5,6, 7,9,11,13, 8,10,12,14, 18,19,20,21, 22,
                            23,24,25, 26,27, 28, 29, 30, 33, 35, 36};
    const int sz[28] = {262144,262144,262144,262144, 393216,393216,393216,393216,
                        131072,131072,131072,131072, 262144,262144,262144,262144,
                        1048576, 131072,131072,131072, 196608,196608, 393216,
                        98304, 294912, 589824, 2359296, 2359296};
    int off = 0, c4 = 0;
    for (int i = 0; i < 28; ++i) {
      t.src[i] = (const float*)d_in[srcIdx[i]];
      t.off[i] = off;
      t.cum[i] = c4;
      off += sz[i];
      c4 += sz[i] / 4;
    }
    t.cum[28] = c4;
    multi_f2b<<<(c4 + 255) / 256, 256, 0, stream>>>(t, wb, c4);
  }

  long sXT = (long)S_ * D1_;
  long sT1 = (long)SR_ * D1_;
  long sZT = (long)SR_ * MVH_;
  long sUP = (long)SN_ * MVH_;
  long sTK = (long)SN_ * D1_;

  // 4) VAE q
  G0(wb + W_mq, 0, xqT, sXT, t1_b, sT1, SR_, D1_, S_, B_);
  G0(t1_b, 0, wb + Wq1, 0, t2_b, 0, B_ * SR_, D2_, D1_, 1);
  G0(t2_b, 0, wb + Wq2, 0, mean_b, 0, B_ * SR_, MVH_, D2_, 1);
  G0(wb + W_vq, 0, xqT, sXT, t1_b, sT1, SR_, D1_, S_, B_);
  G0(t1_b, 0, wb + Wv1, 0, t2_b, 0, B_ * SR_, D2_, D1_, 1);
  G0(t2_b, 0, wb + Wv2, 0, var_b, 0, B_ * SR_, MVH_, D2_, 1);
  z_combine_b<<<(B_ * SR_ * MVH_) / 256, 256, 0, stream>>>(mean_b, var_b, eps_zq,
      dirty_zq, e2de, zq_b, B_ * SR_ * MVH_, SR_ * MVH_);
  // VAE kv
  G0(wb + W_mkv, 0, xkvT, sXT, t1_b, sT1, SR_, D1_, S_, B_);
  G0(t1_b, 0, wb + Wk1, 0, t2_b, 0, B_ * SR_, D2_, D1_, 1);
  G0(t2_b, 0, wb + Wk2, 0, mean_b, 0, B_ * SR_, MVH_, D2_, 1);
  G0(wb + W_vkv, 0, xkvT, sXT, t1_b, sT1, SR_, D1_, S_, B_);
  G0(t1_b, 0, wb + Wkv1, 0, t2_b, 0, B_ * SR_, D2_, D1_, 1);
  G0(t2_b, 0, wb + Wkv2, 0, var_b, 0, B_ * SR_, MVH_, D2_, 1);
  z_combine_b<<<(B_ * SR_ * MVH_) / 256, 256, 0, stream>>>(mean_b, var_b, eps_zkv,
      dirty_zkv, e2de, zkv_b, B_ * SR_ * MVH_, SR_ * MVH_);

  // 5) z transposes
  {
    dim3 g(MVH_ / 32, SR_ / 32, B_);
    trans_b2b<<<g, 256, 0, stream>>>(zq_b, zqT, SR_, MVH_, sZT);
    trans_b2b<<<g, 256, 0, stream>>>(zkv_b, zkvT, SR_, MVH_, sZT);
  }

  // 6) upsample chains
  G0(wb + W_qzu, 0, zqT, sZT, up_b, sUP, SN_, MVH_, SR_, B_);
  G0(up_b, 0, wb + W_qzup, 0, mid_b, 0, B_ * SN_, D2_, MVH_, 1);
  G0(mid_b, 0, wb + W_qw, 0, qzf_b, 0, B_ * SN_, H_ * 32, D2_, 1);
  G0(wb + W_kzu, 0, zkvT, sZT, up_b, sUP, SN_, MVH_, SR_, B_);
  G0(up_b, 0, wb + W_kzup, 0, mid_b, 0, B_ * SN_, D2_, MVH_, 1);
  G0(mid_b, 0, wb + W_kw, 0, kzf_b, 0, B_ * SN_, H_ * 32, D2_, 1);
  G0(wb + W_vzu, 0, zkvT, sZT, up_b, sUP, SN_, MVH_, SR_, B_);
  G0(up_b, 0, wb + W_vzup, 0, mid_b, 0, B_ * SN_, D2_, MVH_, 1);
  G0(mid_b, 0, wb + W_vw, 0, vzf_b, 0, B_ * SN_, D3_, D2_, 1);
  G0(wb + W_qr, 0, zqT, sZT, up_b, sUP, SN_, MVH_, SR_, B_);
  G0(up_b, 0, wb + W_qrw, 0, qrf_b, 0, B_ * SN_, H_ * 32, MVH_, 1);
  G0(wb + W_kr, 0, inT, sXT, tkr_b, sTK, SN_, D1_, S_, B_);
  G0(tkr_b, 0, wb + W_krw, 0, krf_b, 0, B_ * SN_, H_ * 32, D1_, 1);

  // 7) pack heads (+RoPE; q pre-scaled), bf16 out
  int tot = B_ * H_ * S_ * HD_;
  pack_qk_b<<<tot / 256, 256, 0, stream>>>(qzf_b, qrf_b, rope_q_f, qp_b, 0.125f);
  pack_qk_b<<<tot / 256, 256, 0, stream>>>(kzf_b, krf_b, rope_k_f, kp_b, 1.0f);
  pack_v_b<<<tot / 256, 256, 0, stream>>>(vzf_b, vp_b);

  // 8) attention (bf16 MFMA)
  {
    dim3 g(S_ / 64, B_ * H_);
    attn_mfma<<<g, 256, 0, stream>>>(qp_b, kp_b, vp_b, of_b);
  }

  // 9) epilogue
  {
    dim3 g(D3_ / 128, (B_ * SN_) / 128);
    gemm_bf16<1><<<g, 256, 0, stream>>>(of_b, 0, wb + W_ow, 0, input_q, xb, 0,
                                        B_ * SN_, D3_, D3_);
  }
  ln_dual<<<B_ * SN_, 256, 0, stream>>>(xb, ln2_w, nullptr, yl, nullptr, D3_);
  f2b_kern<<<(B_ * SN_ * D3_ / 4 + 255) / 256, 256, 0, stream>>>(yl, yl_b,
                                                                 B_ * SN_ * D3_ / 4);
  {
    dim3 g(MLP_ / 128, (B_ * SN_) / 128);
    gemm_bf16<2><<<g, 256, 0, stream>>>(yl_b, 0, wb + W_m1, 0, nullptr, hm_b, 0,
                                        B_ * SN_, MLP_, D3_);
  }
  {
    dim3 g(D3_ / 128, (B_ * SN_) / 128);
    gemm_bf16<1><<<g, 256, 0, stream>>>(hm_b, 0, wb + W_m2, 0, xb, (float*)d_out, 0,
                                        B_ * SN_, D3_, MLP_);
  }
}

// Round 10
// 589.357 us; speedup vs baseline: 9.8843x; 1.3912x over previous
//
#include <hip/hip_runtime.h>
#include <math.h>

#define B_   8
#define S_   1024
#define SR_  256
#define SN_  1024
#define D1_  768
#define D2_  512
#define D3_  768
#define MVH_ 256
#define H_   12
#define HD_  64
#define MLP_ 3072

typedef __attribute__((ext_vector_type(8))) short bf16x8;
typedef __attribute__((ext_vector_type(4))) float f32x4;

__device__ inline ushort f2bf(float f) {
  uint u = __float_as_uint(f);
  uint r = (u + 0x7fffu + ((u >> 16) & 1u)) >> 16;
  return (ushort)r;
}
__device__ inline float b2f(ushort u) { return __uint_as_float(((uint)u) << 16); }

__device__ inline void gload16(const void* g, void* l) {
  __builtin_amdgcn_global_load_lds(
      (const __attribute__((address_space(1))) void*)g,
      (__attribute__((address_space(3))) void*)l, 16, 0, 0);
}

// ---------------- LayerNorm (dual fp32 out) ----------------
__global__ __launch_bounds__(256) void ln_dual(const float* __restrict__ x,
    const float* __restrict__ w1, const float* __restrict__ w2,
    float* __restrict__ o1, float* __restrict__ o2, int D) {
  int row = blockIdx.x;
  const float* xr = x + (size_t)row * D;
  int tid = threadIdx.x;
  float s = 0.f, ss = 0.f;
  for (int i = tid; i < D; i += 256) { float v = xr[i]; s += v; ss += v * v; }
  __shared__ float rs[256];
  __shared__ float rq[256];
  rs[tid] = s; rq[tid] = ss;
  __syncthreads();
  for (int off = 128; off > 0; off >>= 1) {
    if (tid < off) { rs[tid] += rs[tid + off]; rq[tid] += rq[tid + off]; }
    __syncthreads();
  }
  float mu  = rs[0] / (float)D;
  float var = rq[0] / (float)D - mu * mu;
  float inv = rsqrtf(var + 1e-6f);
  for (int i = tid; i < D; i += 256) {
    float v = (xr[i] - mu) * inv;
    o1[(size_t)row * D + i] = v * w1[i];
    if (o2) o2[(size_t)row * D + i] = v * w2[i];
  }
}

// ---------------- LayerNorm (bf16 out) ----------------
__global__ __launch_bounds__(256) void ln_b(const float* __restrict__ x,
    const float* __restrict__ w, ushort* __restrict__ o, int D) {
  int row = blockIdx.x;
  const float* xr = x + (size_t)row * D;
  int tid = threadIdx.x;
  float s = 0.f, ss = 0.f;
  for (int i = tid; i < D; i += 256) { float v = xr[i]; s += v; ss += v * v; }
  __shared__ float rs[256];
  __shared__ float rq[256];
  rs[tid] = s; rq[tid] = ss;
  __syncthreads();
  for (int off = 128; off > 0; off >>= 1) {
    if (tid < off) { rs[tid] += rs[tid + off]; rq[tid] += rq[tid + off]; }
    __syncthreads();
  }
  float mu  = rs[0] / (float)D;
  float var = rq[0] / (float)D - mu * mu;
  float inv = rsqrtf(var + 1e-6f);
  for (int i = tid; i < D; i += 256) {
    float v = (xr[i] - mu) * inv;
    o[(size_t)row * D + i] = f2bf(v * w[i]);
  }
}

// ---------------- transpose fp32 -> bf16 ----------------
__global__ __launch_bounds__(256) void trans_f2b(const float* __restrict__ in,
    ushort* __restrict__ out, int R, int C, long strideEl) {
  __shared__ float tile[32][33];
  int bb = blockIdx.z;
  const float* ib = in + (size_t)bb * strideEl;
  ushort* ob = out + (size_t)bb * strideEl;
  int c0 = blockIdx.x << 5, r0 = blockIdx.y << 5;
  int tx = threadIdx.x & 31, ty = threadIdx.x >> 5;
#pragma unroll
  for (int i = 0; i < 4; ++i)
    tile[ty + 8 * i][tx] = ib[(size_t)(r0 + ty + 8 * i) * C + c0 + tx];
  __syncthreads();
#pragma unroll
  for (int i = 0; i < 4; ++i)
    ob[(size_t)(c0 + ty + 8 * i) * R + r0 + tx] = f2bf(tile[tx][ty + 8 * i]);
}

// ---------------- transpose bf16 -> bf16 ----------------
__global__ __launch_bounds__(256) void trans_b2b(const ushort* __restrict__ in,
    ushort* __restrict__ out, int R, int C, long strideEl) {
  __shared__ ushort tile[32][33];
  int bb = blockIdx.z;
  const ushort* ib = in + (size_t)bb * strideEl;
  ushort* ob = out + (size_t)bb * strideEl;
  int c0 = blockIdx.x << 5, r0 = blockIdx.y << 5;
  int tx = threadIdx.x & 31, ty = threadIdx.x >> 5;
#pragma unroll
  for (int i = 0; i < 4; ++i)
    tile[ty + 8 * i][tx] = ib[(size_t)(r0 + ty + 8 * i) * C + c0 + tx];
  __syncthreads();
#pragma unroll
  for (int i = 0; i < 4; ++i)
    ob[(size_t)(c0 + ty + 8 * i) * R + r0 + tx] = tile[tx][ty + 8 * i];
}

// ---------------- multi-tensor fp32 -> bf16 weight conversion ----------------
struct ConvTab {
  const float* src[28];
  int off[28];
  int cum[29];
};
__global__ __launch_bounds__(256) void multi_f2b(ConvTab t, ushort* __restrict__ wb,
                                                 int total4) {
  int i = blockIdx.x * 256 + threadIdx.x;
  if (i >= total4) return;
  int ti = 0;
  while (t.cum[ti + 1] <= i) ++ti;
  int j = i - t.cum[ti];
  float4 v = ((const float4*)t.src[ti])[j];
  ushort4 o;
  o.x = f2bf(v.x); o.y = f2bf(v.y); o.z = f2bf(v.z); o.w = f2bf(v.w);
  ((ushort4*)(wb + t.off[ti]))[j] = o;
}

// ---------------- bf16 MFMA GEMM (strided batch): C_b = A_b @ B_b^T ----------------
// EPI: 0 = bf16 out, 1 = fp32 out + R, 2 = fast-gelu bf16 out
template <int EPI>
__global__ __launch_bounds__(256) void gemm_bf16(const ushort* __restrict__ A, long sA,
    const ushort* __restrict__ Bm, long sB, const float* __restrict__ R,
    void* __restrict__ Cout, long sC, int M, int N, int K) {
  int bb = blockIdx.z;
  const ushort* Ab = A + (size_t)bb * sA;
  const ushort* Bb = Bm + (size_t)bb * sB;
  __shared__ ushort As[128 * 32];
  __shared__ ushort Bs[128 * 32];
  int tid = threadIdx.x;
  int lane = tid & 63, wid = tid >> 6;
  int m0 = blockIdx.y << 7, n0 = blockIdx.x << 7;
  int wm = (wid >> 1) << 6, wn = (wid & 1) << 6;
  f32x4 acc[4][4];
#pragma unroll
  for (int i = 0; i < 4; ++i)
#pragma unroll
    for (int j = 0; j < 4; ++j) acc[i][j] = (f32x4){0.f, 0.f, 0.f, 0.f};
  char* asb = (char*)As;
  char* bsb = (char*)Bs;
  int srow = lane >> 2;
  int skb  = (lane & 3) << 4;
  for (int k0 = 0; k0 < K; k0 += 32) {
    __syncthreads();
#pragma unroll
    for (int i = 0; i < 2; ++i) {
      int rr = wid * 32 + i * 16;
      gload16((const char*)Ab + ((size_t)(m0 + rr + srow) * K + k0) * 2 + skb,
              asb + rr * 64);
      gload16((const char*)Bb + ((size_t)(n0 + rr + srow) * K + k0) * 2 + skb,
              bsb + rr * 64);
    }
    __syncthreads();
    bf16x8 af[4], bf[4];
#pragma unroll
    for (int m = 0; m < 4; ++m)
      af[m] = *(bf16x8*)&As[(wm + m * 16 + (lane & 15)) * 32 + ((lane >> 4) << 3)];
#pragma unroll
    for (int n = 0; n < 4; ++n)
      bf[n] = *(bf16x8*)&Bs[(wn + n * 16 + (lane & 15)) * 32 + ((lane >> 4) << 3)];
#pragma unroll
    for (int m = 0; m < 4; ++m)
#pragma unroll
      for (int n = 0; n < 4; ++n)
        acc[m][n] = __builtin_amdgcn_mfma_f32_16x16x32_bf16(af[m], bf[n], acc[m][n], 0, 0, 0);
  }
  int cr = (lane >> 4) << 2, cc = lane & 15;
#pragma unroll
  for (int m = 0; m < 4; ++m)
#pragma unroll
    for (int n = 0; n < 4; ++n) {
#pragma unroll
      for (int r = 0; r < 4; ++r) {
        int row = m0 + wm + m * 16 + cr + r;
        int col = n0 + wn + n * 16 + cc;
        float v = acc[m][n][r];
        if (EPI == 0) {
          ((ushort*)Cout)[(size_t)bb * sC + (size_t)row * N + col] = f2bf(v);
        } else if (EPI == 1) {
          ((float*)Cout)[(size_t)row * N + col] = v + R[(size_t)row * N + col];
        } else {
          float y = 0.7978845608f * (v + 0.044715f * v * v * v);
          float sg = 1.0f / (1.0f + __expf(-2.0f * y));
          ((ushort*)Cout)[(size_t)row * N + col] = f2bf(v * sg);
        }
      }
    }
}

// ---------------- grouped bf16 MFMA GEMM: per-z pointer table, bf16 out ----------------
struct GrpTab {
  const ushort* A[32];
  const ushort* Bm[32];
  ushort* C[32];
};
__global__ __launch_bounds__(256) void gemm_grp(GrpTab t, int M, int N, int K) {
  int zz = blockIdx.z;
  const ushort* Ab = t.A[zz];
  const ushort* Bb = t.Bm[zz];
  ushort* Cb = t.C[zz];
  __shared__ ushort As[128 * 32];
  __shared__ ushort Bs[128 * 32];
  int tid = threadIdx.x;
  int lane = tid & 63, wid = tid >> 6;
  int m0 = blockIdx.y << 7, n0 = blockIdx.x << 7;
  int wm = (wid >> 1) << 6, wn = (wid & 1) << 6;
  f32x4 acc[4][4];
#pragma unroll
  for (int i = 0; i < 4; ++i)
#pragma unroll
    for (int j = 0; j < 4; ++j) acc[i][j] = (f32x4){0.f, 0.f, 0.f, 0.f};
  char* asb = (char*)As;
  char* bsb = (char*)Bs;
  int srow = lane >> 2;
  int skb  = (lane & 3) << 4;
  for (int k0 = 0; k0 < K; k0 += 32) {
    __syncthreads();
#pragma unroll
    for (int i = 0; i < 2; ++i) {
      int rr = wid * 32 + i * 16;
      gload16((const char*)Ab + ((size_t)(m0 + rr + srow) * K + k0) * 2 + skb,
              asb + rr * 64);
      gload16((const char*)Bb + ((size_t)(n0 + rr + srow) * K + k0) * 2 + skb,
              bsb + rr * 64);
    }
    __syncthreads();
    bf16x8 af[4], bf[4];
#pragma unroll
    for (int m = 0; m < 4; ++m)
      af[m] = *(bf16x8*)&As[(wm + m * 16 + (lane & 15)) * 32 + ((lane >> 4) << 3)];
#pragma unroll
    for (int n = 0; n < 4; ++n)
      bf[n] = *(bf16x8*)&Bs[(wn + n * 16 + (lane & 15)) * 32 + ((lane >> 4) << 3)];
#pragma unroll
    for (int m = 0; m < 4; ++m)
#pragma unroll
      for (int n = 0; n < 4; ++n)
        acc[m][n] = __builtin_amdgcn_mfma_f32_16x16x32_bf16(af[m], bf[n], acc[m][n], 0, 0, 0);
  }
  int cr = (lane >> 4) << 2, cc = lane & 15;
#pragma unroll
  for (int m = 0; m < 4; ++m)
#pragma unroll
    for (int n = 0; n < 4; ++n) {
#pragma unroll
      for (int r = 0; r < 4; ++r) {
        int row = m0 + wm + m * 16 + cr + r;
        int col = n0 + wn + n * 16 + cc;
        Cb[(size_t)row * N + col] = f2bf(acc[m][n][r]);
      }
    }
}

// ---------------- reparameterization (bf16 in/out) ----------------
__global__ __launch_bounds__(256) void z_combine_b(const ushort* __restrict__ mean,
    const ushort* __restrict__ var, const float* __restrict__ eps,
    const float* __restrict__ dirty, const float* __restrict__ e2de_p,
    ushort* __restrict__ zout, int total, int perBatch) {
  int i = blockIdx.x * 256 + threadIdx.x;
  if (i >= total) return;
  float e = e2de_p[0];
  float v = b2f(mean[i]) +
            (e * eps[i] + (1.0f - e) * dirty[i % perBatch]) * expf(0.5f * b2f(var[i]));
  zout[i] = f2bf(v);
}

// ---------------- head pack + RoPE (bf16 in, bf16 out) ----------------
__global__ __launch_bounds__(256) void pack_qk_b(const ushort* __restrict__ zf,
    const ushort* __restrict__ rf, const float* __restrict__ freqs,
    ushort* __restrict__ out, float scale) {
  int i = blockIdx.x * 256 + threadIdx.x;  // i = ((b*H+h)*S + s)*64 + d
  int d = i & 63;
  int s = (i >> 6) & (S_ - 1);
  int bh = i >> 16;
  int b = bh / H_, h = bh % H_;
  float v;
  if (d < 32) {
    v = b2f(zf[((size_t)(b * S_ + s)) * (H_ * 32) + h * 32 + d]);
  } else {
    int dr = d - 32;
    const ushort* xr = rf + ((size_t)(b * S_ + s)) * (H_ * 32) + h * 32;
    float f = freqs[s * 16 + (dr & 15)];
    float c = cosf(f), sn = sinf(f);
    if (dr < 16) v = b2f(xr[dr]) * c - b2f(xr[dr + 16]) * sn;
    else         v = b2f(xr[dr]) * c + b2f(xr[dr - 16]) * sn;
  }
  out[i] = f2bf(v * scale);
}

__global__ __launch_bounds__(256) void pack_v_b(const ushort* __restrict__ vzf,
    ushort* __restrict__ out) {
  int i = blockIdx.x * 256 + threadIdx.x;
  int d = i & 63;
  int s = (i >> 6) & (S_ - 1);
  int bh = i >> 16;
  int b = bh / H_, h = bh % H_;
  out[i] = vzf[((size_t)(b * S_ + s)) * D3_ + h * 64 + d];
}

// ---------------- MFMA flash attention ----------------
__global__ __launch_bounds__(256) void attn_mfma(const ushort* __restrict__ Q,
    const ushort* __restrict__ K, const ushort* __restrict__ V,
    ushort* __restrict__ O) {
  __shared__ ushort lds[16384];                 // 32 KB
  char* qc = (char*)lds;
  char* kc = (char*)lds + 8192;
  char* vc = (char*)lds + 16384;
  char* pc = (char*)lds + 24576;
  int tid = threadIdx.x, lane = tid & 63, wid = tid >> 6;
  int bh = blockIdx.y, q0 = blockIdx.x << 6;
  int b = bh / H_, h = bh % H_;
  const ushort* Qb = Q + ((size_t)bh * S_ + q0) * HD_;
  const ushort* Kb = K + (size_t)bh * S_ * HD_;
  const ushort* Vb = V + (size_t)bh * S_ * HD_;
  {
    int r = tid >> 2, c0 = (tid & 3) * 32;
    const char* src = (const char*)Qb + r * 128;
    uint4 v0 = *(const uint4*)(src + c0);
    uint4 v1 = *(const uint4*)(src + c0 + 16);
    int sw = (r & 7) << 4;
    *(uint4*)(qc + r * 128 + (c0 ^ sw)) = v0;
    *(uint4*)(qc + r * 128 + ((c0 + 16) ^ sw)) = v1;
  }
  __syncthreads();
  bf16x8 aq[2];
  {
    int r = wid * 16 + (lane & 15);
    int sw = (r & 7) << 4;
#pragma unroll
    for (int kk = 0; kk < 2; ++kk) {
      int c2 = kk * 64 + ((lane >> 4) << 4);
      aq[kk] = *(bf16x8*)(qc + r * 128 + (c2 ^ sw));
    }
  }
  f32x4 o_[4];
  float m_[4], l_[4];
#pragma unroll
  for (int i = 0; i < 4; ++i) { o_[i] = (f32x4){0.f,0.f,0.f,0.f}; m_[i] = -1e30f; l_[i] = 0.f; }

  for (int kt = 0; kt < S_ / 64; ++kt) {
    __syncthreads();
    {
      int r = tid >> 2, c0 = (tid & 3) * 32;
      const char* src = (const char*)(Kb + (size_t)(kt * 64 + r) * HD_);
      uint4 v0 = *(const uint4*)(src + c0);
      uint4 v1 = *(const uint4*)(src + c0 + 16);
      int sw = (r & 7) << 4;
      *(uint4*)(kc + r * 128 + (c0 ^ sw)) = v0;
      *(uint4*)(kc + r * 128 + ((c0 + 16) ^ sw)) = v1;
    }
    {
      int kp = tid & 31, g = tid >> 5, d0 = g * 8;
      const ushort* s0 = Vb + (size_t)(kt * 64 + 2 * kp) * HD_ + d0;
      bf16x8 va = *(const bf16x8*)s0;
      bf16x8 vb2 = *(const bf16x8*)(s0 + HD_);
#pragma unroll
      for (int j = 0; j < 8; ++j) {
        int d = d0 + j;
        uint val = (uint)(ushort)va[j] | ((uint)(ushort)vb2[j] << 16);
        *(uint*)(vc + d * 128 + ((kp * 4) ^ ((d & 7) << 4))) = val;
      }
    }
    __syncthreads();
    f32x4 sacc[4];
#pragma unroll
    for (int ksub = 0; ksub < 4; ++ksub) {
      sacc[ksub] = (f32x4){0.f,0.f,0.f,0.f};
#pragma unroll
      for (int kk = 0; kk < 2; ++kk) {
        int r = ksub * 16 + (lane & 15);
        int c2 = kk * 64 + ((lane >> 4) << 4);
        bf16x8 bk = *(bf16x8*)(kc + r * 128 + (c2 ^ ((r & 7) << 4)));
        sacc[ksub] = __builtin_amdgcn_mfma_f32_16x16x32_bf16(aq[kk], bk, sacc[ksub], 0, 0, 0);
      }
    }
    float p[4][4];
#pragma unroll
    for (int rr = 0; rr < 4; ++rr) {
      float cm = fmaxf(fmaxf(sacc[0][rr], sacc[1][rr]), fmaxf(sacc[2][rr], sacc[3][rr]));
      cm = fmaxf(cm, __shfl_xor(cm, 1));
      cm = fmaxf(cm, __shfl_xor(cm, 2));
      cm = fmaxf(cm, __shfl_xor(cm, 4));
      cm = fmaxf(cm, __shfl_xor(cm, 8));
      float mn = fmaxf(m_[rr], cm);
      float al = __expf(m_[rr] - mn);
      float ps = 0.f;
#pragma unroll
      for (int ksub = 0; ksub < 4; ++ksub) {
        float pv = __expf(sacc[ksub][rr] - mn);
        p[ksub][rr] = pv;
        ps += pv;
      }
      ps += __shfl_xor(ps, 1);
      ps += __shfl_xor(ps, 2);
      ps += __shfl_xor(ps, 4);
      ps += __shfl_xor(ps, 8);
      l_[rr] = l_[rr] * al + ps;
      m_[rr] = mn;
#pragma unroll
      for (int ds = 0; ds < 4; ++ds) o_[ds][rr] *= al;
    }
#pragma unroll
    for (int ksub = 0; ksub < 4; ++ksub)
#pragma unroll
      for (int rr = 0; rr < 4; ++rr) {
        int r = wid * 16 + ((lane >> 4) << 2) + rr;
        int cb = (ksub * 16 + (lane & 15)) * 2;
        *(ushort*)(pc + r * 128 + (cb ^ ((r & 7) << 4))) = f2bf(p[ksub][rr]);
      }
#pragma unroll
    for (int kk2 = 0; kk2 < 2; ++kk2) {
      int rA = wid * 16 + (lane & 15);
      int c2 = kk2 * 64 + ((lane >> 4) << 4);
      bf16x8 ap = *(bf16x8*)(pc + rA * 128 + (c2 ^ ((rA & 7) << 4)));
#pragma unroll
      for (int ds = 0; ds < 4; ++ds) {
        int rB = ds * 16 + (lane & 15);
        bf16x8 bv = *(bf16x8*)(vc + rB * 128 + (c2 ^ ((rB & 7) << 4)));
        o_[ds] = __builtin_amdgcn_mfma_f32_16x16x32_bf16(ap, bv, o_[ds], 0, 0, 0);
      }
    }
  }
#pragma unroll
  for (int rr = 0; rr < 4; ++rr) {
    float inv = 1.f / l_[rr];
    int q = q0 + wid * 16 + ((lane >> 4) << 2) + rr;
#pragma unroll
    for (int ds = 0; ds < 4; ++ds) {
      int d = ds * 16 + (lane & 15);
      O[((size_t)(b * S_ + q)) * D3_ + h * HD_ + d] = f2bf(o_[ds][rr] * inv);
    }
  }
}

// ---------------- host ----------------
extern "C" void kernel_launch(void* const* d_in, const int* in_sizes, int n_in,
                              void* d_out, int out_size, void* d_ws, size_t ws_size,
                              hipStream_t stream) {
  const float* input_q = (const float*)d_in[0];
  const float* ln_q_w  = (const float*)d_in[1];
  const float* ln_kv_w = (const float*)d_in[2];
  const float* dirty_zq  = (const float*)d_in[15];
  const float* dirty_zkv = (const float*)d_in[16];
  const float* e2de    = (const float*)d_in[17];
  const float* rope_q_f = (const float*)d_in[31];
  const float* rope_k_f = (const float*)d_in[32];
  const float* ln2_w   = (const float*)d_in[34];
  const float* eps_zq  = (const float*)d_in[37];
  const float* eps_zkv = (const float*)d_in[38];

  ushort* wsu = (ushort*)d_ws;
  // ---- arena (ushort-element offsets; liveness audited) ----
  ushort* wb   = wsu;                         // weights bf16, 12124160 el
  float*  xq   = (float*)(wsu + 12124160);    // [8,1024,768] fp32
  float*  xkv  = (float*)(wsu + 24707072);
  ushort* xqT  = wsu + 37289984;              // [8,768,1024]
  ushort* xkvT = wsu + 43581440;
  ushort* inT  = wsu + 49872896;
  ushort* t1q  = wsu + 12124160;              // [8][512][768] (mq rows 0-255, vq 256-511)
  ushort* t1kv = wsu + 15269888;
  ushort* t2b  = wsu + 18415616;              // [32][256][512]... [16 used pairs? no: 32 chunks]
  ushort* mv   = wsu + 20512768;              // [32][256][256] (mq,vq,mkv,vkv x batch)
  ushort* zqb  = wsu + 21561344;              // [8,256,256]
  ushort* zkvb = wsu + 22085632;
  ushort* zqT  = wsu + 22609920;
  ushort* zkvT = wsu + 23134208;
  ushort* up   = wsu + 23658496;              // [4][8][1024][256] (qz,kz,vz,qr)
  ushort* mid  = wsu + 56164352;              // [3][8192][512]
  ushort* tkr  = wsu + 37289984;              // [8][1024][768] (xqT dead)
  ushort* qzf  = wsu + 68747264;              // [8192,384]
  ushort* kzf  = wsu + 71892992;
  ushort* qrf  = wsu + 75038720;
  ushort* krf  = wsu + 78184448;
  ushort* vzf  = wsu + 23658496;              // [8192,768] (up chunks 0-2 dead)
  ushort* qp   = wsu + 12124160;              // packs (t1/t2 dead)
  ushort* kp   = wsu + 43581440;              // (xkvT dead)
  ushort* vp   = wsu + 49872896;              // (inT dead after kr1)
  ushort* ofb  = wsu + 56164352;              // (mid dead after stage3)
  float*  xb   = (float*)(wsu + 12124160);    // (qp dead after attn)
  ushort* ylb  = wsu + 37289984;              // (tkr dead after kr2)
  ushort* hm   = wsu + 43581440;              // [8192,3072] (kp/vp/ofb dead)

  // NOTE: t2b needs 32*256*512 = 4194304 el -> [18415616, 22609920). That would
  // overlap zqb/zkvb. Re-pack: t2b gets [15269888+3145728? ] -- instead place
  // t2b and mv in the xkv region which is free after transposes:
  t2b = wsu + 24707072;                       // [32][256][512] = 4194304 -> ends 28901376
  mv  = wsu + 28901376;                       // [32][256][256] = 2097152 -> ends 30998528
  zqb  = wsu + 30998528;                      // ends 31522816
  zkvb = wsu + 31522816;                      // ends 32047104
  zqT  = wsu + 32047104;                      // ends 32571392
  zkvT = wsu + 32571392;                      // ends 33095680 (xkv region ends 37289984)
  up   = wsu + 12124160;                      // [4][8][1024][256] = 8388608 -> ends 20512768 (t1/t2 in xq region... t1 dead after w1 stage)
  vzf  = wsu + 20512768;                      // [8192,768] = 6291456 -> ends 26804224? overlaps t2b!
  // up chunks: qz,kz,vz used in stage2 (reads up), qr used in qr-stage2.
  // vzf written at step 13 AFTER t2b dead (t2b dead after w2 step 6). But 26804224 > 24707072 overlaps t2b [24707072,28901376) which is dead by then. OK.
  qp   = wsu + 33095680;                      // [6291456] -> ends 39387136 (tkr at 37289984 CONFLICT!)
  // tkr live until kr stage-2 (step 15); qp written step 16 after. OK - no temporal overlap.
  qp   = wsu + 12124160;                      // reuse up region (up dead after steps 10-11): [12124160, 18415616)
  // but vzf lives [20512768, 26804224) - qp ends before. OK.

  // weight offsets within wb (elements)
  const int W_mq = 0,       W_vq = 262144,  W_mkv = 524288, W_vkv = 786432;
  const int Wq1 = 1048576,  Wv1 = 1441792,  Wk1 = 1835008,  Wkv1 = 2228224;
  const int Wq2 = 2621440,  Wv2 = 2752512,  Wk2 = 2883584,  Wkv2 = 3014656;
  const int W_qzu = 3145728, W_kzu = 3407872, W_vzu = 3670016, W_qr = 3932160;
  const int W_kr = 4194304, W_qzup = 5242880, W_kzup = 5373952, W_vzup = 5505024;
  const int W_qw = 5636096, W_kw = 5832704,  W_vw = 6029312,  W_qrw = 6422528;
  const int W_krw = 6520832, W_ow = 6815744, W_m1 = 7405568,  W_m2 = 9764864;
  (void)W_vq; (void)W_vkv;

  // 1) dual LN (fp32 out)
  ln_dual<<<B_ * S_, 256, 0, stream>>>(input_q, ln_q_w, ln_kv_w, xq, xkv, D1_);

  // 2) transposes to bf16 [b, D, S]
  {
    dim3 g(D1_ / 32, S_ / 32, B_);
    trans_f2b<<<g, 256, 0, stream>>>(xq, xqT, S_, D1_, (long)S_ * D1_);
    trans_f2b<<<g, 256, 0, stream>>>(xkv, xkvT, S_, D1_, (long)S_ * D1_);
    trans_f2b<<<g, 256, 0, stream>>>(input_q, inT, S_, D1_, (long)S_ * D1_);
  }

  // 3) weights -> bf16 (single kernel)
  {
    ConvTab t;
    const int srcIdx[28] = {3,4,5,6, 7,9,11,13, 8,10,12,14, 18,19,20,21, 22,
                            23,24,25, 26,27, 28, 29, 30, 33, 35, 36};
    const int sz[28] = {262144,262144,262144,262144, 393216,393216,393216,393216,
                        131072,131072,131072,131072, 262144,262144,262144,262144,
                        1048576, 131072,131072,131072, 196608,196608, 393216,
                        98304, 294912, 589824, 2359296, 2359296};
    int off = 0, c4 = 0;
    for (int i = 0; i < 28; ++i) {
      t.src[i] = (const float*)d_in[srcIdx[i]];
      t.off[i] = off;
      t.cum[i] = c4;
      off += sz[i];
      c4 += sz[i] / 4;
    }
    t.cum[28] = c4;
    multi_f2b<<<(c4 + 255) / 256, 256, 0, stream>>>(t, wb, c4);
  }

  long sXT = (long)S_ * D1_;   // 786432

  // 4) grouped seq-compress: z=16 (q/kv x batch); A = stacked [Wt_m;Wt_v] M=512
  {
    GrpTab t;
    for (int c = 0; c < 2; ++c)
      for (int b = 0; b < 8; ++b) {
        int z = c * 8 + b;
        t.A[z] = wb + (c == 0 ? W_mq : W_mkv);
        t.Bm[z] = (c == 0 ? xqT : xkvT) + (size_t)b * sXT;
        t.C[z] = (c == 0 ? t1q : t1kv) + (size_t)b * 512 * 768;
      }
    dim3 g(D1_ / 128, 512 / 128, 16);
    gemm_grp<<<g, 256, 0, stream>>>(t, 512, D1_, S_);
  }
  // 5) grouped w1: z=32 (chain {mq,vq,mkv,vkv} x batch), M=256,N=512,K=768
  {
    GrpTab t;
    const int wo[4] = {Wq1, Wv1, Wk1, Wkv1};
    for (int c = 0; c < 4; ++c)
      for (int b = 0; b < 8; ++b) {
        int z = c * 8 + b;
        ushort* t1 = (c < 2 ? t1q : t1kv);
        t.A[z] = t1 + (size_t)b * 512 * 768 + (size_t)(c & 1) * 256 * 768;
        t.Bm[z] = wb + wo[c];
        t.C[z] = t2b + (size_t)z * 256 * 512;
      }
    dim3 g(D2_ / 128, 256 / 128, 32);
    gemm_grp<<<g, 256, 0, stream>>>(t, 256, D2_, D1_);
  }
  // 6) grouped w2: z=32, M=256,N=256,K=512
  {
    GrpTab t;
    const int wo[4] = {Wq2, Wv2, Wk2, Wkv2};
    for (int c = 0; c < 4; ++c)
      for (int b = 0; b < 8; ++b) {
        int z = c * 8 + b;
        t.A[z] = t2b + (size_t)z * 256 * 512;
        t.Bm[z] = wb + wo[c];
        t.C[z] = mv + (size_t)z * 256 * 256;
      }
    dim3 g(MVH_ / 128, 256 / 128, 32);
    gemm_grp<<<g, 256, 0, stream>>>(t, 256, MVH_, D2_);
  }
  // 7) reparam (mean chunks z: q=0-7, kv=16-23; var chunks: q=8-15, kv=24-31)
  z_combine_b<<<(B_ * SR_ * MVH_) / 256, 256, 0, stream>>>(mv, mv + 8 * 65536,
      eps_zq, dirty_zq, e2de, zqb, B_ * SR_ * MVH_, SR_ * MVH_);
  z_combine_b<<<(B_ * SR_ * MVH_) / 256, 256, 0, stream>>>(mv + 16 * 65536,
      mv + 24 * 65536, eps_zkv, dirty_zkv, e2de, zkvb, B_ * SR_ * MVH_, SR_ * MVH_);
  // 8) z transposes
  {
    dim3 g(MVH_ / 32, SR_ / 32, B_);
    trans_b2b<<<g, 256, 0, stream>>>(zqb, zqT, SR_, MVH_, (long)SR_ * MVH_);
    trans_b2b<<<g, 256, 0, stream>>>(zkvb, zkvT, SR_, MVH_, (long)SR_ * MVH_);
  }
  // 9) grouped upsample-1: z=32 (chain {qzu,kzu,vzu,qr} x batch), M=1024,N=256,K=256
  {
    GrpTab t;
    const int wo[4] = {W_qzu, W_kzu, W_vzu, W_qr};
    for (int c = 0; c < 4; ++c)
      for (int b = 0; b < 8; ++b) {
        int z = c * 8 + b;
        t.A[z] = wb + wo[c];
        t.Bm[z] = ((c == 0 || c == 3) ? zqT : zkvT) + (size_t)b * 65536;
        t.C[z] = up + (size_t)z * 1024 * 256;
      }
    dim3 g(MVH_ / 128, SN_ / 128, 32);
    gemm_grp<<<g, 256, 0, stream>>>(t, SN_, MVH_, SR_);
  }
  // 10) grouped upsample-2 (qz,kz,vz): z=3, M=8192,N=512,K=256
  {
    GrpTab t;
    const int wo[3] = {W_qzup, W_kzup, W_vzup};
    for (int c = 0; c < 3; ++c) {
      t.A[c] = up + (size_t)c * 8 * 1024 * 256;
      t.Bm[c] = wb + wo[c];
      t.C[c] = mid + (size_t)c * 8192 * 512;
    }
    dim3 g(D2_ / 128, (B_ * SN_) / 128, 3);
    gemm_grp<<<g, 256, 0, stream>>>(t, B_ * SN_, D2_, MVH_);
  }
  // 11) qr stage-2: M=8192,N=384,K=256
  {
    dim3 g(384 / 128, (B_ * SN_) / 128, 1);
    gemm_bf16<0><<<g, 256, 0, stream>>>(up + (size_t)3 * 8 * 1024 * 256, 0,
        wb + W_qrw, 0, nullptr, qrf, 0, B_ * SN_, 384, MVH_);
  }
  // 12) grouped stage-3 (q_w, k_w): z=2, M=8192,N=384,K=512
  {
    GrpTab t;
    t.A[0] = mid;                 t.Bm[0] = wb + W_qw; t.C[0] = qzf;
    t.A[1] = mid + (size_t)8192 * 512; t.Bm[1] = wb + W_kw; t.C[1] = kzf;
    dim3 g(384 / 128, (B_ * SN_) / 128, 2);
    gemm_grp<<<g, 256, 0, stream>>>(t, B_ * SN_, 384, D2_);
  }
  // 13) v_w: M=8192,N=768,K=512
  {
    dim3 g(D3_ / 128, (B_ * SN_) / 128, 1);
    gemm_bf16<0><<<g, 256, 0, stream>>>(mid + (size_t)2 * 8192 * 512, 0,
        wb + W_vw, 0, nullptr, vzf, 0, B_ * SN_, D3_, D2_);
  }
  // 14) kr stage-1 (strided batch): M=1024,N=768,K=1024
  {
    dim3 g(D1_ / 128, SN_ / 128, B_);
    gemm_bf16<0><<<g, 256, 0, stream>>>(wb + W_kr, 0, inT, sXT, nullptr, tkr,
        (long)SN_ * D1_, SN_, D1_, S_);
  }
  // 15) kr stage-2: M=8192,N=384,K=768
  {
    dim3 g(384 / 128, (B_ * SN_) / 128, 1);
    gemm_bf16<0><<<g, 256, 0, stream>>>(tkr, 0, wb + W_krw, 0, nullptr, krf, 0,
        B_ * SN_, 384, D1_);
  }

  // 16) pack heads (+RoPE; q pre-scaled)
  int tot = B_ * H_ * S_ * HD_;
  pack_qk_b<<<tot / 256, 256, 0, stream>>>(qzf, qrf, rope_q_f, qp, 0.125f);
  pack_qk_b<<<tot / 256, 256, 0, stream>>>(kzf, krf, rope_k_f, kp, 1.0f);
  pack_v_b<<<tot / 256, 256, 0, stream>>>(vzf, vp);

  // 17) attention
  {
    dim3 g(S_ / 64, B_ * H_);
    attn_mfma<<<g, 256, 0, stream>>>(qp, kp, vp, ofb);
  }

  // 18) epilogue
  {
    dim3 g(D3_ / 128, (B_ * SN_) / 128);
    gemm_bf16<1><<<g, 256, 0, stream>>>(ofb, 0, wb + W_ow, 0, input_q, xb, 0,
                                        B_ * SN_, D3_, D3_);
  }
  ln_b<<<B_ * SN_, 256, 0, stream>>>(xb, ln2_w, ylb, D3_);
  {
    dim3 g(MLP_ / 128, (B_ * SN_) / 128);
    gemm_bf16<2><<<g, 256, 0, stream>>>(ylb, 0, wb + W_m1, 0, nullptr, hm, 0,
                                        B_ * SN_, MLP_, D3_);
  }
  {
    dim3 g(D3_ / 128, (B_ * SN_) / 128);
    gemm_bf16<1><<<g, 256, 0, stream>>>(hm, 0, wb + W_m2, 0, xb, (float*)d_out, 0,
                                        B_ * SN_, D3_, MLP_);
  }
}

// Round 11
// 542.919 us; speedup vs baseline: 10.7297x; 1.0855x over previous
//
#include <hip/hip_runtime.h>
#include <math.h>

#define B_   8
#define S_   1024
#define SR_  256
#define SN_  1024
#define D1_  768
#define D2_  512
#define D3_  768
#define MVH_ 256
#define H_   12
#define HD_  64
#define MLP_ 3072

typedef __attribute__((ext_vector_type(8))) short bf16x8;
typedef __attribute__((ext_vector_type(4))) float f32x4;

__device__ inline ushort f2bf(float f) {
  uint u = __float_as_uint(f);
  uint r = (u + 0x7fffu + ((u >> 16) & 1u)) >> 16;
  return (ushort)r;
}
__device__ inline float b2f(ushort u) { return __uint_as_float(((uint)u) << 16); }

__device__ inline void gload16(const void* g, void* l) {
  __builtin_amdgcn_global_load_lds(
      (const __attribute__((address_space(1))) void*)g,
      (__attribute__((address_space(3))) void*)l, 16, 0, 0);
}

// bijective XCD-aware work remap (m204): consecutive NEW ids come from one XCD.
__device__ inline int xcd_swz(int lin, int n) {
  int xcd = lin & 7, idx = lin >> 3;
  int q = n >> 3, r = n & 7;
  return (xcd < r ? xcd * (q + 1) : r * (q + 1) + (xcd - r) * q) + idx;
}

// ---------------- LayerNorm (dual bf16 out) ----------------
__global__ __launch_bounds__(256) void ln_dual_b(const float* __restrict__ x,
    const float* __restrict__ w1, const float* __restrict__ w2,
    ushort* __restrict__ o1, ushort* __restrict__ o2, int D) {
  int row = blockIdx.x;
  const float* xr = x + (size_t)row * D;
  int tid = threadIdx.x;
  float s = 0.f, ss = 0.f;
  for (int i = tid; i < D; i += 256) { float v = xr[i]; s += v; ss += v * v; }
  __shared__ float rs[256];
  __shared__ float rq[256];
  rs[tid] = s; rq[tid] = ss;
  __syncthreads();
  for (int off = 128; off > 0; off >>= 1) {
    if (tid < off) { rs[tid] += rs[tid + off]; rq[tid] += rq[tid + off]; }
    __syncthreads();
  }
  float mu  = rs[0] / (float)D;
  float var = rq[0] / (float)D - mu * mu;
  float inv = rsqrtf(var + 1e-6f);
  for (int i = tid; i < D; i += 256) {
    float v = (xr[i] - mu) * inv;
    o1[(size_t)row * D + i] = f2bf(v * w1[i]);
    o2[(size_t)row * D + i] = f2bf(v * w2[i]);
  }
}

// ---------------- LayerNorm (bf16 out, single) ----------------
__global__ __launch_bounds__(256) void ln_b(const float* __restrict__ x,
    const float* __restrict__ w, ushort* __restrict__ o, int D) {
  int row = blockIdx.x;
  const float* xr = x + (size_t)row * D;
  int tid = threadIdx.x;
  float s = 0.f, ss = 0.f;
  for (int i = tid; i < D; i += 256) { float v = xr[i]; s += v; ss += v * v; }
  __shared__ float rs[256];
  __shared__ float rq[256];
  rs[tid] = s; rq[tid] = ss;
  __syncthreads();
  for (int off = 128; off > 0; off >>= 1) {
    if (tid < off) { rs[tid] += rs[tid + off]; rq[tid] += rq[tid + off]; }
    __syncthreads();
  }
  float mu  = rs[0] / (float)D;
  float var = rq[0] / (float)D - mu * mu;
  float inv = rsqrtf(var + 1e-6f);
  for (int i = tid; i < D; i += 256) {
    float v = (xr[i] - mu) * inv;
    o[(size_t)row * D + i] = f2bf(v * w[i]);
  }
}

// ---------------- transpose fp32 -> bf16 ----------------
__global__ __launch_bounds__(256) void trans_f2b(const float* __restrict__ in,
    ushort* __restrict__ out, int R, int C, long strideEl) {
  __shared__ float tile[32][33];
  int bb = blockIdx.z;
  const float* ib = in + (size_t)bb * strideEl;
  ushort* ob = out + (size_t)bb * strideEl;
  int c0 = blockIdx.x << 5, r0 = blockIdx.y << 5;
  int tx = threadIdx.x & 31, ty = threadIdx.x >> 5;
#pragma unroll
  for (int i = 0; i < 4; ++i)
    tile[ty + 8 * i][tx] = ib[(size_t)(r0 + ty + 8 * i) * C + c0 + tx];
  __syncthreads();
#pragma unroll
  for (int i = 0; i < 4; ++i)
    ob[(size_t)(c0 + ty + 8 * i) * R + r0 + tx] = f2bf(tile[tx][ty + 8 * i]);
}

// ---------------- transpose bf16 -> bf16 ----------------
__global__ __launch_bounds__(256) void trans_b2b(const ushort* __restrict__ in,
    ushort* __restrict__ out, int R, int C, long strideEl) {
  __shared__ ushort tile[32][33];
  int bb = blockIdx.z;
  const ushort* ib = in + (size_t)bb * strideEl;
  ushort* ob = out + (size_t)bb * strideEl;
  int c0 = blockIdx.x << 5, r0 = blockIdx.y << 5;
  int tx = threadIdx.x & 31, ty = threadIdx.x >> 5;
#pragma unroll
  for (int i = 0; i < 4; ++i)
    tile[ty + 8 * i][tx] = ib[(size_t)(r0 + ty + 8 * i) * C + c0 + tx];
  __syncthreads();
#pragma unroll
  for (int i = 0; i < 4; ++i)
    ob[(size_t)(c0 + ty + 8 * i) * R + r0 + tx] = tile[tx][ty + 8 * i];
}

// ---------------- multi-tensor fp32 -> bf16 weight conversion ----------------
struct ConvTab {
  const float* src[28];
  int off[28];
  int cum[29];
};
__global__ __launch_bounds__(256) void multi_f2b(ConvTab t, ushort* __restrict__ wb,
                                                 int total4) {
  int i = blockIdx.x * 256 + threadIdx.x;
  if (i >= total4) return;
  int ti = 0;
  while (t.cum[ti + 1] <= i) ++ti;
  int j = i - t.cum[ti];
  float4 v = ((const float4*)t.src[ti])[j];
  ushort4 o;
  o.x = f2bf(v.x); o.y = f2bf(v.y); o.z = f2bf(v.z); o.w = f2bf(v.w);
  ((ushort4*)(wb + t.off[ti]))[j] = o;
}

// ---------------- RoPE cos/sin tables ----------------
__global__ __launch_bounds__(256) void rope_tab(const float* __restrict__ fq,
    const float* __restrict__ fk, float* __restrict__ ctq, float* __restrict__ stq,
    float* __restrict__ ctk, float* __restrict__ stk, int n) {
  int i = blockIdx.x * 256 + threadIdx.x;
  if (i >= n) return;
  float a = fq[i]; ctq[i] = cosf(a); stq[i] = sinf(a);
  float c = fk[i]; ctk[i] = cosf(c); stk[i] = sinf(c);
}

// ---------------- bf16 MFMA GEMM (strided batch): C_b = A_b @ B_b^T ----------------
// EPI: 0 = bf16 out, 1 = fp32 out + R, 2 = fast-gelu bf16 out
template <int EPI>
__global__ __launch_bounds__(256) void gemm_bf16(const ushort* __restrict__ A, long sA,
    const ushort* __restrict__ Bm, long sB, const float* __restrict__ R,
    void* __restrict__ Cout, long sC, int M, int N, int K) {
  int gx = gridDim.x, gy = gridDim.y;
  int nwg = gx * gy * gridDim.z;
  int lin = ((int)blockIdx.z * gy + (int)blockIdx.y) * gx + (int)blockIdx.x;
  lin = xcd_swz(lin, nwg);
  int bx = lin % gx, tt = lin / gx;
  int by = tt % gy, bb = tt / gy;
  const ushort* Ab = A + (size_t)bb * sA;
  const ushort* Bb = Bm + (size_t)bb * sB;
  __shared__ ushort As[128 * 32];
  __shared__ ushort Bs[128 * 32];
  int tid = threadIdx.x;
  int lane = tid & 63, wid = tid >> 6;
  int m0 = by << 7, n0 = bx << 7;
  int wm = (wid >> 1) << 6, wn = (wid & 1) << 6;
  f32x4 acc[4][4];
#pragma unroll
  for (int i = 0; i < 4; ++i)
#pragma unroll
    for (int j = 0; j < 4; ++j) acc[i][j] = (f32x4){0.f, 0.f, 0.f, 0.f};
  char* asb = (char*)As;
  char* bsb = (char*)Bs;
  int srow = lane >> 2;
  int skb  = (lane & 3) << 4;
  for (int k0 = 0; k0 < K; k0 += 32) {
    __syncthreads();
#pragma unroll
    for (int i = 0; i < 2; ++i) {
      int rr = wid * 32 + i * 16;
      gload16((const char*)Ab + ((size_t)(m0 + rr + srow) * K + k0) * 2 + skb,
              asb + rr * 64);
      gload16((const char*)Bb + ((size_t)(n0 + rr + srow) * K + k0) * 2 + skb,
              bsb + rr * 64);
    }
    __syncthreads();
    bf16x8 af[4], bf[4];
#pragma unroll
    for (int m = 0; m < 4; ++m)
      af[m] = *(bf16x8*)&As[(wm + m * 16 + (lane & 15)) * 32 + ((lane >> 4) << 3)];
#pragma unroll
    for (int n = 0; n < 4; ++n)
      bf[n] = *(bf16x8*)&Bs[(wn + n * 16 + (lane & 15)) * 32 + ((lane >> 4) << 3)];
#pragma unroll
    for (int m = 0; m < 4; ++m)
#pragma unroll
      for (int n = 0; n < 4; ++n)
        acc[m][n] = __builtin_amdgcn_mfma_f32_16x16x32_bf16(af[m], bf[n], acc[m][n], 0, 0, 0);
  }
  int cr = (lane >> 4) << 2, cc = lane & 15;
#pragma unroll
  for (int m = 0; m < 4; ++m)
#pragma unroll
    for (int n = 0; n < 4; ++n) {
#pragma unroll
      for (int r = 0; r < 4; ++r) {
        int row = m0 + wm + m * 16 + cr + r;
        int col = n0 + wn + n * 16 + cc;
        float v = acc[m][n][r];
        if (EPI == 0) {
          ((ushort*)Cout)[(size_t)bb * sC + (size_t)row * N + col] = f2bf(v);
        } else if (EPI == 1) {
          ((float*)Cout)[(size_t)row * N + col] = v + R[(size_t)row * N + col];
        } else {
          float y = 0.7978845608f * (v + 0.044715f * v * v * v);
          float sg = 1.0f / (1.0f + __expf(-2.0f * y));
          ((ushort*)Cout)[(size_t)row * N + col] = f2bf(v * sg);
        }
      }
    }
}

// ---------------- grouped bf16 MFMA GEMM: per-z pointer table, bf16 out ----------------
struct GrpTab {
  const ushort* A[32];
  const ushort* Bm[32];
  ushort* C[32];
};
__global__ __launch_bounds__(256) void gemm_grp(GrpTab t, int M, int N, int K) {
  int gx = gridDim.x, gy = gridDim.y;
  int nwg = gx * gy * gridDim.z;
  int lin = ((int)blockIdx.z * gy + (int)blockIdx.y) * gx + (int)blockIdx.x;
  lin = xcd_swz(lin, nwg);
  int bx = lin % gx, tt = lin / gx;
  int by = tt % gy, zz = tt / gy;
  const ushort* Ab = t.A[zz];
  const ushort* Bb = t.Bm[zz];
  ushort* Cb = t.C[zz];
  __shared__ ushort As[128 * 32];
  __shared__ ushort Bs[128 * 32];
  int tid = threadIdx.x;
  int lane = tid & 63, wid = tid >> 6;
  int m0 = by << 7, n0 = bx << 7;
  int wm = (wid >> 1) << 6, wn = (wid & 1) << 6;
  f32x4 acc[4][4];
#pragma unroll
  for (int i = 0; i < 4; ++i)
#pragma unroll
    for (int j = 0; j < 4; ++j) acc[i][j] = (f32x4){0.f, 0.f, 0.f, 0.f};
  char* asb = (char*)As;
  char* bsb = (char*)Bs;
  int srow = lane >> 2;
  int skb  = (lane & 3) << 4;
  for (int k0 = 0; k0 < K; k0 += 32) {
    __syncthreads();
#pragma unroll
    for (int i = 0; i < 2; ++i) {
      int rr = wid * 32 + i * 16;
      gload16((const char*)Ab + ((size_t)(m0 + rr + srow) * K + k0) * 2 + skb,
              asb + rr * 64);
      gload16((const char*)Bb + ((size_t)(n0 + rr + srow) * K + k0) * 2 + skb,
              bsb + rr * 64);
    }
    __syncthreads();
    bf16x8 af[4], bf[4];
#pragma unroll
    for (int m = 0; m < 4; ++m)
      af[m] = *(bf16x8*)&As[(wm + m * 16 + (lane & 15)) * 32 + ((lane >> 4) << 3)];
#pragma unroll
    for (int n = 0; n < 4; ++n)
      bf[n] = *(bf16x8*)&Bs[(wn + n * 16 + (lane & 15)) * 32 + ((lane >> 4) << 3)];
#pragma unroll
    for (int m = 0; m < 4; ++m)
#pragma unroll
      for (int n = 0; n < 4; ++n)
        acc[m][n] = __builtin_amdgcn_mfma_f32_16x16x32_bf16(af[m], bf[n], acc[m][n], 0, 0, 0);
  }
  int cr = (lane >> 4) << 2, cc = lane & 15;
#pragma unroll
  for (int m = 0; m < 4; ++m)
#pragma unroll
    for (int n = 0; n < 4; ++n) {
#pragma unroll
      for (int r = 0; r < 4; ++r) {
        int row = m0 + wm + m * 16 + cr + r;
        int col = n0 + wn + n * 16 + cc;
        Cb[(size_t)row * N + col] = f2bf(acc[m][n][r]);
      }
    }
}

// ---------------- reparameterization (bf16 in/out) ----------------
__global__ __launch_bounds__(256) void z_combine_b(const ushort* __restrict__ mean,
    const ushort* __restrict__ var, const float* __restrict__ eps,
    const float* __restrict__ dirty, const float* __restrict__ e2de_p,
    ushort* __restrict__ zout, int total, int perBatch) {
  int i = blockIdx.x * 256 + threadIdx.x;
  if (i >= total) return;
  float e = e2de_p[0];
  float v = b2f(mean[i]) +
            (e * eps[i] + (1.0f - e) * dirty[i % perBatch]) * expf(0.5f * b2f(var[i]));
  zout[i] = f2bf(v);
}

// ---------------- head pack + RoPE (vectorized, bf16 in/out, table trig) ----------------
__global__ __launch_bounds__(256) void pack_qk_b8(const ushort* __restrict__ zf,
    const ushort* __restrict__ rf, const float* __restrict__ ct,
    const float* __restrict__ st, ushort* __restrict__ out, float scale) {
  int i8 = blockIdx.x * 256 + threadIdx.x;
  int i = i8 << 3;                 // element index; chunk of 8 within one 64-d row
  int d0 = i & 63;
  int s = (i >> 6) & (S_ - 1);
  int bh = i >> 16;
  int b = bh / H_, h = bh % H_;
  short res[8];
  if (d0 < 32) {
    bf16x8 v = *(const bf16x8*)(zf + ((size_t)(b * S_ + s)) * (H_ * 32) + h * 32 + d0);
#pragma unroll
    for (int j = 0; j < 8; ++j) res[j] = (short)f2bf(b2f((ushort)v[j]) * scale);
  } else {
    const ushort* xr = rf + ((size_t)(b * S_ + s)) * (H_ * 32) + h * 32;
    int dr0 = d0 - 32;
    if (dr0 < 16) {
      bf16x8 xa = *(const bf16x8*)(xr + dr0);
      bf16x8 xb2 = *(const bf16x8*)(xr + dr0 + 16);
#pragma unroll
      for (int j = 0; j < 8; ++j) {
        float c = ct[s * 16 + dr0 + j], sn = st[s * 16 + dr0 + j];
        res[j] = (short)f2bf((b2f((ushort)xa[j]) * c - b2f((ushort)xb2[j]) * sn) * scale);
      }
    } else {
      bf16x8 xa = *(const bf16x8*)(xr + dr0);
      bf16x8 xb2 = *(const bf16x8*)(xr + dr0 - 16);
#pragma unroll
      for (int j = 0; j < 8; ++j) {
        float c = ct[s * 16 + dr0 - 16 + j], sn = st[s * 16 + dr0 - 16 + j];
        res[j] = (short)f2bf((b2f((ushort)xa[j]) * c + b2f((ushort)xb2[j]) * sn) * scale);
      }
    }
  }
  *(bf16x8*)(out + i) = *(bf16x8*)res;
}

__global__ __launch_bounds__(256) void pack_v_b8(const ushort* __restrict__ vzf,
    ushort* __restrict__ out) {
  int i8 = blockIdx.x * 256 + threadIdx.x;
  int i = i8 << 3;
  int d0 = i & 63;
  int s = (i >> 6) & (S_ - 1);
  int bh = i >> 16;
  int b = bh / H_, h = bh % H_;
  bf16x8 v = *(const bf16x8*)(vzf + ((size_t)(b * S_ + s)) * D3_ + h * 64 + d0);
  *(bf16x8*)(out + i) = v;
}

// ---------------- MFMA flash attention (XCD-swizzled grid) ----------------
__global__ __launch_bounds__(256) void attn_mfma(const ushort* __restrict__ Q,
    const ushort* __restrict__ K, const ushort* __restrict__ V,
    ushort* __restrict__ O) {
  __shared__ ushort lds[16384];                 // 32 KB
  char* qc = (char*)lds;
  char* kc = (char*)lds + 8192;
  char* vc = (char*)lds + 16384;
  char* pc = (char*)lds + 24576;
  int tid = threadIdx.x, lane = tid & 63, wid = tid >> 6;
  int nwg = gridDim.x * gridDim.y;
  int lin = (int)blockIdx.y * gridDim.x + (int)blockIdx.x;
  lin = xcd_swz(lin, nwg);
  int qt = lin % gridDim.x;
  int bh = lin / gridDim.x;
  int q0 = qt << 6;
  int b = bh / H_, h = bh % H_;
  const ushort* Qb = Q + ((size_t)bh * S_ + q0) * HD_;
  const ushort* Kb = K + (size_t)bh * S_ * HD_;
  const ushort* Vb = V + (size_t)bh * S_ * HD_;
  {
    int r = tid >> 2, c0 = (tid & 3) * 32;
    const char* src = (const char*)Qb + r * 128;
    uint4 v0 = *(const uint4*)(src + c0);
    uint4 v1 = *(const uint4*)(src + c0 + 16);
    int sw = (r & 7) << 4;
    *(uint4*)(qc + r * 128 + (c0 ^ sw)) = v0;
    *(uint4*)(qc + r * 128 + ((c0 + 16) ^ sw)) = v1;
  }
  __syncthreads();
  bf16x8 aq[2];
  {
    int r = wid * 16 + (lane & 15);
    int sw = (r & 7) << 4;
#pragma unroll
    for (int kk = 0; kk < 2; ++kk) {
      int c2 = kk * 64 + ((lane >> 4) << 4);
      aq[kk] = *(bf16x8*)(qc + r * 128 + (c2 ^ sw));
    }
  }
  f32x4 o_[4];
  float m_[4], l_[4];
#pragma unroll
  for (int i = 0; i < 4; ++i) { o_[i] = (f32x4){0.f,0.f,0.f,0.f}; m_[i] = -1e30f; l_[i] = 0.f; }

  for (int kt = 0; kt < S_ / 64; ++kt) {
    __syncthreads();
    {
      int r = tid >> 2, c0 = (tid & 3) * 32;
      const char* src = (const char*)(Kb + (size_t)(kt * 64 + r) * HD_);
      uint4 v0 = *(const uint4*)(src + c0);
      uint4 v1 = *(const uint4*)(src + c0 + 16);
      int sw = (r & 7) << 4;
      *(uint4*)(kc + r * 128 + (c0 ^ sw)) = v0;
      *(uint4*)(kc + r * 128 + ((c0 + 16) ^ sw)) = v1;
    }
    {
      int kp = tid & 31, g = tid >> 5, d0 = g * 8;
      const ushort* s0 = Vb + (size_t)(kt * 64 + 2 * kp) * HD_ + d0;
      bf16x8 va = *(const bf16x8*)s0;
      bf16x8 vb2 = *(const bf16x8*)(s0 + HD_);
#pragma unroll
      for (int j = 0; j < 8; ++j) {
        int d = d0 + j;
        uint val = (uint)(ushort)va[j] | ((uint)(ushort)vb2[j] << 16);
        *(uint*)(vc + d * 128 + ((kp * 4) ^ ((d & 7) << 4))) = val;
      }
    }
    __syncthreads();
    f32x4 sacc[4];
#pragma unroll
    for (int ksub = 0; ksub < 4; ++ksub) {
      sacc[ksub] = (f32x4){0.f,0.f,0.f,0.f};
#pragma unroll
      for (int kk = 0; kk < 2; ++kk) {
        int r = ksub * 16 + (lane & 15);
        int c2 = kk * 64 + ((lane >> 4) << 4);
        bf16x8 bk = *(bf16x8*)(kc + r * 128 + (c2 ^ ((r & 7) << 4)));
        sacc[ksub] = __builtin_amdgcn_mfma_f32_16x16x32_bf16(aq[kk], bk, sacc[ksub], 0, 0, 0);
      }
    }
    float p[4][4];
#pragma unroll
    for (int rr = 0; rr < 4; ++rr) {
      float cm = fmaxf(fmaxf(sacc[0][rr], sacc[1][rr]), fmaxf(sacc[2][rr], sacc[3][rr]));
      cm = fmaxf(cm, __shfl_xor(cm, 1));
      cm = fmaxf(cm, __shfl_xor(cm, 2));
      cm = fmaxf(cm, __shfl_xor(cm, 4));
      cm = fmaxf(cm, __shfl_xor(cm, 8));
      float mn = fmaxf(m_[rr], cm);
      float al = __expf(m_[rr] - mn);
      float ps = 0.f;
#pragma unroll
      for (int ksub = 0; ksub < 4; ++ksub) {
        float pv = __expf(sacc[ksub][rr] - mn);
        p[ksub][rr] = pv;
        ps += pv;
      }
      ps += __shfl_xor(ps, 1);
      ps += __shfl_xor(ps, 2);
      ps += __shfl_xor(ps, 4);
      ps += __shfl_xor(ps, 8);
      l_[rr] = l_[rr] * al + ps;
      m_[rr] = mn;
#pragma unroll
      for (int ds = 0; ds < 4; ++ds) o_[ds][rr] *= al;
    }
#pragma unroll
    for (int ksub = 0; ksub < 4; ++ksub)
#pragma unroll
      for (int rr = 0; rr < 4; ++rr) {
        int r = wid * 16 + ((lane >> 4) << 2) + rr;
        int cb = (ksub * 16 + (lane & 15)) * 2;
        *(ushort*)(pc + r * 128 + (cb ^ ((r & 7) << 4))) = f2bf(p[ksub][rr]);
      }
#pragma unroll
    for (int kk2 = 0; kk2 < 2; ++kk2) {
      int rA = wid * 16 + (lane & 15);
      int c2 = kk2 * 64 + ((lane >> 4) << 4);
      bf16x8 ap = *(bf16x8*)(pc + rA * 128 + (c2 ^ ((rA & 7) << 4)));
#pragma unroll
      for (int ds = 0; ds < 4; ++ds) {
        int rB = ds * 16 + (lane & 15);
        bf16x8 bv = *(bf16x8*)(vc + rB * 128 + (c2 ^ ((rB & 7) << 4)));
        o_[ds] = __builtin_amdgcn_mfma_f32_16x16x32_bf16(ap, bv, o_[ds], 0, 0, 0);
      }
    }
  }
#pragma unroll
  for (int rr = 0; rr < 4; ++rr) {
    float inv = 1.f / l_[rr];
    int q = q0 + wid * 16 + ((lane >> 4) << 2) + rr;
#pragma unroll
    for (int ds = 0; ds < 4; ++ds) {
      int d = ds * 16 + (lane & 15);
      O[((size_t)(b * S_ + q)) * D3_ + h * HD_ + d] = f2bf(o_[ds][rr] * inv);
    }
  }
}

// ---------------- host ----------------
extern "C" void kernel_launch(void* const* d_in, const int* in_sizes, int n_in,
                              void* d_out, int out_size, void* d_ws, size_t ws_size,
                              hipStream_t stream) {
  const float* input_q = (const float*)d_in[0];
  const float* ln_q_w  = (const float*)d_in[1];
  const float* ln_kv_w = (const float*)d_in[2];
  const float* dirty_zq  = (const float*)d_in[15];
  const float* dirty_zkv = (const float*)d_in[16];
  const float* e2de    = (const float*)d_in[17];
  const float* rope_q_f = (const float*)d_in[31];
  const float* rope_k_f = (const float*)d_in[32];
  const float* ln2_w   = (const float*)d_in[34];
  const float* eps_zq  = (const float*)d_in[37];
  const float* eps_zkv = (const float*)d_in[38];

  ushort* wsu = (ushort*)d_ws;
  // ---- arena (ushort-element offsets; liveness audited round 10 + bf16-LN swap) ----
  ushort* wb    = wsu;                        // weights bf16 [0, 12124160)
  ushort* xq_b  = wsu + 12124160;             // [8,1024,768] bf16
  ushort* xkv_b = wsu + 18415616;
  ushort* xqT   = wsu + 37289984;             // [8,768,1024]
  ushort* xkvT  = wsu + 43581440;
  ushort* inT   = wsu + 49872896;
  ushort* t1q   = wsu + 12124160;             // (xq_b/xkv_b dead after transposes)
  ushort* t1kv  = wsu + 15269888;
  ushort* t2b   = wsu + 24707072;             // [32][256][512] -> ends 28901376
  ushort* mv    = wsu + 28901376;             // [32][256][256] -> ends 30998528
  ushort* zqb   = wsu + 30998528;
  ushort* zkvb  = wsu + 31522816;
  ushort* zqT   = wsu + 32047104;
  ushort* zkvT  = wsu + 32571392;             // ends 33095680
  ushort* up    = wsu + 12124160;             // [4][8][1024][256] (t1 dead) -> ends 20512768
  ushort* vzf   = wsu + 20512768;             // [8192,768] (t2b dead by step 13) -> ends 26804224
  ushort* mid   = wsu + 56164352;             // [3][8192][512] -> ends 68747264
  ushort* tkr   = wsu + 37289984;             // (xqT dead) -> ends 43581440
  ushort* qzf   = wsu + 68747264;
  ushort* kzf   = wsu + 71892992;
  ushort* qrf   = wsu + 75038720;
  ushort* krf   = wsu + 78184448;             // ends 81330176
  float*  ctq   = (float*)(wsu + 81330176);   // 4 tables x 16384 f32
  float*  stq   = ctq + 16384;
  float*  ctk   = ctq + 32768;
  float*  stk   = ctq + 49152;                // ends 81330176+131072 ushorts
  ushort* qp    = wsu + 12124160;             // (up dead after step 11) -> ends 18415616
  ushort* kp    = wsu + 43581440;             // (xkvT dead)
  ushort* vp    = wsu + 49872896;             // (inT dead after step 14)
  ushort* ofb   = wsu + 56164352;             // (mid dead)
  float*  xb    = (float*)(wsu + 12124160);   // (qp/vzf dead after attn/packs)
  ushort* ylb   = wsu + 37289984;             // (tkr dead)
  ushort* hm    = wsu + 43581440;             // [8192,3072] (kp/vp/ofb dead)

  // weight offsets within wb (elements)
  const int W_mq = 0,       W_mkv = 524288;
  const int Wq1 = 1048576,  Wv1 = 1441792,  Wk1 = 1835008,  Wkv1 = 2228224;
  const int Wq2 = 2621440,  Wv2 = 2752512,  Wk2 = 2883584,  Wkv2 = 3014656;
  const int W_qzu = 3145728, W_kzu = 3407872, W_vzu = 3670016, W_qr = 3932160;
  const int W_kr = 4194304, W_qzup = 5242880, W_kzup = 5373952, W_vzup = 5505024;
  const int W_qw = 5636096, W_kw = 5832704,  W_vw = 6029312,  W_qrw = 6422528;
  const int W_krw = 6520832, W_ow = 6815744, W_m1 = 7405568,  W_m2 = 9764864;

  // 1) dual LN -> bf16
  ln_dual_b<<<B_ * S_, 256, 0, stream>>>(input_q, ln_q_w, ln_kv_w, xq_b, xkv_b, D1_);

  // 2) transposes to [b, D, S]
  {
    dim3 g(D1_ / 32, S_ / 32, B_);
    trans_b2b<<<g, 256, 0, stream>>>(xq_b, xqT, S_, D1_, (long)S_ * D1_);
    trans_b2b<<<g, 256, 0, stream>>>(xkv_b, xkvT, S_, D1_, (long)S_ * D1_);
    trans_f2b<<<g, 256, 0, stream>>>(input_q, inT, S_, D1_, (long)S_ * D1_);
  }

  // 3) weights -> bf16 + RoPE tables
  {
    ConvTab t;
    const int srcIdx[28] = {3,4,5,6, 7,9,11,13, 8,10,12,14, 18,19,20,21, 22,
                            23,24,25, 26,27, 28, 29, 30, 33, 35, 36};
    const int sz[28] = {262144,262144,262144,262144, 393216,393216,393216,393216,
                        131072,131072,131072,131072, 262144,262144,262144,262144,
                        1048576, 131072,131072,131072, 196608,196608, 393216,
                        98304, 294912, 589824, 2359296, 2359296};
    int off = 0, c4 = 0;
    for (int i = 0; i < 28; ++i) {
      t.src[i] = (const float*)d_in[srcIdx[i]];
      t.off[i] = off;
      t.cum[i] = c4;
      off += sz[i];
      c4 += sz[i] / 4;
    }
    t.cum[28] = c4;
    multi_f2b<<<(c4 + 255) / 256, 256, 0, stream>>>(t, wb, c4);
    rope_tab<<<64, 256, 0, stream>>>(rope_q_f, rope_k_f, ctq, stq, ctk, stk, 16384);
  }

  long sXT = (long)S_ * D1_;   // 786432

  // 4) grouped seq-compress: z=16; A = stacked [Wt_m;Wt_v] M=512
  {
    GrpTab t;
    for (int c = 0; c < 2; ++c)
      for (int b = 0; b < 8; ++b) {
        int z = c * 8 + b;
        t.A[z] = wb + (c == 0 ? W_mq : W_mkv);
        t.Bm[z] = (c == 0 ? xqT : xkvT) + (size_t)b * sXT;
        t.C[z] = (c == 0 ? t1q : t1kv) + (size_t)b * 512 * 768;
      }
    dim3 g(D1_ / 128, 512 / 128, 16);
    gemm_grp<<<g, 256, 0, stream>>>(t, 512, D1_, S_);
  }
  // 5) grouped w1: z=32, M=256,N=512,K=768
  {
    GrpTab t;
    const int wo[4] = {Wq1, Wv1, Wk1, Wkv1};
    for (int c = 0; c < 4; ++c)
      for (int b = 0; b < 8; ++b) {
        int z = c * 8 + b;
        ushort* t1 = (c < 2 ? t1q : t1kv);
        t.A[z] = t1 + (size_t)b * 512 * 768 + (size_t)(c & 1) * 256 * 768;
        t.Bm[z] = wb + wo[c];
        t.C[z] = t2b + (size_t)z * 256 * 512;
      }
    dim3 g(D2_ / 128, 256 / 128, 32);
    gemm_grp<<<g, 256, 0, stream>>>(t, 256, D2_, D1_);
  }
  // 6) grouped w2: z=32, M=256,N=256,K=512
  {
    GrpTab t;
    const int wo[4] = {Wq2, Wv2, Wk2, Wkv2};
    for (int c = 0; c < 4; ++c)
      for (int b = 0; b < 8; ++b) {
        int z = c * 8 + b;
        t.A[z] = t2b + (size_t)z * 256 * 512;
        t.Bm[z] = wb + wo[c];
        t.C[z] = mv + (size_t)z * 256 * 256;
      }
    dim3 g(MVH_ / 128, 256 / 128, 32);
    gemm_grp<<<g, 256, 0, stream>>>(t, 256, MVH_, D2_);
  }
  // 7) reparam
  z_combine_b<<<(B_ * SR_ * MVH_) / 256, 256, 0, stream>>>(mv, mv + 8 * 65536,
      eps_zq, dirty_zq, e2de, zqb, B_ * SR_ * MVH_, SR_ * MVH_);
  z_combine_b<<<(B_ * SR_ * MVH_) / 256, 256, 0, stream>>>(mv + 16 * 65536,
      mv + 24 * 65536, eps_zkv, dirty_zkv, e2de, zkvb, B_ * SR_ * MVH_, SR_ * MVH_);
  // 8) z transposes
  {
    dim3 g(MVH_ / 32, SR_ / 32, B_);
    trans_b2b<<<g, 256, 0, stream>>>(zqb, zqT, SR_, MVH_, (long)SR_ * MVH_);
    trans_b2b<<<g, 256, 0, stream>>>(zkvb, zkvT, SR_, MVH_, (long)SR_ * MVH_);
  }
  // 9) grouped upsample-1: z=32, M=1024,N=256,K=256
  {
    GrpTab t;
    const int wo[4] = {W_qzu, W_kzu, W_vzu, W_qr};
    for (int c = 0; c < 4; ++c)
      for (int b = 0; b < 8; ++b) {
        int z = c * 8 + b;
        t.A[z] = wb + wo[c];
        t.Bm[z] = ((c == 0 || c == 3) ? zqT : zkvT) + (size_t)b * 65536;
        t.C[z] = up + (size_t)z * 1024 * 256;
      }
    dim3 g(MVH_ / 128, SN_ / 128, 32);
    gemm_grp<<<g, 256, 0, stream>>>(t, SN_, MVH_, SR_);
  }
  // 10) grouped upsample-2 (qz,kz,vz): z=3, M=8192,N=512,K=256
  {
    GrpTab t;
    const int wo[3] = {W_qzup, W_kzup, W_vzup};
    for (int c = 0; c < 3; ++c) {
      t.A[c] = up + (size_t)c * 8 * 1024 * 256;
      t.Bm[c] = wb + wo[c];
      t.C[c] = mid + (size_t)c * 8192 * 512;
    }
    dim3 g(D2_ / 128, (B_ * SN_) / 128, 3);
    gemm_grp<<<g, 256, 0, stream>>>(t, B_ * SN_, D2_, MVH_);
  }
  // 11) qr stage-2: M=8192,N=384,K=256
  {
    dim3 g(384 / 128, (B_ * SN_) / 128, 1);
    gemm_bf16<0><<<g, 256, 0, stream>>>(up + (size_t)3 * 8 * 1024 * 256, 0,
        wb + W_qrw, 0, nullptr, qrf, 0, B_ * SN_, 384, MVH_);
  }
  // 12) grouped stage-3 (q_w, k_w): z=2, M=8192,N=384,K=512
  {
    GrpTab t;
    t.A[0] = mid;                      t.Bm[0] = wb + W_qw; t.C[0] = qzf;
    t.A[1] = mid + (size_t)8192 * 512; t.Bm[1] = wb + W_kw; t.C[1] = kzf;
    dim3 g(384 / 128, (B_ * SN_) / 128, 2);
    gemm_grp<<<g, 256, 0, stream>>>(t, B_ * SN_, 384, D2_);
  }
  // 13) v_w: M=8192,N=768,K=512
  {
    dim3 g(D3_ / 128, (B_ * SN_) / 128, 1);
    gemm_bf16<0><<<g, 256, 0, stream>>>(mid + (size_t)2 * 8192 * 512, 0,
        wb + W_vw, 0, nullptr, vzf, 0, B_ * SN_, D3_, D2_);
  }
  // 14) kr stage-1 (strided batch): M=1024,N=768,K=1024
  {
    dim3 g(D1_ / 128, SN_ / 128, B_);
    gemm_bf16<0><<<g, 256, 0, stream>>>(wb + W_kr, 0, inT, sXT, nullptr, tkr,
        (long)SN_ * D1_, SN_, D1_, S_);
  }
  // 15) kr stage-2: M=8192,N=384,K=768
  {
    dim3 g(384 / 128, (B_ * SN_) / 128, 1);
    gemm_bf16<0><<<g, 256, 0, stream>>>(tkr, 0, wb + W_krw, 0, nullptr, krf, 0,
        B_ * SN_, 384, D1_);
  }

  // 16) pack heads (+RoPE from tables; q pre-scaled)
  int chunks = (B_ * H_ * S_ * HD_) / 8;
  pack_qk_b8<<<chunks / 256, 256, 0, stream>>>(qzf, qrf, ctq, stq, qp, 0.125f);
  pack_qk_b8<<<chunks / 256, 256, 0, stream>>>(kzf, krf, ctk, stk, kp, 1.0f);
  pack_v_b8<<<chunks / 256, 256, 0, stream>>>(vzf, vp);

  // 17) attention
  {
    dim3 g(S_ / 64, B_ * H_);
    attn_mfma<<<g, 256, 0, stream>>>(qp, kp, vp, ofb);
  }

  // 18) epilogue
  {
    dim3 g(D3_ / 128, (B_ * SN_) / 128);
    gemm_bf16<1><<<g, 256, 0, stream>>>(ofb, 0, wb + W_ow, 0, input_q, xb, 0,
                                        B_ * SN_, D3_, D3_);
  }
  ln_b<<<B_ * SN_, 256, 0, stream>>>(xb, ln2_w, ylb, D3_);
  {
    dim3 g(MLP_ / 128, (B_ * SN_) / 128);
    gemm_bf16<2><<<g, 256, 0, stream>>>(ylb, 0, wb + W_m1, 0, nullptr, hm, 0,
                                        B_ * SN_, MLP_, D3_);
  }
  {
    dim3 g(D3_ / 128, (B_ * SN_) / 128);
    gemm_bf16<1><<<g, 256, 0, stream>>>(hm, 0, wb + W_m2, 0, xb, (float*)d_out, 0,
                                        B_ * SN_, D3_, MLP_);
  }
}